// Round 15
// baseline (104.838 us; speedup 1.0000x reference)
//
#include <hip/hip_runtime.h>
#include <hip/hip_bf16.h>

#define N_NODES 2048
#define N_EDGES 4096
#define F_IN    256
#define H_HEADS 8
#define HD      512
#define LOG2E   1.44269504088896f

typedef __attribute__((ext_vector_type(4))) float f32x4;
typedef __attribute__((ext_vector_type(2))) float f32x2;
typedef __attribute__((ext_vector_type(8))) short s16x8;
typedef __attribute__((ext_vector_type(4))) unsigned u32x4;

static __device__ __forceinline__ unsigned short f2bf(float x) {
  union { float f; unsigned u; } v; v.f = x;
  unsigned r = v.u + 0x7fff + ((v.u >> 16) & 1);   // RNE
  return (unsigned short)(r >> 16);
}
static __device__ __forceinline__ unsigned cvtpk(float lo, float hi) {
  unsigned r;
  asm("v_cvt_pk_bf16_f32 %0, %1, %2" : "=v"(r) : "v"(lo), "v"(hi));
  return r;
}

// ---------------------------------------------------------------------------
// Kernel A: bit-pack masks along m.  bits[n][m/32], bit j = mat[n][w*32+j].
// ---------------------------------------------------------------------------
__global__ __launch_bounds__(256) void pack_masks(
    const int* __restrict__ matN, const int* __restrict__ matE,
    unsigned* __restrict__ bitsN, unsigned* __restrict__ bitsE)
{
  int t = blockIdx.x * 256 + threadIdx.x;      // 393216 threads
  const int* src; unsigned* dst;
  if (t < N_NODES * (N_NODES / 32)) {
    int row = t >> 6, w = t & 63;
    src = &matN[(size_t)row * N_NODES + w * 32]; dst = &bitsN[t];
  } else {
    int tt = t - N_NODES * (N_NODES / 32);
    int row = tt >> 7, w = tt & 127;
    src = &matE[(size_t)row * N_EDGES + w * 32]; dst = &bitsE[tt];
  }
  unsigned b = 0;
#pragma unroll
  for (int k = 7; k >= 0; --k) {
    int4 v = *(const int4*)&src[k * 4];
    b = (b << 1) | ((unsigned)v.w & 1u);
    b = (b << 1) | ((unsigned)v.z & 1u);
    b = (b << 1) | ((unsigned)v.y & 1u);
    b = (b << 1) | ((unsigned)v.x & 1u);
  }
  *dst = b;
}

// ---------------------------------------------------------------------------
// Kernel B: fused ht-GEMM (scalar fp32) + bf16 tiled-transpose-out + scores.
// htT2 layout: [h][m/32][d=64][m%32] bf16  (4KB per 32-m block)
// ---------------------------------------------------------------------------
__global__ __launch_bounds__(256) void gemm_fused(
    const float* __restrict__ nodes, const float* __restrict__ edges,
    const float* __restrict__ WN, const float* __restrict__ WE,
    const float* __restrict__ aN, const float* __restrict__ aE,
    unsigned short* __restrict__ htT_n, unsigned short* __restrict__ htT_e,
    float* __restrict__ srcN, float* __restrict__ tgtN,
    float* __restrict__ srcE, float* __restrict__ tgtE)
{
  const int rt = blockIdx.x;   // 0..31 nodes, 32..95 edges
  const int h  = blockIdx.y;   // head
  const bool isNode = (rt < 32);
  const float* __restrict__ X = isNode ? nodes : edges;
  const float* __restrict__ W = isNode ? WN : WE;
  const int r0 = (isNode ? rt : rt - 32) * 64;
  const int MT = (isNode ? N_NODES : N_EDGES) / 32;

  __shared__ __align__(16) float Xs[32][68];
  __shared__ __align__(16) float Ws[32][64];
  __shared__ __align__(16) float T[64][68];    // T[d][m_local]

  const int tid = threadIdx.x;
  const int tx = tid & 15, ty = tid >> 4;

  float acc[4][4];
#pragma unroll
  for (int i = 0; i < 4; ++i)
#pragma unroll
    for (int j = 0; j < 4; ++j) acc[i][j] = 0.f;

  for (int k0 = 0; k0 < F_IN; k0 += 32) {
    __syncthreads();
#pragma unroll
    for (int i = 0; i < 2; ++i) {
      int v = tid + i * 256;
      int r = v >> 3, kk = (v & 7) * 4;
      float4 x = *(const float4*)&X[(size_t)(r0 + r) * F_IN + k0 + kk];
      Xs[kk + 0][r] = x.x; Xs[kk + 1][r] = x.y;
      Xs[kk + 2][r] = x.z; Xs[kk + 3][r] = x.w;
      int kw = v >> 4, cc = (v & 15) * 4;
      *(float4*)&Ws[kw][cc] =
          *(const float4*)&W[(size_t)(k0 + kw) * HD + h * 64 + cc];
    }
    __syncthreads();
#pragma unroll
    for (int k = 0; k < 32; ++k) {
      float4 a4 = *(const float4*)&Xs[k][ty * 4];
      float4 b4 = *(const float4*)&Ws[k][tx * 4];
      float av[4] = {a4.x, a4.y, a4.z, a4.w};
      float bv[4] = {b4.x, b4.y, b4.z, b4.w};
#pragma unroll
      for (int i = 0; i < 4; ++i)
#pragma unroll
        for (int j = 0; j < 4; ++j)
          acc[i][j] = fmaf(av[i], bv[j], acc[i][j]);
    }
  }

  __syncthreads();
#pragma unroll
  for (int i = 0; i < 4; ++i)
#pragma unroll
    for (int j = 0; j < 4; ++j)
      T[tx * 4 + j][ty * 4 + i] = acc[i][j];
  __syncthreads();

  // bf16 tiled transposed write: htT2[h][mblk][d][m%32]
  {
    int d = tid >> 2, mq = tid & 3;
    s16x8 o0, o1;
#pragma unroll
    for (int k = 0; k < 8; ++k) o0[k] = (short)f2bf(T[d][mq * 16 + k]);
#pragma unroll
    for (int k = 0; k < 8; ++k) o1[k] = (short)f2bf(T[d][mq * 16 + 8 + k]);
    unsigned short* dst = isNode ? htT_n : htT_e;
    int mb0 = r0 >> 5;
    size_t base = (size_t)h * MT * 2048 + (size_t)(mb0 + (mq >> 1)) * 2048
                + d * 32 + (mq & 1) * 16;
    *(s16x8*)&dst[base] = o0;
    *(s16x8*)&dst[base + 8] = o1;
  }

  // score vectors, pre-scaled by LOG2E
  {
    int r = tid >> 2, q4 = tid & 3;
    float tr[16];
#pragma unroll
    for (int k = 0; k < 16; ++k) tr[k] = T[q4 * 16 + k][r];
    if (isNode) {
      float s1 = 0.f, s2 = 0.f, s3 = 0.f;
#pragma unroll
      for (int k = 0; k < 16; ++k) {
        s1 = fmaf(tr[k], aN[h * 128 + q4 * 16 + k], s1);
        s2 = fmaf(tr[k], aN[h * 128 + 64 + q4 * 16 + k], s2);
        s3 = fmaf(tr[k], aE[h * 128 + q4 * 16 + k], s3);
      }
      s1 += __shfl_xor(s1, 1); s1 += __shfl_xor(s1, 2);
      s2 += __shfl_xor(s2, 1); s2 += __shfl_xor(s2, 2);
      s3 += __shfl_xor(s3, 1); s3 += __shfl_xor(s3, 2);
      if (q4 == 0) {
        srcN[h * N_NODES + r0 + r] = s1 * LOG2E;
        tgtN[h * N_NODES + r0 + r] = s2 * LOG2E;
        srcE[h * N_NODES + r0 + r] = s3 * LOG2E;
      }
    } else {
      float s4 = 0.f;
#pragma unroll
      for (int k = 0; k < 16; ++k)
        s4 = fmaf(tr[k], aE[h * 128 + 64 + q4 * 16 + k], s4);
      s4 += __shfl_xor(s4, 1); s4 += __shfl_xor(s4, 2);
      if (q4 == 0) tgtE[h * N_EDGES + r0 + r] = s4 * LOG2E;
    }
  }
}

// ---------------------------------------------------------------------------
// Kernel B2: expify — scores -> factorized exp pairs.
// ---------------------------------------------------------------------------
__global__ __launch_bounds__(256) void expify(
    const float* __restrict__ srcN, const float* __restrict__ tgtN,
    const float* __restrict__ srcE, const float* __restrict__ tgtE,
    float* __restrict__ srcN1, float* __restrict__ srcN2,
    float* __restrict__ tgtN1, float* __restrict__ tgtN2,
    float* __restrict__ srcE1, float* __restrict__ srcE2,
    float* __restrict__ tgtE1, float* __restrict__ tgtE2)
{
  int t = blockIdx.x * 256 + threadIdx.x;   // 81920 threads
  const float* in; float* o1; float* o2; int idx;
  if (t < 16384)      { in = srcN; o1 = srcN1; o2 = srcN2; idx = t; }
  else if (t < 32768) { in = tgtN; o1 = tgtN1; o2 = tgtN2; idx = t - 16384; }
  else if (t < 49152) { in = srcE; o1 = srcE1; o2 = srcE2; idx = t - 32768; }
  else                { in = tgtE; o1 = tgtE1; o2 = tgtE2; idx = t - 49152; }
  float s = in[idx];
  o1[idx] = __builtin_amdgcn_exp2f(s);
  o2[idx] = __builtin_amdgcn_exp2f(0.2f * s);
}

// ---------------------------------------------------------------------------
// Kernel C: main GAT. w = mask & max(E1n*E1m, E2n*E2m) — no exp in loop.
// Block = (32-node tile, head, msplit of 2), **8 waves** (512 thr); wave w
// owns one m-slice of 8. Tiled htT2 layout, 2-stage pipeline.
// ---------------------------------------------------------------------------
struct StepIn {
  unsigned wd00, wd01, wd10, wd11;
  float4 ta1, tb1, tc1, td1;    // E1m at qo, qo+4, 32+qo, 32+qo+4
  float4 ta2, tb2, tc2, td2;    // E2m same offsets
  s16x8 bf0, bf1, bf2, bf3;     // ks=0, dt=0..3
  s16x8 bf4, bf5, bf6, bf7;     // ks=1, dt=0..3
};

template<int REL>
__device__ __forceinline__ StepIn load_step(
    const unsigned* __restrict__ br0, const unsigned* __restrict__ br1,
    const float* __restrict__ t1, const float* __restrict__ t2,
    const unsigned short* __restrict__ hb0,
    const unsigned short* __restrict__ hb1)
{
  StepIn s;
  s.wd00 = br0[REL * 2]; s.wd01 = br0[REL * 2 + 1];
  s.wd10 = br1[REL * 2]; s.wd11 = br1[REL * 2 + 1];
  s.ta1 = *(const float4*)&t1[REL * 64];
  s.tb1 = *(const float4*)&t1[REL * 64 + 4];
  s.tc1 = *(const float4*)&t1[REL * 64 + 32];
  s.td1 = *(const float4*)&t1[REL * 64 + 36];
  s.ta2 = *(const float4*)&t2[REL * 64];
  s.tb2 = *(const float4*)&t2[REL * 64 + 4];
  s.tc2 = *(const float4*)&t2[REL * 64 + 32];
  s.td2 = *(const float4*)&t2[REL * 64 + 36];
  const unsigned short* hb = REL ? hb1 : hb0;
  s.bf0 = *(const s16x8*)&hb[0 * 512];
  s.bf1 = *(const s16x8*)&hb[1 * 512];
  s.bf2 = *(const s16x8*)&hb[2 * 512];
  s.bf3 = *(const s16x8*)&hb[3 * 512];
  s.bf4 = *(const s16x8*)&hb[2048 + 0 * 512];
  s.bf5 = *(const s16x8*)&hb[2048 + 1 * 512];
  s.bf6 = *(const s16x8*)&hb[2048 + 2 * 512];
  s.bf7 = *(const s16x8*)&hb[2048 + 3 * 512];
  return s;
}

__device__ __forceinline__ void compute_step(
    const StepIn& sI, int qo,
    float e1n0, float e2n0, float e1n1, float e2n1, s16x8 ones,
    f32x4 acc[2][4], f32x4 accd[2])
{
  s16x8 afr[2][2];
#pragma unroll
  for (int nt = 0; nt < 2; ++nt) {
    float e1n = nt ? e1n1 : e1n0;
    float e2n = nt ? e2n1 : e2n0;
#pragma unroll
    for (int ks = 0; ks < 2; ++ks) {
      unsigned wdw = nt ? (ks ? sI.wd11 : sI.wd10) : (ks ? sI.wd01 : sI.wd00);
      unsigned wq = wdw >> qo;
      float4 u1 = ks ? sI.tc1 : sI.ta1;
      float4 v1 = ks ? sI.td1 : sI.tb1;
      float4 u2 = ks ? sI.tc2 : sI.ta2;
      float4 v2 = ks ? sI.td2 : sI.tb2;
      float m1[8] = {u1.x, u1.y, u1.z, u1.w, v1.x, v1.y, v1.z, v1.w};
      float m2[8] = {u2.x, u2.y, u2.z, u2.w, v2.x, v2.y, v2.z, v2.w};
      float wv[8];
#pragma unroll
      for (int j = 0; j < 8; ++j) {
        float p1 = e1n * m1[j];
        float p2 = e2n * m2[j];
        float mx = fmaxf(p1, p2);               // = exp(lrelu(e)) by monotonicity
        int msk = -(int)((wq >> j) & 1u);       // 0 or 0xFFFFFFFF (portable)
        wv[j] = __int_as_float(msk & __float_as_int(mx));
      }
      u32x4 p;
      p[0] = cvtpk(wv[0], wv[1]);
      p[1] = cvtpk(wv[2], wv[3]);
      p[2] = cvtpk(wv[4], wv[5]);
      p[3] = cvtpk(wv[6], wv[7]);
      afr[nt][ks] = __builtin_bit_cast(s16x8, p);
    }
  }
  acc[0][0] = __builtin_amdgcn_mfma_f32_16x16x32_bf16(afr[0][0], sI.bf0, acc[0][0], 0, 0, 0);
  acc[0][1] = __builtin_amdgcn_mfma_f32_16x16x32_bf16(afr[0][0], sI.bf1, acc[0][1], 0, 0, 0);
  acc[0][2] = __builtin_amdgcn_mfma_f32_16x16x32_bf16(afr[0][0], sI.bf2, acc[0][2], 0, 0, 0);
  acc[0][3] = __builtin_amdgcn_mfma_f32_16x16x32_bf16(afr[0][0], sI.bf3, acc[0][3], 0, 0, 0);
  accd[0]   = __builtin_amdgcn_mfma_f32_16x16x32_bf16(afr[0][0], ones,   accd[0],   0, 0, 0);
  acc[1][0] = __builtin_amdgcn_mfma_f32_16x16x32_bf16(afr[1][0], sI.bf0, acc[1][0], 0, 0, 0);
  acc[1][1] = __builtin_amdgcn_mfma_f32_16x16x32_bf16(afr[1][0], sI.bf1, acc[1][1], 0, 0, 0);
  acc[1][2] = __builtin_amdgcn_mfma_f32_16x16x32_bf16(afr[1][0], sI.bf2, acc[1][2], 0, 0, 0);
  acc[1][3] = __builtin_amdgcn_mfma_f32_16x16x32_bf16(afr[1][0], sI.bf3, acc[1][3], 0, 0, 0);
  accd[1]   = __builtin_amdgcn_mfma_f32_16x16x32_bf16(afr[1][0], ones,   accd[1],   0, 0, 0);
  acc[0][0] = __builtin_amdgcn_mfma_f32_16x16x32_bf16(afr[0][1], sI.bf4, acc[0][0], 0, 0, 0);
  acc[0][1] = __builtin_amdgcn_mfma_f32_16x16x32_bf16(afr[0][1], sI.bf5, acc[0][1], 0, 0, 0);
  acc[0][2] = __builtin_amdgcn_mfma_f32_16x16x32_bf16(afr[0][1], sI.bf6, acc[0][2], 0, 0, 0);
  acc[0][3] = __builtin_amdgcn_mfma_f32_16x16x32_bf16(afr[0][1], sI.bf7, acc[0][3], 0, 0, 0);
  accd[0]   = __builtin_amdgcn_mfma_f32_16x16x32_bf16(afr[0][1], ones,   accd[0],   0, 0, 0);
  acc[1][0] = __builtin_amdgcn_mfma_f32_16x16x32_bf16(afr[1][1], sI.bf4, acc[1][0], 0, 0, 0);
  acc[1][1] = __builtin_amdgcn_mfma_f32_16x16x32_bf16(afr[1][1], sI.bf5, acc[1][1], 0, 0, 0);
  acc[1][2] = __builtin_amdgcn_mfma_f32_16x16x32_bf16(afr[1][1], sI.bf6, acc[1][2], 0, 0, 0);
  acc[1][3] = __builtin_amdgcn_mfma_f32_16x16x32_bf16(afr[1][1], sI.bf7, acc[1][3], 0, 0, 0);
  accd[1]   = __builtin_amdgcn_mfma_f32_16x16x32_bf16(afr[1][1], ones,   accd[1],   0, 0, 0);
}

template<int NSTEPS>
__device__ __forceinline__ void gat_part32(
    const unsigned* __restrict__ bits, int MT,
    const float* __restrict__ t1_h, const float* __restrict__ t2_h,
    const unsigned short* __restrict__ htT_h,
    int n0, int m_begin, int r16, int qo,
    float e1n0, float e2n0, float e1n1, float e2n1, s16x8 ones,
    f32x4 acc[2][4], f32x4 accd[2])
{
#pragma unroll
  for (int nt = 0; nt < 2; ++nt) {
    accd[nt] = (f32x4){0.f, 0.f, 0.f, 0.f};
#pragma unroll
    for (int dt = 0; dt < 4; ++dt) acc[nt][dt] = (f32x4){0.f, 0.f, 0.f, 0.f};
  }
  int mb0 = m_begin >> 5;
  const unsigned* br0 = &bits[(size_t)(n0 + r16) * MT + mb0];
  const unsigned* br1 = &bits[(size_t)(n0 + 16 + r16) * MT + mb0];
  const float* t1 = &t1_h[m_begin + qo];
  const float* t2 = &t2_h[m_begin + qo];
  const unsigned short* hb0 = &htT_h[(size_t)mb0 * 2048 + r16 * 32 + qo];
  const unsigned short* hb1 = hb0 + 4096;

  StepIn sA = load_step<0>(br0, br1, t1, t2, hb0, hb1);
#pragma unroll
  for (int st = 0; st < NSTEPS - 2; st += 2) {
    StepIn sB = load_step<1>(br0, br1, t1, t2, hb0, hb1);
    br0 += 4; br1 += 4; t1 += 128; t2 += 128; hb0 += 8192; hb1 += 8192;
    compute_step(sA, qo, e1n0, e2n0, e1n1, e2n1, ones, acc, accd);
    sA = load_step<0>(br0, br1, t1, t2, hb0, hb1);
    compute_step(sB, qo, e1n0, e2n0, e1n1, e2n1, ones, acc, accd);
  }
  StepIn sB = load_step<1>(br0, br1, t1, t2, hb0, hb1);
  compute_step(sA, qo, e1n0, e2n0, e1n1, e2n1, ones, acc, accd);
  compute_step(sB, qo, e1n0, e2n0, e1n1, e2n1, ones, acc, accd);
}

// two-pass (d-half) combine over 8 waves + global store (512 threads)
__device__ __forceinline__ void combine_store8(
    f32x4 acc[2][4], f32x4 accd[2],
    float lnum[8][32][36], float lden[8][32],
    int w, int q, int r16, int tid,
    float* __restrict__ NUM, float* __restrict__ DEN, int sh, int n0)
{
  const int crow = tid >> 4, c2 = (tid & 15) * 2;
#pragma unroll
  for (int pass = 0; pass < 2; ++pass) {
    __syncthreads();
#pragma unroll
    for (int nt = 0; nt < 2; ++nt)
#pragma unroll
      for (int dtl = 0; dtl < 2; ++dtl)
#pragma unroll
        for (int qi = 0; qi < 4; ++qi)
          lnum[w][nt * 16 + q * 4 + qi][dtl * 16 + r16] =
              acc[nt][pass * 2 + dtl][qi];
    if (pass == 0 && r16 == 0) {
#pragma unroll
      for (int nt = 0; nt < 2; ++nt)
#pragma unroll
        for (int qi = 0; qi < 4; ++qi)
          lden[w][nt * 16 + q * 4 + qi] = accd[nt][qi];
    }
    __syncthreads();
    f32x2 s = (f32x2){0.f, 0.f};
#pragma unroll
    for (int ww = 0; ww < 8; ++ww) s += *(const f32x2*)&lnum[ww][crow][c2];
    *(f32x2*)&NUM[((size_t)sh * N_NODES + n0 + crow) * 64 + pass * 32 + c2] = s;
    if (pass == 0 && (tid & 15) == 0) {
      float dsum = 0.f;
#pragma unroll
      for (int ww = 0; ww < 8; ++ww) dsum += lden[ww][crow];
      DEN[(size_t)sh * N_NODES + n0 + crow] = dsum;
    }
  }
}

__global__ __launch_bounds__(512, 4) void gat_main(
    const unsigned short* __restrict__ htT_n, const unsigned short* __restrict__ htT_e,
    const float* __restrict__ srcN1, const float* __restrict__ srcN2,
    const float* __restrict__ tgtN1, const float* __restrict__ tgtN2,
    const float* __restrict__ srcE1, const float* __restrict__ srcE2,
    const float* __restrict__ tgtE1, const float* __restrict__ tgtE2,
    const unsigned* __restrict__ bitsN, const unsigned* __restrict__ bitsE,
    float* __restrict__ NUM_N, float* __restrict__ DEN_N,
    float* __restrict__ NUM_E, float* __restrict__ DEN_E)
{
  const int i = blockIdx.x;                     // 1024 blocks
  const int h = i & 7;
  const int tile = (i >> 3) & 63;
  const int ms = i >> 9;                        // m-split 0/1
  const int n0 = tile * 32;
  const int tid = threadIdx.x, w = tid >> 6, lane = tid & 63;
  const int r16 = lane & 15, q = lane >> 4, qo = q * 8;
  const int sh = ms * 8 + h;

  __shared__ __align__(16) float lnum[8][32][36];   // 36.9 KiB
  __shared__ float lden[8][32];                     // 1 KiB

  s16x8 ones;
#pragma unroll
  for (int j = 0; j < 8; ++j) ones[j] = (short)0x3F80;    // bf16 1.0

  f32x4 acc[2][4], accd[2];

  // ---------------- nodes part: 2 steps/wave ----------------
  {
    float e1n0 = srcN1[h * N_NODES + n0 + r16];
    float e2n0 = srcN2[h * N_NODES + n0 + r16];
    float e1n1 = srcN1[h * N_NODES + n0 + 16 + r16];
    float e2n1 = srcN2[h * N_NODES + n0 + 16 + r16];
    gat_part32<2>(bitsN, N_NODES / 32,
                  tgtN1 + (size_t)h * N_NODES, tgtN2 + (size_t)h * N_NODES,
                  htT_n + (size_t)h * (N_NODES / 32) * 2048,
                  n0, ms * 1024 + w * 128, r16, qo,
                  e1n0, e2n0, e1n1, e2n1, ones, acc, accd);
    combine_store8(acc, accd, lnum, lden, w, q, r16, tid, NUM_N, DEN_N, sh, n0);
  }

  // ---------------- edges part: 4 steps/wave ----------------
  {
    float e1n0 = srcE1[h * N_NODES + n0 + r16];
    float e2n0 = srcE2[h * N_NODES + n0 + r16];
    float e1n1 = srcE1[h * N_NODES + n0 + 16 + r16];
    float e2n1 = srcE2[h * N_NODES + n0 + 16 + r16];
    gat_part32<4>(bitsE, N_EDGES / 32,
                  tgtE1 + (size_t)h * N_EDGES, tgtE2 + (size_t)h * N_EDGES,
                  htT_e + (size_t)h * (N_EDGES / 32) * 2048,
                  n0, ms * 2048 + w * 256, r16, qo,
                  e1n0, e2n0, e1n1, e2n1, ones, acc, accd);
    combine_store8(acc, accd, lnum, lden, w, q, r16, tid, NUM_E, DEN_E, sh, n0);
  }
}

// ---------------------------------------------------------------------------
// Kernel D: combine 2 msplit partials, normalize, mean over heads.
// ---------------------------------------------------------------------------
__global__ __launch_bounds__(256) void reduce_out(
    const float* __restrict__ NUM_N, const float* __restrict__ DEN_N,
    const float* __restrict__ NUM_E, const float* __restrict__ DEN_E,
    float* __restrict__ out)
{
  int idx = blockIdx.x * 256 + threadIdx.x;   // 32768 threads
  int n = idx >> 4, d4 = (idx & 15) * 4;
  f32x4 r = (f32x4){0.f, 0.f, 0.f, 0.f};
#pragma unroll
  for (int h = 0; h < H_HEADS; ++h) {
    f32x4 nn = *(const f32x4*)&NUM_N[((size_t)h * N_NODES + n) * 64 + d4]
             + *(const f32x4*)&NUM_N[((size_t)(8 + h) * N_NODES + n) * 64 + d4];
    float dn = DEN_N[(size_t)h * N_NODES + n] + DEN_N[(size_t)(8 + h) * N_NODES + n];
    f32x4 ne = *(const f32x4*)&NUM_E[((size_t)h * N_NODES + n) * 64 + d4]
             + *(const f32x4*)&NUM_E[((size_t)(8 + h) * N_NODES + n) * 64 + d4];
    float de = DEN_E[(size_t)h * N_NODES + n] + DEN_E[(size_t)(8 + h) * N_NODES + n];
    float idn = 1.0f / dn, ide = 1.0f / de;
    r.x += nn.x * idn + ne.x * ide;
    r.y += nn.y * idn + ne.y * ide;
    r.z += nn.z * idn + ne.z * ide;
    r.w += nn.w * idn + ne.w * ide;
  }
  f32x4 o = (f32x4){r.x * 0.125f, r.y * 0.125f, r.z * 0.125f, r.w * 0.125f};
  *(f32x4*)&out[(size_t)n * 64 + d4] = o;
}

// ---------------------------------------------------------------------------
extern "C" void kernel_launch(void* const* d_in, const int* in_sizes, int n_in,
                              void* d_out, int out_size, void* d_ws, size_t ws_size,
                              hipStream_t stream)
{
  const float* nodes = (const float*)d_in[0];
  const float* edges = (const float*)d_in[1];
  const float* WN    = (const float*)d_in[2];
  const float* WE    = (const float*)d_in[3];
  const float* aN    = (const float*)d_in[4];
  const float* aE    = (const float*)d_in[5];
  const int*   matN  = (const int*)d_in[6];
  const int*   matE  = (const int*)d_in[7];
  float* out = (float*)d_out;

  float* ws = (float*)d_ws;
  size_t o = 0;
  unsigned short* htT_n = (unsigned short*)(ws + o); o += (size_t)H_HEADS * 64 * N_NODES / 2;  // 2MB
  unsigned short* htT_e = (unsigned short*)(ws + o); o += (size_t)H_HEADS * 64 * N_EDGES / 2;  // 4MB
  unsigned* bitsN = (unsigned*)(ws + o); o += (size_t)N_NODES * (N_NODES / 32);                // 512KB
  unsigned* bitsE = (unsigned*)(ws + o); o += (size_t)N_NODES * (N_EDGES / 32);                // 1MB
  float* srcN  = ws + o;  o += (size_t)H_HEADS * N_NODES;
  float* tgtN  = ws + o;  o += (size_t)H_HEADS * N_NODES;
  float* srcE  = ws + o;  o += (size_t)H_HEADS * N_NODES;
  float* tgtE  = ws + o;  o += (size_t)H_HEADS * N_EDGES;
  float* srcN1 = ws + o;  o += (size_t)H_HEADS * N_NODES;
  float* srcN2 = ws + o;  o += (size_t)H_HEADS * N_NODES;
  float* tgtN1 = ws + o;  o += (size_t)H_HEADS * N_NODES;
  float* tgtN2 = ws + o;  o += (size_t)H_HEADS * N_NODES;
  float* srcE1 = ws + o;  o += (size_t)H_HEADS * N_NODES;
  float* srcE2 = ws + o;  o += (size_t)H_HEADS * N_NODES;
  float* tgtE1 = ws + o;  o += (size_t)H_HEADS * N_EDGES;
  float* tgtE2 = ws + o;  o += (size_t)H_HEADS * N_EDGES;
  float* NUM_N = ws + o;  o += (size_t)2 * H_HEADS * N_NODES * 64;   // 8MB
  float* DEN_N = ws + o;  o += (size_t)2 * H_HEADS * N_NODES;
  float* NUM_E = ws + o;  o += (size_t)2 * H_HEADS * N_NODES * 64;   // 8MB
  float* DEN_E = ws + o;  o += (size_t)2 * H_HEADS * N_NODES;

  hipLaunchKernelGGL(pack_masks, dim3(1536), dim3(256), 0, stream,
                     matN, matE, bitsN, bitsE);
  hipLaunchKernelGGL(gemm_fused, dim3(96, 8), dim3(256), 0, stream,
                     nodes, edges, WN, WE, aN, aE,
                     htT_n, htT_e, srcN, tgtN, srcE, tgtE);
  hipLaunchKernelGGL(expify, dim3(320), dim3(256), 0, stream,
                     srcN, tgtN, srcE, tgtE,
                     srcN1, srcN2, tgtN1, tgtN2, srcE1, srcE2, tgtE1, tgtE2);
  hipLaunchKernelGGL(gat_main, dim3(1024), dim3(512), 0, stream,
                     htT_n, htT_e, srcN1, srcN2, tgtN1, tgtN2,
                     srcE1, srcE2, tgtE1, tgtE2, bitsN, bitsE,
                     NUM_N, DEN_N, NUM_E, DEN_E);
  hipLaunchKernelGGL(reduce_out, dim3(128), dim3(256), 0, stream,
                     NUM_N, DEN_N, NUM_E, DEN_E, out);
}

// Round 17
// 101.613 us; speedup vs baseline: 1.0317x; 1.0317x over previous
//
#include <hip/hip_runtime.h>
#include <hip/hip_bf16.h>

#define N_NODES 2048
#define N_EDGES 4096
#define F_IN    256
#define H_HEADS 8
#define HD      512
#define LOG2E   1.44269504088896f

typedef __attribute__((ext_vector_type(4))) float f32x4;
typedef __attribute__((ext_vector_type(8))) short s16x8;
typedef __attribute__((ext_vector_type(4))) unsigned u32x4;

static __device__ __forceinline__ unsigned short f2bf(float x) {
  union { float f; unsigned u; } v; v.f = x;
  unsigned r = v.u + 0x7fff + ((v.u >> 16) & 1);   // RNE
  return (unsigned short)(r >> 16);
}
static __device__ __forceinline__ float bf2f(unsigned short h) {
  union { unsigned u; float f; } v; v.u = ((unsigned)h) << 16;
  return v.f;
}
static __device__ __forceinline__ unsigned cvtpk(float lo, float hi) {
  unsigned r;
  asm("v_cvt_pk_bf16_f32 %0, %1, %2" : "=v"(r) : "v"(lo), "v"(hi));
  return r;
}

// ---------------------------------------------------------------------------
// Kernel A: bit-pack masks along m.  bits[n][m/32], bit j = mat[n][w*32+j].
// ---------------------------------------------------------------------------
__global__ __launch_bounds__(256) void pack_masks(
    const int* __restrict__ matN, const int* __restrict__ matE,
    unsigned* __restrict__ bitsN, unsigned* __restrict__ bitsE)
{
  int t = blockIdx.x * 256 + threadIdx.x;      // 393216 threads
  const int* src; unsigned* dst;
  if (t < N_NODES * (N_NODES / 32)) {
    int row = t >> 6, w = t & 63;
    src = &matN[(size_t)row * N_NODES + w * 32]; dst = &bitsN[t];
  } else {
    int tt = t - N_NODES * (N_NODES / 32);
    int row = tt >> 7, w = tt & 127;
    src = &matE[(size_t)row * N_EDGES + w * 32]; dst = &bitsE[tt];
  }
  unsigned b = 0;
#pragma unroll
  for (int k = 7; k >= 0; --k) {
    int4 v = *(const int4*)&src[k * 4];
    b = (b << 1) | ((unsigned)v.w & 1u);
    b = (b << 1) | ((unsigned)v.z & 1u);
    b = (b << 1) | ((unsigned)v.y & 1u);
    b = (b << 1) | ((unsigned)v.x & 1u);
  }
  *dst = b;
}

// ---------------------------------------------------------------------------
// Kernel A2: prep — split X into hi/lo bf16 (coalesced); W: LDS-tiled
// transpose+split -> Wt[mat][c][k] (coalesced both sides).
// Blocks 0..767: X.  Blocks 768..831: W 64x64 tiles (2 mats x 8 c x 4 k).
// ---------------------------------------------------------------------------
__global__ __launch_bounds__(256) void prep(
    const float* __restrict__ nodes, const float* __restrict__ edges,
    const float* __restrict__ WN, const float* __restrict__ WE,
    unsigned short* __restrict__ Xhi, unsigned short* __restrict__ Xlo,
    unsigned short* __restrict__ Wthi, unsigned short* __restrict__ Wtlo)
{
  __shared__ __align__(16) float Tw[64][68];   // [k_local][c_local]
  int b = blockIdx.x;
  if (b < 768) {                               // X split: 8 elems/thread
    int base = (b * 256 + threadIdx.x) * 8;
    const float* src = (base < N_NODES * F_IN)
                     ? nodes + base : edges + (base - N_NODES * F_IN);
    float4 a = *(const float4*)src;
    float4 c = *(const float4*)(src + 4);
    float v[8] = {a.x, a.y, a.z, a.w, c.x, c.y, c.z, c.w};
    s16x8 hi, lo;
#pragma unroll
    for (int j = 0; j < 8; ++j) {
      unsigned short h = f2bf(v[j]);
      hi[j] = (short)h;
      lo[j] = (short)f2bf(v[j] - bf2f(h));
    }
    *(s16x8*)&Xhi[base] = hi;
    *(s16x8*)&Xlo[base] = lo;
  } else {
    int b2 = b - 768;                          // 0..63
    int mat = b2 >> 5, rem = b2 & 31;
    int c0 = (rem >> 2) * 64, k0 = (rem & 3) * 64;
    const float* W = mat ? WE : WN;
    int t = threadIdx.x;
#pragma unroll
    for (int i = 0; i < 4; ++i) {
      int v = t + i * 256;                     // 0..1023
      int kr = v >> 4, cq = (v & 15) * 4;
      float4 x = *(const float4*)&W[(size_t)(k0 + kr) * HD + c0 + cq];
      Tw[kr][cq + 0] = x.x; Tw[kr][cq + 1] = x.y;
      Tw[kr][cq + 2] = x.z; Tw[kr][cq + 3] = x.w;
    }
    __syncthreads();
    int c = t >> 2, kq = (t & 3) * 16;
    s16x8 hi0, lo0, hi1, lo1;
#pragma unroll
    for (int j = 0; j < 8; ++j) {
      float v0 = Tw[kq + j][c];
      unsigned short h0 = f2bf(v0);
      hi0[j] = (short)h0; lo0[j] = (short)f2bf(v0 - bf2f(h0));
      float v1 = Tw[kq + 8 + j][c];
      unsigned short h1 = f2bf(v1);
      hi1[j] = (short)h1; lo1[j] = (short)f2bf(v1 - bf2f(h1));
    }
    size_t ob = ((size_t)mat * 512 + c0 + c) * 256 + k0 + kq;
    *(s16x8*)&Wthi[ob] = hi0;     *(s16x8*)&Wthi[ob + 8] = hi1;
    *(s16x8*)&Wtlo[ob] = lo0;     *(s16x8*)&Wtlo[ob + 8] = lo1;
  }
}

// ---------------------------------------------------------------------------
// Kernel B: MFMA ht-GEMM (split-bf16 x3, pure-register; R12-proven) +
// bf16 tiled transpose-out + score vectors (xLOG2E).
// ---------------------------------------------------------------------------
__global__ __launch_bounds__(256) void gemm_fused(
    const unsigned short* __restrict__ Xhi, const unsigned short* __restrict__ Xlo,
    const unsigned short* __restrict__ Wthi, const unsigned short* __restrict__ Wtlo,
    const float* __restrict__ aN, const float* __restrict__ aE,
    unsigned short* __restrict__ htT_n, unsigned short* __restrict__ htT_e,
    float* __restrict__ srcN, float* __restrict__ tgtN,
    float* __restrict__ srcE, float* __restrict__ tgtE)
{
  const int rt = blockIdx.x;   // 0..31 nodes, 32..95 edges
  const int h  = blockIdx.y;   // head
  const bool isNode = (rt < 32);
  const int r0 = (isNode ? rt : rt - 32) * 64;
  const int rowg = (isNode ? 0 : N_NODES) + r0;
  const int MT = (isNode ? N_NODES : N_EDGES) / 32;

  __shared__ __align__(16) float T[64][68];    // T[d][m_local]

  const int tid = threadIdx.x;
  const int w = tid >> 6, l = tid & 63;
  const int r16 = l & 15, q8 = (l >> 4) * 8;

  const unsigned short* Ah = &Xhi[(size_t)(rowg + 16 * w + r16) * 256 + q8];
  const unsigned short* Al = &Xlo[(size_t)(rowg + 16 * w + r16) * 256 + q8];
  size_t wb = ((size_t)(isNode ? 0 : 1) * 512 + h * 64 + r16) * 256 + q8;
  const unsigned short* WH = &Wthi[wb];
  const unsigned short* WL = &Wtlo[wb];

  f32x4 acc[4];
#pragma unroll
  for (int dt = 0; dt < 4; ++dt) acc[dt] = (f32x4){0.f, 0.f, 0.f, 0.f};

#pragma unroll
  for (int ks = 0; ks < 8; ++ks) {
    int ko = ks * 32;
    s16x8 ahi = *(const s16x8*)&Ah[ko];
    s16x8 alo = *(const s16x8*)&Al[ko];
#pragma unroll
    for (int dt = 0; dt < 4; ++dt) {
      s16x8 bhi = *(const s16x8*)&WH[dt * 4096 + ko];
      s16x8 blo = *(const s16x8*)&WL[dt * 4096 + ko];
      acc[dt] = __builtin_amdgcn_mfma_f32_16x16x32_bf16(ahi, bhi, acc[dt], 0, 0, 0);
      acc[dt] = __builtin_amdgcn_mfma_f32_16x16x32_bf16(ahi, blo, acc[dt], 0, 0, 0);
      acc[dt] = __builtin_amdgcn_mfma_f32_16x16x32_bf16(alo, bhi, acc[dt], 0, 0, 0);
    }
  }

  // C[m_local = 16w + (l>>4)*4 + reg][d = dt*16 + r16] -> T[d][m_local]
#pragma unroll
  for (int dt = 0; dt < 4; ++dt)
#pragma unroll
    for (int reg = 0; reg < 4; ++reg)
      T[dt * 16 + r16][16 * w + (l >> 4) * 4 + reg] = acc[dt][reg];
  __syncthreads();

  // bf16 tiled transposed write: htT2[h][mblk][d][m%32]
  {
    int d = tid >> 2, mq = tid & 3;
    s16x8 o0, o1;
#pragma unroll
    for (int k = 0; k < 8; ++k) o0[k] = (short)f2bf(T[d][mq * 16 + k]);
#pragma unroll
    for (int k = 0; k < 8; ++k) o1[k] = (short)f2bf(T[d][mq * 16 + 8 + k]);
    unsigned short* dst = isNode ? htT_n : htT_e;
    int mb0 = r0 >> 5;
    size_t base = (size_t)h * MT * 2048 + (size_t)(mb0 + (mq >> 1)) * 2048
                + d * 32 + (mq & 1) * 16;
    *(s16x8*)&dst[base] = o0;
    *(s16x8*)&dst[base + 8] = o1;
  }

  // score vectors, pre-scaled by LOG2E
  {
    int r = tid >> 2, q4 = tid & 3;
    float tr[16];
#pragma unroll
    for (int k = 0; k < 16; ++k) tr[k] = T[q4 * 16 + k][r];
    if (isNode) {
      float s1 = 0.f, s2 = 0.f, s3 = 0.f;
#pragma unroll
      for (int k = 0; k < 16; ++k) {
        s1 = fmaf(tr[k], aN[h * 128 + q4 * 16 + k], s1);
        s2 = fmaf(tr[k], aN[h * 128 + 64 + q4 * 16 + k], s2);
        s3 = fmaf(tr[k], aE[h * 128 + q4 * 16 + k], s3);
      }
      s1 += __shfl_xor(s1, 1); s1 += __shfl_xor(s1, 2);
      s2 += __shfl_xor(s2, 1); s2 += __shfl_xor(s2, 2);
      s3 += __shfl_xor(s3, 1); s3 += __shfl_xor(s3, 2);
      if (q4 == 0) {
        srcN[h * N_NODES + r0 + r] = s1 * LOG2E;
        tgtN[h * N_NODES + r0 + r] = s2 * LOG2E;
        srcE[h * N_NODES + r0 + r] = s3 * LOG2E;
      }
    } else {
      float s4 = 0.f;
#pragma unroll
      for (int k = 0; k < 16; ++k)
        s4 = fmaf(tr[k], aE[h * 128 + 64 + q4 * 16 + k], s4);
      s4 += __shfl_xor(s4, 1); s4 += __shfl_xor(s4, 2);
      if (q4 == 0) tgtE[h * N_EDGES + r0 + r] = s4 * LOG2E;
    }
  }
}

// ---------------------------------------------------------------------------
// Kernel B2: expify — scores -> factorized exp pairs.
// ---------------------------------------------------------------------------
__global__ __launch_bounds__(256) void expify(
    const float* __restrict__ srcN, const float* __restrict__ tgtN,
    const float* __restrict__ srcE, const float* __restrict__ tgtE,
    float* __restrict__ srcN1, float* __restrict__ srcN2,
    float* __restrict__ tgtN1, float* __restrict__ tgtN2,
    float* __restrict__ srcE1, float* __restrict__ srcE2,
    float* __restrict__ tgtE1, float* __restrict__ tgtE2)
{
  int t = blockIdx.x * 256 + threadIdx.x;   // 81920 threads
  const float* in; float* o1; float* o2; int idx;
  if (t < 16384)      { in = srcN; o1 = srcN1; o2 = srcN2; idx = t; }
  else if (t < 32768) { in = tgtN; o1 = tgtN1; o2 = tgtN2; idx = t - 16384; }
  else if (t < 49152) { in = srcE; o1 = srcE1; o2 = srcE2; idx = t - 32768; }
  else                { in = tgtE; o1 = tgtE1; o2 = tgtE2; idx = t - 49152; }
  float s = in[idx];
  o1[idx] = __builtin_amdgcn_exp2f(s);
  o2[idx] = __builtin_amdgcn_exp2f(0.2f * s);
}

// ---------------------------------------------------------------------------
// Kernel C: main GAT (R14 exact). w = mask & max(E1n*E1m, E2n*E2m).
// ---------------------------------------------------------------------------
struct StepIn {
  unsigned wd00, wd01, wd10, wd11;
  float4 ta1, tb1, tc1, td1;    // E1m at qo, qo+4, 32+qo, 32+qo+4
  float4 ta2, tb2, tc2, td2;    // E2m same offsets
  s16x8 bf0, bf1, bf2, bf3;     // ks=0, dt=0..3
  s16x8 bf4, bf5, bf6, bf7;     // ks=1, dt=0..3
};

template<int REL>
__device__ __forceinline__ StepIn load_step(
    const unsigned* __restrict__ br0, const unsigned* __restrict__ br1,
    const float* __restrict__ t1, const float* __restrict__ t2,
    const unsigned short* __restrict__ hb0,
    const unsigned short* __restrict__ hb1)
{
  StepIn s;
  s.wd00 = br0[REL * 2]; s.wd01 = br0[REL * 2 + 1];
  s.wd10 = br1[REL * 2]; s.wd11 = br1[REL * 2 + 1];
  s.ta1 = *(const float4*)&t1[REL * 64];
  s.tb1 = *(const float4*)&t1[REL * 64 + 4];
  s.tc1 = *(const float4*)&t1[REL * 64 + 32];
  s.td1 = *(const float4*)&t1[REL * 64 + 36];
  s.ta2 = *(const float4*)&t2[REL * 64];
  s.tb2 = *(const float4*)&t2[REL * 64 + 4];
  s.tc2 = *(const float4*)&t2[REL * 64 + 32];
  s.td2 = *(const float4*)&t2[REL * 64 + 36];
  const unsigned short* hb = REL ? hb1 : hb0;
  s.bf0 = *(const s16x8*)&hb[0 * 512];
  s.bf1 = *(const s16x8*)&hb[1 * 512];
  s.bf2 = *(const s16x8*)&hb[2 * 512];
  s.bf3 = *(const s16x8*)&hb[3 * 512];
  s.bf4 = *(const s16x8*)&hb[2048 + 0 * 512];
  s.bf5 = *(const s16x8*)&hb[2048 + 1 * 512];
  s.bf6 = *(const s16x8*)&hb[2048 + 2 * 512];
  s.bf7 = *(const s16x8*)&hb[2048 + 3 * 512];
  return s;
}

__device__ __forceinline__ void compute_step(
    const StepIn& sI, int qo,
    float e1n0, float e2n0, float e1n1, float e2n1, s16x8 ones,
    f32x4 acc[2][4], f32x4 accd[2])
{
  s16x8 afr[2][2];
#pragma unroll
  for (int nt = 0; nt < 2; ++nt) {
    float e1n = nt ? e1n1 : e1n0;
    float e2n = nt ? e2n1 : e2n0;
#pragma unroll
    for (int ks = 0; ks < 2; ++ks) {
      unsigned wdw = nt ? (ks ? sI.wd11 : sI.wd10) : (ks ? sI.wd01 : sI.wd00);
      unsigned wq = wdw >> qo;
      float4 u1 = ks ? sI.tc1 : sI.ta1;
      float4 v1 = ks ? sI.td1 : sI.tb1;
      float4 u2 = ks ? sI.tc2 : sI.ta2;
      float4 v2 = ks ? sI.td2 : sI.tb2;
      float m1[8] = {u1.x, u1.y, u1.z, u1.w, v1.x, v1.y, v1.z, v1.w};
      float m2[8] = {u2.x, u2.y, u2.z, u2.w, v2.x, v2.y, v2.z, v2.w};
      float wv[8];
#pragma unroll
      for (int j = 0; j < 8; ++j) {
        float p1 = e1n * m1[j];
        float p2 = e2n * m2[j];
        float mx = fmaxf(p1, p2);               // = exp(lrelu(e)) by monotonicity
        int msk = -(int)((wq >> j) & 1u);       // 0 or 0xFFFFFFFF (portable)
        wv[j] = __int_as_float(msk & __float_as_int(mx));
      }
      u32x4 p;
      p[0] = cvtpk(wv[0], wv[1]);
      p[1] = cvtpk(wv[2], wv[3]);
      p[2] = cvtpk(wv[4], wv[5]);
      p[3] = cvtpk(wv[6], wv[7]);
      afr[nt][ks] = __builtin_bit_cast(s16x8, p);
    }
  }
  acc[0][0] = __builtin_amdgcn_mfma_f32_16x16x32_bf16(afr[0][0], sI.bf0, acc[0][0], 0, 0, 0);
  acc[0][1] = __builtin_amdgcn_mfma_f32_16x16x32_bf16(afr[0][0], sI.bf1, acc[0][1], 0, 0, 0);
  acc[0][2] = __builtin_amdgcn_mfma_f32_16x16x32_bf16(afr[0][0], sI.bf2, acc[0][2], 0, 0, 0);
  acc[0][3] = __builtin_amdgcn_mfma_f32_16x16x32_bf16(afr[0][0], sI.bf3, acc[0][3], 0, 0, 0);
  accd[0]   = __builtin_amdgcn_mfma_f32_16x16x32_bf16(afr[0][0], ones,   accd[0],   0, 0, 0);
  acc[1][0] = __builtin_amdgcn_mfma_f32_16x16x32_bf16(afr[1][0], sI.bf0, acc[1][0], 0, 0, 0);
  acc[1][1] = __builtin_amdgcn_mfma_f32_16x16x32_bf16(afr[1][0], sI.bf1, acc[1][1], 0, 0, 0);
  acc[1][2] = __builtin_amdgcn_mfma_f32_16x16x32_bf16(afr[1][0], sI.bf2, acc[1][2], 0, 0, 0);
  acc[1][3] = __builtin_amdgcn_mfma_f32_16x16x32_bf16(afr[1][0], sI.bf3, acc[1][3], 0, 0, 0);
  accd[1]   = __builtin_amdgcn_mfma_f32_16x16x32_bf16(afr[1][0], ones,   accd[1],   0, 0, 0);
  acc[0][0] = __builtin_amdgcn_mfma_f32_16x16x32_bf16(afr[0][1], sI.bf4, acc[0][0], 0, 0, 0);
  acc[0][1] = __builtin_amdgcn_mfma_f32_16x16x32_bf16(afr[0][1], sI.bf5, acc[0][1], 0, 0, 0);
  acc[0][2] = __builtin_amdgcn_mfma_f32_16x16x32_bf16(afr[0][1], sI.bf6, acc[0][2], 0, 0, 0);
  acc[0][3] = __builtin_amdgcn_mfma_f32_16x16x32_bf16(afr[0][1], sI.bf7, acc[0][3], 0, 0, 0);
  accd[0]   = __builtin_amdgcn_mfma_f32_16x16x32_bf16(afr[0][1], ones,   accd[0],   0, 0, 0);
  acc[1][0] = __builtin_amdgcn_mfma_f32_16x16x32_bf16(afr[1][1], sI.bf4, acc[1][0], 0, 0, 0);
  acc[1][1] = __builtin_amdgcn_mfma_f32_16x16x32_bf16(afr[1][1], sI.bf5, acc[1][1], 0, 0, 0);
  acc[1][2] = __builtin_amdgcn_mfma_f32_16x16x32_bf16(afr[1][1], sI.bf6, acc[1][2], 0, 0, 0);
  acc[1][3] = __builtin_amdgcn_mfma_f32_16x16x32_bf16(afr[1][1], sI.bf7, acc[1][3], 0, 0, 0);
  accd[1]   = __builtin_amdgcn_mfma_f32_16x16x32_bf16(afr[1][1], ones,   accd[1],   0, 0, 0);
}

template<int NSTEPS>
__device__ __forceinline__ void gat_part32(
    const unsigned* __restrict__ bits, int MT,
    const float* __restrict__ t1_h, const float* __restrict__ t2_h,
    const unsigned short* __restrict__ htT_h,
    int n0, int m_begin, int r16, int qo,
    float e1n0, float e2n0, float e1n1, float e2n1, s16x8 ones,
    f32x4 acc[2][4], f32x4 accd[2])
{
#pragma unroll
  for (int nt = 0; nt < 2; ++nt) {
    accd[nt] = (f32x4){0.f, 0.f, 0.f, 0.f};
#pragma unroll
    for (int dt = 0; dt < 4; ++dt) acc[nt][dt] = (f32x4){0.f, 0.f, 0.f, 0.f};
  }
  int mb0 = m_begin >> 5;
  const unsigned* br0 = &bits[(size_t)(n0 + r16) * MT + mb0];
  const unsigned* br1 = &bits[(size_t)(n0 + 16 + r16) * MT + mb0];
  const float* t1 = &t1_h[m_begin + qo];
  const float* t2 = &t2_h[m_begin + qo];
  const unsigned short* hb0 = &htT_h[(size_t)mb0 * 2048 + r16 * 32 + qo];
  const unsigned short* hb1 = hb0 + 4096;

  StepIn sA = load_step<0>(br0, br1, t1, t2, hb0, hb1);
#pragma unroll
  for (int st = 0; st < NSTEPS - 2; st += 2) {
    StepIn sB = load_step<1>(br0, br1, t1, t2, hb0, hb1);
    br0 += 4; br1 += 4; t1 += 128; t2 += 128; hb0 += 8192; hb1 += 8192;
    compute_step(sA, qo, e1n0, e2n0, e1n1, e2n1, ones, acc, accd);
    sA = load_step<0>(br0, br1, t1, t2, hb0, hb1);
    compute_step(sB, qo, e1n0, e2n0, e1n1, e2n1, ones, acc, accd);
  }
  StepIn sB = load_step<1>(br0, br1, t1, t2, hb0, hb1);
  compute_step(sA, qo, e1n0, e2n0, e1n1, e2n1, ones, acc, accd);
  compute_step(sB, qo, e1n0, e2n0, e1n1, e2n1, ones, acc, accd);
}

// two-pass (d-half) combine + global store
__device__ __forceinline__ void combine_store(
    f32x4 acc[2][4], f32x4 accd[2],
    float lnum[4][32][36], float lden[4][32],
    int w, int q, int r16, int tid,
    float* __restrict__ NUM, float* __restrict__ DEN, int sh, int n0)
{
  const int crow = tid >> 3, cd4 = (tid & 7) * 4;
#pragma unroll
  for (int pass = 0; pass < 2; ++pass) {
    __syncthreads();
#pragma unroll
    for (int nt = 0; nt < 2; ++nt)
#pragma unroll
      for (int dtl = 0; dtl < 2; ++dtl)
#pragma unroll
        for (int qi = 0; qi < 4; ++qi)
          lnum[w][nt * 16 + q * 4 + qi][dtl * 16 + r16] =
              acc[nt][pass * 2 + dtl][qi];
    if (pass == 0 && r16 == 0) {
#pragma unroll
      for (int nt = 0; nt < 2; ++nt)
#pragma unroll
        for (int qi = 0; qi < 4; ++qi)
          lden[w][nt * 16 + q * 4 + qi] = accd[nt][qi];
    }
    __syncthreads();
    f32x4 s = (f32x4){0.f, 0.f, 0.f, 0.f};
#pragma unroll
    for (int ww = 0; ww < 4; ++ww) s += *(const f32x4*)&lnum[ww][crow][cd4];
    *(f32x4*)&NUM[((size_t)sh * N_NODES + n0 + crow) * 64 + pass * 32 + cd4] = s;
    if (pass == 0 && (tid & 7) == 0) {
      float dsum = lden[0][crow] + lden[1][crow] + lden[2][crow] + lden[3][crow];
      DEN[(size_t)sh * N_NODES + n0 + crow] = dsum;
    }
  }
}

__global__ __launch_bounds__(256, 2) void gat_main(
    const unsigned short* __restrict__ htT_n, const unsigned short* __restrict__ htT_e,
    const float* __restrict__ srcN1, const float* __restrict__ srcN2,
    const float* __restrict__ tgtN1, const float* __restrict__ tgtN2,
    const float* __restrict__ srcE1, const float* __restrict__ srcE2,
    const float* __restrict__ tgtE1, const float* __restrict__ tgtE2,
    const unsigned* __restrict__ bitsN, const unsigned* __restrict__ bitsE,
    float* __restrict__ NUM_N, float* __restrict__ DEN_N,
    float* __restrict__ NUM_E, float* __restrict__ DEN_E)
{
  const int i = blockIdx.x;                     // 1024 blocks
  const int h = i & 7;
  const int tile = (i >> 3) & 63;
  const int ms = i >> 9;                        // m-split 0/1
  const int n0 = tile * 32;
  const int tid = threadIdx.x, w = tid >> 6, lane = tid & 63;
  const int r16 = lane & 15, q = lane >> 4, qo = q * 8;
  const int sh = ms * 8 + h;

  __shared__ __align__(16) float lnum[4][32][36];
  __shared__ float lden[4][32];

  s16x8 ones;
#pragma unroll
  for (int j = 0; j < 8; ++j) ones[j] = (short)0x3F80;    // bf16 1.0

  f32x4 acc[2][4], accd[2];

  // ---------------- nodes part: 4 steps ----------------
  {
    float e1n0 = srcN1[h * N_NODES + n0 + r16];
    float e2n0 = srcN2[h * N_NODES + n0 + r16];
    float e1n1 = srcN1[h * N_NODES + n0 + 16 + r16];
    float e2n1 = srcN2[h * N_NODES + n0 + 16 + r16];
    gat_part32<4>(bitsN, N_NODES / 32,
                  tgtN1 + (size_t)h * N_NODES, tgtN2 + (size_t)h * N_NODES,
                  htT_n + (size_t)h * (N_NODES / 32) * 2048,
                  n0, ms * 1024 + w * 256, r16, qo,
                  e1n0, e2n0, e1n1, e2n1, ones, acc, accd);
    combine_store(acc, accd, lnum, lden, w, q, r16, tid, NUM_N, DEN_N, sh, n0);
  }

  // ---------------- edges part: 8 steps ----------------
  {
    float e1n0 = srcE1[h * N_NODES + n0 + r16];
    float e2n0 = srcE2[h * N_NODES + n0 + r16];
    float e1n1 = srcE1[h * N_NODES + n0 + 16 + r16];
    float e2n1 = srcE2[h * N_NODES + n0 + 16 + r16];
    gat_part32<8>(bitsE, N_EDGES / 32,
                  tgtE1 + (size_t)h * N_EDGES, tgtE2 + (size_t)h * N_EDGES,
                  htT_e + (size_t)h * (N_EDGES / 32) * 2048,
                  n0, ms * 2048 + w * 512, r16, qo,
                  e1n0, e2n0, e1n1, e2n1, ones, acc, accd);
    combine_store(acc, accd, lnum, lden, w, q, r16, tid, NUM_E, DEN_E, sh, n0);
  }
}

// ---------------------------------------------------------------------------
// Kernel D: combine 2 msplit partials, normalize, mean over heads.
// ---------------------------------------------------------------------------
__global__ __launch_bounds__(256) void reduce_out(
    const float* __restrict__ NUM_N, const float* __restrict__ DEN_N,
    const float* __restrict__ NUM_E, const float* __restrict__ DEN_E,
    float* __restrict__ out)
{
  int idx = blockIdx.x * 256 + threadIdx.x;   // 32768 threads
  int n = idx >> 4, d4 = (idx & 15) * 4;
  f32x4 r = (f32x4){0.f, 0.f, 0.f, 0.f};
#pragma unroll
  for (int h = 0; h < H_HEADS; ++h) {
    f32x4 nn = *(const f32x4*)&NUM_N[((size_t)h * N_NODES + n) * 64 + d4]
             + *(const f32x4*)&NUM_N[((size_t)(8 + h) * N_NODES + n) * 64 + d4];
    float dn = DEN_N[(size_t)h * N_NODES + n] + DEN_N[(size_t)(8 + h) * N_NODES + n];
    f32x4 ne = *(const f32x4*)&NUM_E[((size_t)h * N_NODES + n) * 64 + d4]
             + *(const f32x4*)&NUM_E[((size_t)(8 + h) * N_NODES + n) * 64 + d4];
    float de = DEN_E[(size_t)h * N_NODES + n] + DEN_E[(size_t)(8 + h) * N_NODES + n];
    float idn = 1.0f / dn, ide = 1.0f / de;
    r.x += nn.x * idn + ne.x * ide;
    r.y += nn.y * idn + ne.y * ide;
    r.z += nn.z * idn + ne.z * ide;
    r.w += nn.w * idn + ne.w * ide;
  }
  f32x4 o = (f32x4){r.x * 0.125f, r.y * 0.125f, r.z * 0.125f, r.w * 0.125f};
  *(f32x4*)&out[(size_t)n * 64 + d4] = o;
}

// ---------------------------------------------------------------------------
extern "C" void kernel_launch(void* const* d_in, const int* in_sizes, int n_in,
                              void* d_out, int out_size, void* d_ws, size_t ws_size,
                              hipStream_t stream)
{
  const float* nodes = (const float*)d_in[0];
  const float* edges = (const float*)d_in[1];
  const float* WN    = (const float*)d_in[2];
  const float* WE    = (const float*)d_in[3];
  const float* aN    = (const float*)d_in[4];
  const float* aE    = (const float*)d_in[5];
  const int*   matN  = (const int*)d_in[6];
  const int*   matE  = (const int*)d_in[7];
  float* out = (float*)d_out;

  float* ws = (float*)d_ws;
  size_t o = 0;
  unsigned short* htT_n = (unsigned short*)(ws + o); o += (size_t)H_HEADS * 64 * N_NODES / 2;  // 2MB
  unsigned short* htT_e = (unsigned short*)(ws + o); o += (size_t)H_HEADS * 64 * N_EDGES / 2;  // 4MB
  unsigned* bitsN = (unsigned*)(ws + o); o += (size_t)N_NODES * (N_NODES / 32);                // 512KB
  unsigned* bitsE = (unsigned*)(ws + o); o += (size_t)N_NODES * (N_EDGES / 32);                // 1MB
  unsigned short* Xhi = (unsigned short*)(ws + o); o += (size_t)6144 * 256 / 2;                // 3MB
  unsigned short* Xlo = (unsigned short*)(ws + o); o += (size_t)6144 * 256 / 2;                // 3MB
  unsigned short* Wthi = (unsigned short*)(ws + o); o += (size_t)2 * 512 * 256 / 2;            // 512KB
  unsigned short* Wtlo = (unsigned short*)(ws + o); o += (size_t)2 * 512 * 256 / 2;            // 512KB
  float* srcN  = ws + o;  o += (size_t)H_HEADS * N_NODES;
  float* tgtN  = ws + o;  o += (size_t)H_HEADS * N_NODES;
  float* srcE  = ws + o;  o += (size_t)H_HEADS * N_NODES;
  float* tgtE  = ws + o;  o += (size_t)H_HEADS * N_EDGES;
  float* srcN1 = ws + o;  o += (size_t)H_HEADS * N_NODES;
  float* srcN2 = ws + o;  o += (size_t)H_HEADS * N_NODES;
  float* tgtN1 = ws + o;  o += (size_t)H_HEADS * N_NODES;
  float* tgtN2 = ws + o;  o += (size_t)H_HEADS * N_NODES;
  float* srcE1 = ws + o;  o += (size_t)H_HEADS * N_NODES;
  float* srcE2 = ws + o;  o += (size_t)H_HEADS * N_NODES;
  float* tgtE1 = ws + o;  o += (size_t)H_HEADS * N_EDGES;
  float* tgtE2 = ws + o;  o += (size_t)H_HEADS * N_EDGES;
  float* NUM_N = ws + o;  o += (size_t)2 * H_HEADS * N_NODES * 64;   // 8MB
  float* DEN_N = ws + o;  o += (size_t)2 * H_HEADS * N_NODES;
  float* NUM_E = ws + o;  o += (size_t)2 * H_HEADS * N_NODES * 64;   // 8MB
  float* DEN_E = ws + o;  o += (size_t)2 * H_HEADS * N_NODES;

  hipLaunchKernelGGL(pack_masks, dim3(1536), dim3(256), 0, stream,
                     matN, matE, bitsN, bitsE);
  hipLaunchKernelGGL(prep, dim3(832), dim3(256), 0, stream,
                     nodes, edges, WN, WE, Xhi, Xlo, Wthi, Wtlo);
  hipLaunchKernelGGL(gemm_fused, dim3(96, 8), dim3(256), 0, stream,
                     Xhi, Xlo, Wthi, Wtlo, aN, aE,
                     htT_n, htT_e, srcN, tgtN, srcE, tgtE);
  hipLaunchKernelGGL(expify, dim3(320), dim3(256), 0, stream,
                     srcN, tgtN, srcE, tgtE,
                     srcN1, srcN2, tgtN1, tgtN2, srcE1, srcE2, tgtE1, tgtE2);
  hipLaunchKernelGGL(gat_main, dim3(1024), dim3(256), 0, stream,
                     htT_n, htT_e, srcN1, srcN2, tgtN1, tgtN2,
                     srcE1, srcE2, tgtE1, tgtE2, bitsN, bitsE,
                     NUM_N, DEN_N, NUM_E, DEN_E);
  hipLaunchKernelGGL(reduce_out, dim3(128), dim3(256), 0, stream,
                     NUM_N, DEN_N, NUM_E, DEN_E, out);
}

// Round 18
// 91.838 us; speedup vs baseline: 1.1415x; 1.1064x over previous
//
#include <hip/hip_runtime.h>
#include <hip/hip_bf16.h>

#define N_NODES 2048
#define N_EDGES 4096
#define F_IN    256
#define H_HEADS 8
#define HD      512
#define LOG2E   1.44269504088896f

typedef __attribute__((ext_vector_type(4))) float f32x4;
typedef __attribute__((ext_vector_type(8))) short s16x8;
typedef __attribute__((ext_vector_type(4))) unsigned u32x4;

static __device__ __forceinline__ unsigned short f2bf(float x) {
  union { float f; unsigned u; } v; v.f = x;
  unsigned r = v.u + 0x7fff + ((v.u >> 16) & 1);   // RNE
  return (unsigned short)(r >> 16);
}
static __device__ __forceinline__ unsigned cvtpk(float lo, float hi) {
  unsigned r;
  asm("v_cvt_pk_bf16_f32 %0, %1, %2" : "=v"(r) : "v"(lo), "v"(hi));
  return r;
}

// ---------------------------------------------------------------------------
// Kernel FRONT: blocks 0..767 = scalar ht-GEMM + transpose + scores (R11/R14
// proven body); blocks 768..2303 = mask bit-pack (independent work, overlaps).
// ---------------------------------------------------------------------------
__global__ __launch_bounds__(256) void front(
    const float* __restrict__ nodes, const float* __restrict__ edges,
    const float* __restrict__ WN, const float* __restrict__ WE,
    const float* __restrict__ aN, const float* __restrict__ aE,
    const int* __restrict__ matN, const int* __restrict__ matE,
    unsigned* __restrict__ bitsN, unsigned* __restrict__ bitsE,
    unsigned short* __restrict__ htT_n, unsigned short* __restrict__ htT_e,
    float* __restrict__ srcN, float* __restrict__ tgtN,
    float* __restrict__ srcE, float* __restrict__ tgtE)
{
  __shared__ __align__(16) float Xs[32][68];
  __shared__ __align__(16) float Ws[32][64];
  __shared__ __align__(16) float T[64][68];    // T[d][m_local]

  const int b = blockIdx.x;
  const int tid = threadIdx.x;

  if (b >= 768) {
    // ---------------- pack_masks body (R14-exact) ----------------
    int t = (b - 768) * 256 + tid;             // 393216 threads
    const int* src; unsigned* dst;
    if (t < N_NODES * (N_NODES / 32)) {
      int row = t >> 6, w = t & 63;
      src = &matN[(size_t)row * N_NODES + w * 32]; dst = &bitsN[t];
    } else {
      int tt = t - N_NODES * (N_NODES / 32);
      int row = tt >> 7, w = tt & 127;
      src = &matE[(size_t)row * N_EDGES + w * 32]; dst = &bitsE[tt];
    }
    unsigned bb = 0;
#pragma unroll
    for (int k = 7; k >= 0; --k) {
      int4 v = *(const int4*)&src[k * 4];
      bb = (bb << 1) | ((unsigned)v.w & 1u);
      bb = (bb << 1) | ((unsigned)v.z & 1u);
      bb = (bb << 1) | ((unsigned)v.y & 1u);
      bb = (bb << 1) | ((unsigned)v.x & 1u);
    }
    *dst = bb;
    return;
  }

  // ---------------- gemm_fused body (R11/R14-exact) ----------------
  const int rt = b % 96;      // 0..31 nodes, 32..95 edges
  const int h  = b / 96;      // head
  const bool isNode = (rt < 32);
  const float* __restrict__ X = isNode ? nodes : edges;
  const float* __restrict__ W = isNode ? WN : WE;
  const int r0 = (isNode ? rt : rt - 32) * 64;
  const int MT = (isNode ? N_NODES : N_EDGES) / 32;

  const int tx = tid & 15, ty = tid >> 4;

  float acc[4][4];
#pragma unroll
  for (int i = 0; i < 4; ++i)
#pragma unroll
    for (int j = 0; j < 4; ++j) acc[i][j] = 0.f;

  for (int k0 = 0; k0 < F_IN; k0 += 32) {
    __syncthreads();
#pragma unroll
    for (int i = 0; i < 2; ++i) {
      int v = tid + i * 256;
      int r = v >> 3, kk = (v & 7) * 4;
      float4 x = *(const float4*)&X[(size_t)(r0 + r) * F_IN + k0 + kk];
      Xs[kk + 0][r] = x.x; Xs[kk + 1][r] = x.y;
      Xs[kk + 2][r] = x.z; Xs[kk + 3][r] = x.w;
      int kw = v >> 4, cc = (v & 15) * 4;
      *(float4*)&Ws[kw][cc] =
          *(const float4*)&W[(size_t)(k0 + kw) * HD + h * 64 + cc];
    }
    __syncthreads();
#pragma unroll
    for (int k = 0; k < 32; ++k) {
      float4 a4 = *(const float4*)&Xs[k][ty * 4];
      float4 b4 = *(const float4*)&Ws[k][tx * 4];
      float av[4] = {a4.x, a4.y, a4.z, a4.w};
      float bv[4] = {b4.x, b4.y, b4.z, b4.w};
#pragma unroll
      for (int i = 0; i < 4; ++i)
#pragma unroll
        for (int j = 0; j < 4; ++j)
          acc[i][j] = fmaf(av[i], bv[j], acc[i][j]);
    }
  }

  __syncthreads();
#pragma unroll
  for (int i = 0; i < 4; ++i)
#pragma unroll
    for (int j = 0; j < 4; ++j)
      T[tx * 4 + j][ty * 4 + i] = acc[i][j];
  __syncthreads();

  // bf16 tiled transposed write: htT2[h][mblk][d][m%32]
  {
    int d = tid >> 2, mq = tid & 3;
    s16x8 o0, o1;
#pragma unroll
    for (int k = 0; k < 8; ++k) o0[k] = (short)f2bf(T[d][mq * 16 + k]);
#pragma unroll
    for (int k = 0; k < 8; ++k) o1[k] = (short)f2bf(T[d][mq * 16 + 8 + k]);
    unsigned short* dst = isNode ? htT_n : htT_e;
    int mb0 = r0 >> 5;
    size_t base = (size_t)h * MT * 2048 + (size_t)(mb0 + (mq >> 1)) * 2048
                + d * 32 + (mq & 1) * 16;
    *(s16x8*)&dst[base] = o0;
    *(s16x8*)&dst[base + 8] = o1;
  }

  // score vectors, pre-scaled by LOG2E
  {
    int r = tid >> 2, q4 = tid & 3;
    float tr[16];
#pragma unroll
    for (int k = 0; k < 16; ++k) tr[k] = T[q4 * 16 + k][r];
    if (isNode) {
      float s1 = 0.f, s2 = 0.f, s3 = 0.f;
#pragma unroll
      for (int k = 0; k < 16; ++k) {
        s1 = fmaf(tr[k], aN[h * 128 + q4 * 16 + k], s1);
        s2 = fmaf(tr[k], aN[h * 128 + 64 + q4 * 16 + k], s2);
        s3 = fmaf(tr[k], aE[h * 128 + q4 * 16 + k], s3);
      }
      s1 += __shfl_xor(s1, 1); s1 += __shfl_xor(s1, 2);
      s2 += __shfl_xor(s2, 1); s2 += __shfl_xor(s2, 2);
      s3 += __shfl_xor(s3, 1); s3 += __shfl_xor(s3, 2);
      if (q4 == 0) {
        srcN[h * N_NODES + r0 + r] = s1 * LOG2E;
        tgtN[h * N_NODES + r0 + r] = s2 * LOG2E;
        srcE[h * N_NODES + r0 + r] = s3 * LOG2E;
      }
    } else {
      float s4 = 0.f;
#pragma unroll
      for (int k = 0; k < 16; ++k)
        s4 = fmaf(tr[k], aE[h * 128 + 64 + q4 * 16 + k], s4);
      s4 += __shfl_xor(s4, 1); s4 += __shfl_xor(s4, 2);
      if (q4 == 0) tgtE[h * N_EDGES + r0 + r] = s4 * LOG2E;
    }
  }
}

// ---------------------------------------------------------------------------
// Kernel B2: expify — scores -> factorized exp pairs.
// ---------------------------------------------------------------------------
__global__ __launch_bounds__(256) void expify(
    const float* __restrict__ srcN, const float* __restrict__ tgtN,
    const float* __restrict__ srcE, const float* __restrict__ tgtE,
    float* __restrict__ srcN1, float* __restrict__ srcN2,
    float* __restrict__ tgtN1, float* __restrict__ tgtN2,
    float* __restrict__ srcE1, float* __restrict__ srcE2,
    float* __restrict__ tgtE1, float* __restrict__ tgtE2)
{
  int t = blockIdx.x * 256 + threadIdx.x;   // 81920 threads
  const float* in; float* o1; float* o2; int idx;
  if (t < 16384)      { in = srcN; o1 = srcN1; o2 = srcN2; idx = t; }
  else if (t < 32768) { in = tgtN; o1 = tgtN1; o2 = tgtN2; idx = t - 16384; }
  else if (t < 49152) { in = srcE; o1 = srcE1; o2 = srcE2; idx = t - 32768; }
  else                { in = tgtE; o1 = tgtE1; o2 = tgtE2; idx = t - 49152; }
  float s = in[idx];
  o1[idx] = __builtin_amdgcn_exp2f(s);
  o2[idx] = __builtin_amdgcn_exp2f(0.2f * s);
}

// ---------------------------------------------------------------------------
// Kernel C: main GAT (R14 exact). w = mask & max(E1n*E1m, E2n*E2m).
// ---------------------------------------------------------------------------
struct StepIn {
  unsigned wd00, wd01, wd10, wd11;
  float4 ta1, tb1, tc1, td1;    // E1m at qo, qo+4, 32+qo, 32+qo+4
  float4 ta2, tb2, tc2, td2;    // E2m same offsets
  s16x8 bf0, bf1, bf2, bf3;     // ks=0, dt=0..3
  s16x8 bf4, bf5, bf6, bf7;     // ks=1, dt=0..3
};

template<int REL>
__device__ __forceinline__ StepIn load_step(
    const unsigned* __restrict__ br0, const unsigned* __restrict__ br1,
    const float* __restrict__ t1, const float* __restrict__ t2,
    const unsigned short* __restrict__ hb0,
    const unsigned short* __restrict__ hb1)
{
  StepIn s;
  s.wd00 = br0[REL * 2]; s.wd01 = br0[REL * 2 + 1];
  s.wd10 = br1[REL * 2]; s.wd11 = br1[REL * 2 + 1];
  s.ta1 = *(const float4*)&t1[REL * 64];
  s.tb1 = *(const float4*)&t1[REL * 64 + 4];
  s.tc1 = *(const float4*)&t1[REL * 64 + 32];
  s.td1 = *(const float4*)&t1[REL * 64 + 36];
  s.ta2 = *(const float4*)&t2[REL * 64];
  s.tb2 = *(const float4*)&t2[REL * 64 + 4];
  s.tc2 = *(const float4*)&t2[REL * 64 + 32];
  s.td2 = *(const float4*)&t2[REL * 64 + 36];
  const unsigned short* hb = REL ? hb1 : hb0;
  s.bf0 = *(const s16x8*)&hb[0 * 512];
  s.bf1 = *(const s16x8*)&hb[1 * 512];
  s.bf2 = *(const s16x8*)&hb[2 * 512];
  s.bf3 = *(const s16x8*)&hb[3 * 512];
  s.bf4 = *(const s16x8*)&hb[2048 + 0 * 512];
  s.bf5 = *(const s16x8*)&hb[2048 + 1 * 512];
  s.bf6 = *(const s16x8*)&hb[2048 + 2 * 512];
  s.bf7 = *(const s16x8*)&hb[2048 + 3 * 512];
  return s;
}

__device__ __forceinline__ void compute_step(
    const StepIn& sI, int qo,
    float e1n0, float e2n0, float e1n1, float e2n1, s16x8 ones,
    f32x4 acc[2][4], f32x4 accd[2])
{
  s16x8 afr[2][2];
#pragma unroll
  for (int nt = 0; nt < 2; ++nt) {
    float e1n = nt ? e1n1 : e1n0;
    float e2n = nt ? e2n1 : e2n0;
#pragma unroll
    for (int ks = 0; ks < 2; ++ks) {
      unsigned wdw = nt ? (ks ? sI.wd11 : sI.wd10) : (ks ? sI.wd01 : sI.wd00);
      unsigned wq = wdw >> qo;
      float4 u1 = ks ? sI.tc1 : sI.ta1;
      float4 v1 = ks ? sI.td1 : sI.tb1;
      float4 u2 = ks ? sI.tc2 : sI.ta2;
      float4 v2 = ks ? sI.td2 : sI.tb2;
      float m1[8] = {u1.x, u1.y, u1.z, u1.w, v1.x, v1.y, v1.z, v1.w};
      float m2[8] = {u2.x, u2.y, u2.z, u2.w, v2.x, v2.y, v2.z, v2.w};
      float wv[8];
#pragma unroll
      for (int j = 0; j < 8; ++j) {
        float p1 = e1n * m1[j];
        float p2 = e2n * m2[j];
        float mx = fmaxf(p1, p2);               // = exp(lrelu(e)) by monotonicity
        int msk = -(int)((wq >> j) & 1u);       // 0 or 0xFFFFFFFF (portable)
        wv[j] = __int_as_float(msk & __float_as_int(mx));
      }
      u32x4 p;
      p[0] = cvtpk(wv[0], wv[1]);
      p[1] = cvtpk(wv[2], wv[3]);
      p[2] = cvtpk(wv[4], wv[5]);
      p[3] = cvtpk(wv[6], wv[7]);
      afr[nt][ks] = __builtin_bit_cast(s16x8, p);
    }
  }
  acc[0][0] = __builtin_amdgcn_mfma_f32_16x16x32_bf16(afr[0][0], sI.bf0, acc[0][0], 0, 0, 0);
  acc[0][1] = __builtin_amdgcn_mfma_f32_16x16x32_bf16(afr[0][0], sI.bf1, acc[0][1], 0, 0, 0);
  acc[0][2] = __builtin_amdgcn_mfma_f32_16x16x32_bf16(afr[0][0], sI.bf2, acc[0][2], 0, 0, 0);
  acc[0][3] = __builtin_amdgcn_mfma_f32_16x16x32_bf16(afr[0][0], sI.bf3, acc[0][3], 0, 0, 0);
  accd[0]   = __builtin_amdgcn_mfma_f32_16x16x32_bf16(afr[0][0], ones,   accd[0],   0, 0, 0);
  acc[1][0] = __builtin_amdgcn_mfma_f32_16x16x32_bf16(afr[1][0], sI.bf0, acc[1][0], 0, 0, 0);
  acc[1][1] = __builtin_amdgcn_mfma_f32_16x16x32_bf16(afr[1][0], sI.bf1, acc[1][1], 0, 0, 0);
  acc[1][2] = __builtin_amdgcn_mfma_f32_16x16x32_bf16(afr[1][0], sI.bf2, acc[1][2], 0, 0, 0);
  acc[1][3] = __builtin_amdgcn_mfma_f32_16x16x32_bf16(afr[1][0], sI.bf3, acc[1][3], 0, 0, 0);
  accd[1]   = __builtin_amdgcn_mfma_f32_16x16x32_bf16(afr[1][0], ones,   accd[1],   0, 0, 0);
  acc[0][0] = __builtin_amdgcn_mfma_f32_16x16x32_bf16(afr[0][1], sI.bf4, acc[0][0], 0, 0, 0);
  acc[0][1] = __builtin_amdgcn_mfma_f32_16x16x32_bf16(afr[0][1], sI.bf5, acc[0][1], 0, 0, 0);
  acc[0][2] = __builtin_amdgcn_mfma_f32_16x16x32_bf16(afr[0][1], sI.bf6, acc[0][2], 0, 0, 0);
  acc[0][3] = __builtin_amdgcn_mfma_f32_16x16x32_bf16(afr[0][1], sI.bf7, acc[0][3], 0, 0, 0);
  accd[0]   = __builtin_amdgcn_mfma_f32_16x16x32_bf16(afr[0][1], ones,   accd[0],   0, 0, 0);
  acc[1][0] = __builtin_amdgcn_mfma_f32_16x16x32_bf16(afr[1][1], sI.bf4, acc[1][0], 0, 0, 0);
  acc[1][1] = __builtin_amdgcn_mfma_f32_16x16x32_bf16(afr[1][1], sI.bf5, acc[1][1], 0, 0, 0);
  acc[1][2] = __builtin_amdgcn_mfma_f32_16x16x32_bf16(afr[1][1], sI.bf6, acc[1][2], 0, 0, 0);
  acc[1][3] = __builtin_amdgcn_mfma_f32_16x16x32_bf16(afr[1][1], sI.bf7, acc[1][3], 0, 0, 0);
  accd[1]   = __builtin_amdgcn_mfma_f32_16x16x32_bf16(afr[1][1], ones,   accd[1],   0, 0, 0);
}

template<int NSTEPS>
__device__ __forceinline__ void gat_part32(
    const unsigned* __restrict__ bits, int MT,
    const float* __restrict__ t1_h, const float* __restrict__ t2_h,
    const unsigned short* __restrict__ htT_h,
    int n0, int m_begin, int r16, int qo,
    float e1n0, float e2n0, float e1n1, float e2n1, s16x8 ones,
    f32x4 acc[2][4], f32x4 accd[2])
{
#pragma unroll
  for (int nt = 0; nt < 2; ++nt) {
    accd[nt] = (f32x4){0.f, 0.f, 0.f, 0.f};
#pragma unroll
    for (int dt = 0; dt < 4; ++dt) acc[nt][dt] = (f32x4){0.f, 0.f, 0.f, 0.f};
  }
  int mb0 = m_begin >> 5;
  const unsigned* br0 = &bits[(size_t)(n0 + r16) * MT + mb0];
  const unsigned* br1 = &bits[(size_t)(n0 + 16 + r16) * MT + mb0];
  const float* t1 = &t1_h[m_begin + qo];
  const float* t2 = &t2_h[m_begin + qo];
  const unsigned short* hb0 = &htT_h[(size_t)mb0 * 2048 + r16 * 32 + qo];
  const unsigned short* hb1 = hb0 + 4096;

  StepIn sA = load_step<0>(br0, br1, t1, t2, hb0, hb1);
#pragma unroll
  for (int st = 0; st < NSTEPS - 2; st += 2) {
    StepIn sB = load_step<1>(br0, br1, t1, t2, hb0, hb1);
    br0 += 4; br1 += 4; t1 += 128; t2 += 128; hb0 += 8192; hb1 += 8192;
    compute_step(sA, qo, e1n0, e2n0, e1n1, e2n1, ones, acc, accd);
    sA = load_step<0>(br0, br1, t1, t2, hb0, hb1);
    compute_step(sB, qo, e1n0, e2n0, e1n1, e2n1, ones, acc, accd);
  }
  StepIn sB = load_step<1>(br0, br1, t1, t2, hb0, hb1);
  compute_step(sA, qo, e1n0, e2n0, e1n1, e2n1, ones, acc, accd);
  compute_step(sB, qo, e1n0, e2n0, e1n1, e2n1, ones, acc, accd);
}

// two-pass (d-half) combine + global store
__device__ __forceinline__ void combine_store(
    f32x4 acc[2][4], f32x4 accd[2],
    float lnum[4][32][36], float lden[4][32],
    int w, int q, int r16, int tid,
    float* __restrict__ NUM, float* __restrict__ DEN, int sh, int n0)
{
  const int crow = tid >> 3, cd4 = (tid & 7) * 4;
#pragma unroll
  for (int pass = 0; pass < 2; ++pass) {
    __syncthreads();
#pragma unroll
    for (int nt = 0; nt < 2; ++nt)
#pragma unroll
      for (int dtl = 0; dtl < 2; ++dtl)
#pragma unroll
        for (int qi = 0; qi < 4; ++qi)
          lnum[w][nt * 16 + q * 4 + qi][dtl * 16 + r16] =
              acc[nt][pass * 2 + dtl][qi];
    if (pass == 0 && r16 == 0) {
#pragma unroll
      for (int nt = 0; nt < 2; ++nt)
#pragma unroll
        for (int qi = 0; qi < 4; ++qi)
          lden[w][nt * 16 + q * 4 + qi] = accd[nt][qi];
    }
    __syncthreads();
    f32x4 s = (f32x4){0.f, 0.f, 0.f, 0.f};
#pragma unroll
    for (int ww = 0; ww < 4; ++ww) s += *(const f32x4*)&lnum[ww][crow][cd4];
    *(f32x4*)&NUM[((size_t)sh * N_NODES + n0 + crow) * 64 + pass * 32 + cd4] = s;
    if (pass == 0 && (tid & 7) == 0) {
      float dsum = lden[0][crow] + lden[1][crow] + lden[2][crow] + lden[3][crow];
      DEN[(size_t)sh * N_NODES + n0 + crow] = dsum;
    }
  }
}

__global__ __launch_bounds__(256, 2) void gat_main(
    const unsigned short* __restrict__ htT_n, const unsigned short* __restrict__ htT_e,
    const float* __restrict__ srcN1, const float* __restrict__ srcN2,
    const float* __restrict__ tgtN1, const float* __restrict__ tgtN2,
    const float* __restrict__ srcE1, const float* __restrict__ srcE2,
    const float* __restrict__ tgtE1, const float* __restrict__ tgtE2,
    const unsigned* __restrict__ bitsN, const unsigned* __restrict__ bitsE,
    float* __restrict__ NUM_N, float* __restrict__ DEN_N,
    float* __restrict__ NUM_E, float* __restrict__ DEN_E)
{
  const int i = blockIdx.x;                     // 1024 blocks
  const int h = i & 7;
  const int tile = (i >> 3) & 63;
  const int ms = i >> 9;                        // m-split 0/1
  const int n0 = tile * 32;
  const int tid = threadIdx.x, w = tid >> 6, lane = tid & 63;
  const int r16 = lane & 15, q = lane >> 4, qo = q * 8;
  const int sh = ms * 8 + h;

  __shared__ __align__(16) float lnum[4][32][36];
  __shared__ float lden[4][32];

  s16x8 ones;
#pragma unroll
  for (int j = 0; j < 8; ++j) ones[j] = (short)0x3F80;    // bf16 1.0

  f32x4 acc[2][4], accd[2];

  // ---------------- nodes part: 4 steps ----------------
  {
    float e1n0 = srcN1[h * N_NODES + n0 + r16];
    float e2n0 = srcN2[h * N_NODES + n0 + r16];
    float e1n1 = srcN1[h * N_NODES + n0 + 16 + r16];
    float e2n1 = srcN2[h * N_NODES + n0 + 16 + r16];
    gat_part32<4>(bitsN, N_NODES / 32,
                  tgtN1 + (size_t)h * N_NODES, tgtN2 + (size_t)h * N_NODES,
                  htT_n + (size_t)h * (N_NODES / 32) * 2048,
                  n0, ms * 1024 + w * 256, r16, qo,
                  e1n0, e2n0, e1n1, e2n1, ones, acc, accd);
    combine_store(acc, accd, lnum, lden, w, q, r16, tid, NUM_N, DEN_N, sh, n0);
  }

  // ---------------- edges part: 8 steps ----------------
  {
    float e1n0 = srcE1[h * N_NODES + n0 + r16];
    float e2n0 = srcE2[h * N_NODES + n0 + r16];
    float e1n1 = srcE1[h * N_NODES + n0 + 16 + r16];
    float e2n1 = srcE2[h * N_NODES + n0 + 16 + r16];
    gat_part32<8>(bitsE, N_EDGES / 32,
                  tgtE1 + (size_t)h * N_EDGES, tgtE2 + (size_t)h * N_EDGES,
                  htT_e + (size_t)h * (N_EDGES / 32) * 2048,
                  n0, ms * 2048 + w * 512, r16, qo,
                  e1n0, e2n0, e1n1, e2n1, ones, acc, accd);
    combine_store(acc, accd, lnum, lden, w, q, r16, tid, NUM_E, DEN_E, sh, n0);
  }
}

// ---------------------------------------------------------------------------
// Kernel D: combine 2 msplit partials, normalize, mean over heads.
// ---------------------------------------------------------------------------
__global__ __launch_bounds__(128) void reduce_out(
    const float* __restrict__ NUM_N, const float* __restrict__ DEN_N,
    const float* __restrict__ NUM_E, const float* __restrict__ DEN_E,
    float* __restrict__ out)
{
  int idx = blockIdx.x * 128 + threadIdx.x;   // 32768 threads (256 blocks)
  int n = idx >> 4, d4 = (idx & 15) * 4;
  f32x4 r = (f32x4){0.f, 0.f, 0.f, 0.f};
#pragma unroll
  for (int h = 0; h < H_HEADS; ++h) {
    f32x4 nn = *(const f32x4*)&NUM_N[((size_t)h * N_NODES + n) * 64 + d4]
             + *(const f32x4*)&NUM_N[((size_t)(8 + h) * N_NODES + n) * 64 + d4];
    float dn = DEN_N[(size_t)h * N_NODES + n] + DEN_N[(size_t)(8 + h) * N_NODES + n];
    f32x4 ne = *(const f32x4*)&NUM_E[((size_t)h * N_NODES + n) * 64 + d4]
             + *(const f32x4*)&NUM_E[((size_t)(8 + h) * N_NODES + n) * 64 + d4];
    float de = DEN_E[(size_t)h * N_NODES + n] + DEN_E[(size_t)(8 + h) * N_NODES + n];
    float idn = 1.0f / dn, ide = 1.0f / de;
    r.x += nn.x * idn + ne.x * ide;
    r.y += nn.y * idn + ne.y * ide;
    r.z += nn.z * idn + ne.z * ide;
    r.w += nn.w * idn + ne.w * ide;
  }
  f32x4 o = (f32x4){r.x * 0.125f, r.y * 0.125f, r.z * 0.125f, r.w * 0.125f};
  *(f32x4*)&out[(size_t)n * 64 + d4] = o;
}

// ---------------------------------------------------------------------------
extern "C" void kernel_launch(void* const* d_in, const int* in_sizes, int n_in,
                              void* d_out, int out_size, void* d_ws, size_t ws_size,
                              hipStream_t stream)
{
  const float* nodes = (const float*)d_in[0];
  const float* edges = (const float*)d_in[1];
  const float* WN    = (const float*)d_in[2];
  const float* WE    = (const float*)d_in[3];
  const float* aN    = (const float*)d_in[4];
  const float* aE    = (const float*)d_in[5];
  const int*   matN  = (const int*)d_in[6];
  const int*   matE  = (const int*)d_in[7];
  float* out = (float*)d_out;

  float* ws = (float*)d_ws;
  size_t o = 0;
  unsigned short* htT_n = (unsigned short*)(ws + o); o += (size_t)H_HEADS * 64 * N_NODES / 2;  // 2MB
  unsigned short* htT_e = (unsigned short*)(ws + o); o += (size_t)H_HEADS * 64 * N_EDGES / 2;  // 4MB
  unsigned* bitsN = (unsigned*)(ws + o); o += (size_t)N_NODES * (N_NODES / 32);                // 512KB
  unsigned* bitsE = (unsigned*)(ws + o); o += (size_t)N_NODES * (N_EDGES / 32);                // 1MB
  float* srcN  = ws + o;  o += (size_t)H_HEADS * N_NODES;
  float* tgtN  = ws + o;  o += (size_t)H_HEADS * N_NODES;
  float* srcE  = ws + o;  o += (size_t)H_HEADS * N_NODES;
  float* tgtE  = ws + o;  o += (size_t)H_HEADS * N_EDGES;
  float* srcN1 = ws + o;  o += (size_t)H_HEADS * N_NODES;
  float* srcN2 = ws + o;  o += (size_t)H_HEADS * N_NODES;
  float* tgtN1 = ws + o;  o += (size_t)H_HEADS * N_NODES;
  float* tgtN2 = ws + o;  o += (size_t)H_HEADS * N_NODES;
  float* srcE1 = ws + o;  o += (size_t)H_HEADS * N_NODES;
  float* srcE2 = ws + o;  o += (size_t)H_HEADS * N_NODES;
  float* tgtE1 = ws + o;  o += (size_t)H_HEADS * N_EDGES;
  float* tgtE2 = ws + o;  o += (size_t)H_HEADS * N_EDGES;
  float* NUM_N = ws + o;  o += (size_t)2 * H_HEADS * N_NODES * 64;   // 8MB
  float* DEN_N = ws + o;  o += (size_t)2 * H_HEADS * N_NODES;
  float* NUM_E = ws + o;  o += (size_t)2 * H_HEADS * N_NODES * 64;   // 8MB
  float* DEN_E = ws + o;  o += (size_t)2 * H_HEADS * N_NODES;

  hipLaunchKernelGGL(front, dim3(2304), dim3(256), 0, stream,
                     nodes, edges, WN, WE, aN, aE, matN, matE, bitsN, bitsE,
                     htT_n, htT_e, srcN, tgtN, srcE, tgtE);
  hipLaunchKernelGGL(expify, dim3(320), dim3(256), 0, stream,
                     srcN, tgtN, srcE, tgtE,
                     srcN1, srcN2, tgtN1, tgtN2, srcE1, srcE2, tgtE1, tgtE2);
  hipLaunchKernelGGL(gat_main, dim3(1024), dim3(256), 0, stream,
                     htT_n, htT_e, srcN1, srcN2, tgtN1, tgtN2,
                     srcE1, srcE2, tgtE1, tgtE2, bitsN, bitsE,
                     NUM_N, DEN_N, NUM_E, DEN_E);
  hipLaunchKernelGGL(reduce_out, dim3(256), dim3(128), 0, stream,
                     NUM_N, DEN_N, NUM_E, DEN_E, out);
}

// Round 19
// 82.901 us; speedup vs baseline: 1.2646x; 1.1078x over previous
//
#include <hip/hip_runtime.h>
#include <hip/hip_bf16.h>

#define N_NODES 2048
#define N_EDGES 4096
#define F_IN    256
#define H_HEADS 8
#define HD      512
#define LOG2E   1.44269504088896f

typedef __attribute__((ext_vector_type(4))) float f32x4;
typedef __attribute__((ext_vector_type(8))) short s16x8;
typedef __attribute__((ext_vector_type(4))) unsigned u32x4;

static __device__ __forceinline__ unsigned short f2bf(float x) {
  union { float f; unsigned u; } v; v.f = x;
  unsigned r = v.u + 0x7fff + ((v.u >> 16) & 1);   // RNE
  return (unsigned short)(r >> 16);
}
static __device__ __forceinline__ unsigned cvtpk(float lo, float hi) {
  unsigned r;
  asm("v_cvt_pk_bf16_f32 %0, %1, %2" : "=v"(r) : "v"(lo), "v"(hi));
  return r;
}

// ---------------------------------------------------------------------------
// Kernel FRONT: blocks 0..767 = scalar ht-GEMM + transpose + scores;
// blocks 768..2303 = mask bit-pack (independent, overlaps).  (R18-exact)
// ---------------------------------------------------------------------------
__global__ __launch_bounds__(256) void front(
    const float* __restrict__ nodes, const float* __restrict__ edges,
    const float* __restrict__ WN, const float* __restrict__ WE,
    const float* __restrict__ aN, const float* __restrict__ aE,
    const int* __restrict__ matN, const int* __restrict__ matE,
    unsigned* __restrict__ bitsN, unsigned* __restrict__ bitsE,
    unsigned short* __restrict__ htT_n, unsigned short* __restrict__ htT_e,
    float* __restrict__ srcN, float* __restrict__ tgtN,
    float* __restrict__ srcE, float* __restrict__ tgtE)
{
  __shared__ __align__(16) float Xs[32][68];
  __shared__ __align__(16) float Ws[32][64];
  __shared__ __align__(16) float T[64][68];    // T[d][m_local]

  const int b = blockIdx.x;
  const int tid = threadIdx.x;

  if (b >= 768) {
    int t = (b - 768) * 256 + tid;             // 393216 threads
    const int* src; unsigned* dst;
    if (t < N_NODES * (N_NODES / 32)) {
      int row = t >> 6, w = t & 63;
      src = &matN[(size_t)row * N_NODES + w * 32]; dst = &bitsN[t];
    } else {
      int tt = t - N_NODES * (N_NODES / 32);
      int row = tt >> 7, w = tt & 127;
      src = &matE[(size_t)row * N_EDGES + w * 32]; dst = &bitsE[tt];
    }
    unsigned bb = 0;
#pragma unroll
    for (int k = 7; k >= 0; --k) {
      int4 v = *(const int4*)&src[k * 4];
      bb = (bb << 1) | ((unsigned)v.w & 1u);
      bb = (bb << 1) | ((unsigned)v.z & 1u);
      bb = (bb << 1) | ((unsigned)v.y & 1u);
      bb = (bb << 1) | ((unsigned)v.x & 1u);
    }
    *dst = bb;
    return;
  }

  const int rt = b % 96;      // 0..31 nodes, 32..95 edges
  const int h  = b / 96;      // head
  const bool isNode = (rt < 32);
  const float* __restrict__ X = isNode ? nodes : edges;
  const float* __restrict__ W = isNode ? WN : WE;
  const int r0 = (isNode ? rt : rt - 32) * 64;
  const int MT = (isNode ? N_NODES : N_EDGES) / 32;

  const int tx = tid & 15, ty = tid >> 4;

  float acc[4][4];
#pragma unroll
  for (int i = 0; i < 4; ++i)
#pragma unroll
    for (int j = 0; j < 4; ++j) acc[i][j] = 0.f;

  for (int k0 = 0; k0 < F_IN; k0 += 32) {
    __syncthreads();
#pragma unroll
    for (int i = 0; i < 2; ++i) {
      int v = tid + i * 256;
      int r = v >> 3, kk = (v & 7) * 4;
      float4 x = *(const float4*)&X[(size_t)(r0 + r) * F_IN + k0 + kk];
      Xs[kk + 0][r] = x.x; Xs[kk + 1][r] = x.y;
      Xs[kk + 2][r] = x.z; Xs[kk + 3][r] = x.w;
      int kw = v >> 4, cc = (v & 15) * 4;
      *(float4*)&Ws[kw][cc] =
          *(const float4*)&W[(size_t)(k0 + kw) * HD + h * 64 + cc];
    }
    __syncthreads();
#pragma unroll
    for (int k = 0; k < 32; ++k) {
      float4 a4 = *(const float4*)&Xs[k][ty * 4];
      float4 b4 = *(const float4*)&Ws[k][tx * 4];
      float av[4] = {a4.x, a4.y, a4.z, a4.w};
      float bv[4] = {b4.x, b4.y, b4.z, b4.w};
#pragma unroll
      for (int i = 0; i < 4; ++i)
#pragma unroll
        for (int j = 0; j < 4; ++j)
          acc[i][j] = fmaf(av[i], bv[j], acc[i][j]);
    }
  }

  __syncthreads();
#pragma unroll
  for (int i = 0; i < 4; ++i)
#pragma unroll
    for (int j = 0; j < 4; ++j)
      T[tx * 4 + j][ty * 4 + i] = acc[i][j];
  __syncthreads();

  // bf16 tiled transposed write: htT2[h][mblk][d][m%32]
  {
    int d = tid >> 2, mq = tid & 3;
    s16x8 o0, o1;
#pragma unroll
    for (int k = 0; k < 8; ++k) o0[k] = (short)f2bf(T[d][mq * 16 + k]);
#pragma unroll
    for (int k = 0; k < 8; ++k) o1[k] = (short)f2bf(T[d][mq * 16 + 8 + k]);
    unsigned short* dst = isNode ? htT_n : htT_e;
    int mb0 = r0 >> 5;
    size_t base = (size_t)h * MT * 2048 + (size_t)(mb0 + (mq >> 1)) * 2048
                + d * 32 + (mq & 1) * 16;
    *(s16x8*)&dst[base] = o0;
    *(s16x8*)&dst[base + 8] = o1;
  }

  // score vectors, pre-scaled by LOG2E
  {
    int r = tid >> 2, q4 = tid & 3;
    float tr[16];
#pragma unroll
    for (int k = 0; k < 16; ++k) tr[k] = T[q4 * 16 + k][r];
    if (isNode) {
      float s1 = 0.f, s2 = 0.f, s3 = 0.f;
#pragma unroll
      for (int k = 0; k < 16; ++k) {
        s1 = fmaf(tr[k], aN[h * 128 + q4 * 16 + k], s1);
        s2 = fmaf(tr[k], aN[h * 128 + 64 + q4 * 16 + k], s2);
        s3 = fmaf(tr[k], aE[h * 128 + q4 * 16 + k], s3);
      }
      s1 += __shfl_xor(s1, 1); s1 += __shfl_xor(s1, 2);
      s2 += __shfl_xor(s2, 1); s2 += __shfl_xor(s2, 2);
      s3 += __shfl_xor(s3, 1); s3 += __shfl_xor(s3, 2);
      if (q4 == 0) {
        srcN[h * N_NODES + r0 + r] = s1 * LOG2E;
        tgtN[h * N_NODES + r0 + r] = s2 * LOG2E;
        srcE[h * N_NODES + r0 + r] = s3 * LOG2E;
      }
    } else {
      float s4 = 0.f;
#pragma unroll
      for (int k = 0; k < 16; ++k)
        s4 = fmaf(tr[k], aE[h * 128 + 64 + q4 * 16 + k], s4);
      s4 += __shfl_xor(s4, 1); s4 += __shfl_xor(s4, 2);
      if (q4 == 0) tgtE[h * N_EDGES + r0 + r] = s4 * LOG2E;
    }
  }
}

// ---------------------------------------------------------------------------
// Kernel B2: expify — scores -> factorized exp pairs.
// ---------------------------------------------------------------------------
__global__ __launch_bounds__(256) void expify(
    const float* __restrict__ srcN, const float* __restrict__ tgtN,
    const float* __restrict__ srcE, const float* __restrict__ tgtE,
    float* __restrict__ srcN1, float* __restrict__ srcN2,
    float* __restrict__ tgtN1, float* __restrict__ tgtN2,
    float* __restrict__ srcE1, float* __restrict__ srcE2,
    float* __restrict__ tgtE1, float* __restrict__ tgtE2)
{
  int t = blockIdx.x * 256 + threadIdx.x;   // 81920 threads
  const float* in; float* o1; float* o2; int idx;
  if (t < 16384)      { in = srcN; o1 = srcN1; o2 = srcN2; idx = t; }
  else if (t < 32768) { in = tgtN; o1 = tgtN1; o2 = tgtN2; idx = t - 16384; }
  else if (t < 49152) { in = srcE; o1 = srcE1; o2 = srcE2; idx = t - 32768; }
  else                { in = tgtE; o1 = tgtE1; o2 = tgtE2; idx = t - 49152; }
  float s = in[idx];
  o1[idx] = __builtin_amdgcn_exp2f(s);
  o2[idx] = __builtin_amdgcn_exp2f(0.2f * s);
}

// ---------------------------------------------------------------------------
// Kernel C: main GAT. tgt E-pairs staged in LDS (broadcast reads, ~60cy);
// w = mask & max(E1n*E1m, E2n*E2m).  Otherwise R18-exact.
// ---------------------------------------------------------------------------
struct StepIn {
  unsigned wd00, wd01, wd10, wd11;
  float4 ta1, tb1, tc1, td1;    // E1m at qo, qo+4, 32+qo, 32+qo+4
  float4 ta2, tb2, tc2, td2;    // E2m same offsets
  s16x8 bf0, bf1, bf2, bf3;     // ks=0, dt=0..3
  s16x8 bf4, bf5, bf6, bf7;     // ks=1, dt=0..3
};

// t1/t2 now point into LDS (block-local m window, wave-offset applied).
template<int REL>
__device__ __forceinline__ StepIn load_step(
    const unsigned* __restrict__ br0, const unsigned* __restrict__ br1,
    const float* t1, const float* t2,
    const unsigned short* __restrict__ hb0,
    const unsigned short* __restrict__ hb1)
{
  StepIn s;
  s.wd00 = br0[REL * 2]; s.wd01 = br0[REL * 2 + 1];
  s.wd10 = br1[REL * 2]; s.wd11 = br1[REL * 2 + 1];
  s.ta1 = *(const float4*)&t1[REL * 64];
  s.tb1 = *(const float4*)&t1[REL * 64 + 4];
  s.tc1 = *(const float4*)&t1[REL * 64 + 32];
  s.td1 = *(const float4*)&t1[REL * 64 + 36];
  s.ta2 = *(const float4*)&t2[REL * 64];
  s.tb2 = *(const float4*)&t2[REL * 64 + 4];
  s.tc2 = *(const float4*)&t2[REL * 64 + 32];
  s.td2 = *(const float4*)&t2[REL * 64 + 36];
  const unsigned short* hb = REL ? hb1 : hb0;
  s.bf0 = *(const s16x8*)&hb[0 * 512];
  s.bf1 = *(const s16x8*)&hb[1 * 512];
  s.bf2 = *(const s16x8*)&hb[2 * 512];
  s.bf3 = *(const s16x8*)&hb[3 * 512];
  s.bf4 = *(const s16x8*)&hb[2048 + 0 * 512];
  s.bf5 = *(const s16x8*)&hb[2048 + 1 * 512];
  s.bf6 = *(const s16x8*)&hb[2048 + 2 * 512];
  s.bf7 = *(const s16x8*)&hb[2048 + 3 * 512];
  return s;
}

__device__ __forceinline__ void compute_step(
    const StepIn& sI, int qo,
    float e1n0, float e2n0, float e1n1, float e2n1, s16x8 ones,
    f32x4 acc[2][4], f32x4 accd[2])
{
  s16x8 afr[2][2];
#pragma unroll
  for (int nt = 0; nt < 2; ++nt) {
    float e1n = nt ? e1n1 : e1n0;
    float e2n = nt ? e2n1 : e2n0;
#pragma unroll
    for (int ks = 0; ks < 2; ++ks) {
      unsigned wdw = nt ? (ks ? sI.wd11 : sI.wd10) : (ks ? sI.wd01 : sI.wd00);
      unsigned wq = wdw >> qo;
      float4 u1 = ks ? sI.tc1 : sI.ta1;
      float4 v1 = ks ? sI.td1 : sI.tb1;
      float4 u2 = ks ? sI.tc2 : sI.ta2;
      float4 v2 = ks ? sI.td2 : sI.tb2;
      float m1[8] = {u1.x, u1.y, u1.z, u1.w, v1.x, v1.y, v1.z, v1.w};
      float m2[8] = {u2.x, u2.y, u2.z, u2.w, v2.x, v2.y, v2.z, v2.w};
      float wv[8];
#pragma unroll
      for (int j = 0; j < 8; ++j) {
        float p1 = e1n * m1[j];
        float p2 = e2n * m2[j];
        float mx = fmaxf(p1, p2);               // = exp(lrelu(e)) by monotonicity
        int msk = -(int)((wq >> j) & 1u);       // 0 or 0xFFFFFFFF (portable)
        wv[j] = __int_as_float(msk & __float_as_int(mx));
      }
      u32x4 p;
      p[0] = cvtpk(wv[0], wv[1]);
      p[1] = cvtpk(wv[2], wv[3]);
      p[2] = cvtpk(wv[4], wv[5]);
      p[3] = cvtpk(wv[6], wv[7]);
      afr[nt][ks] = __builtin_bit_cast(s16x8, p);
    }
  }
  acc[0][0] = __builtin_amdgcn_mfma_f32_16x16x32_bf16(afr[0][0], sI.bf0, acc[0][0], 0, 0, 0);
  acc[0][1] = __builtin_amdgcn_mfma_f32_16x16x32_bf16(afr[0][0], sI.bf1, acc[0][1], 0, 0, 0);
  acc[0][2] = __builtin_amdgcn_mfma_f32_16x16x32_bf16(afr[0][0], sI.bf2, acc[0][2], 0, 0, 0);
  acc[0][3] = __builtin_amdgcn_mfma_f32_16x16x32_bf16(afr[0][0], sI.bf3, acc[0][3], 0, 0, 0);
  accd[0]   = __builtin_amdgcn_mfma_f32_16x16x32_bf16(afr[0][0], ones,   accd[0],   0, 0, 0);
  acc[1][0] = __builtin_amdgcn_mfma_f32_16x16x32_bf16(afr[1][0], sI.bf0, acc[1][0], 0, 0, 0);
  acc[1][1] = __builtin_amdgcn_mfma_f32_16x16x32_bf16(afr[1][0], sI.bf1, acc[1][1], 0, 0, 0);
  acc[1][2] = __builtin_amdgcn_mfma_f32_16x16x32_bf16(afr[1][0], sI.bf2, acc[1][2], 0, 0, 0);
  acc[1][3] = __builtin_amdgcn_mfma_f32_16x16x32_bf16(afr[1][0], sI.bf3, acc[1][3], 0, 0, 0);
  accd[1]   = __builtin_amdgcn_mfma_f32_16x16x32_bf16(afr[1][0], ones,   accd[1],   0, 0, 0);
  acc[0][0] = __builtin_amdgcn_mfma_f32_16x16x32_bf16(afr[0][1], sI.bf4, acc[0][0], 0, 0, 0);
  acc[0][1] = __builtin_amdgcn_mfma_f32_16x16x32_bf16(afr[0][1], sI.bf5, acc[0][1], 0, 0, 0);
  acc[0][2] = __builtin_amdgcn_mfma_f32_16x16x32_bf16(afr[0][1], sI.bf6, acc[0][2], 0, 0, 0);
  acc[0][3] = __builtin_amdgcn_mfma_f32_16x16x32_bf16(afr[0][1], sI.bf7, acc[0][3], 0, 0, 0);
  accd[0]   = __builtin_amdgcn_mfma_f32_16x16x32_bf16(afr[0][1], ones,   accd[0],   0, 0, 0);
  acc[1][0] = __builtin_amdgcn_mfma_f32_16x16x32_bf16(afr[1][1], sI.bf4, acc[1][0], 0, 0, 0);
  acc[1][1] = __builtin_amdgcn_mfma_f32_16x16x32_bf16(afr[1][1], sI.bf5, acc[1][1], 0, 0, 0);
  acc[1][2] = __builtin_amdgcn_mfma_f32_16x16x32_bf16(afr[1][1], sI.bf6, acc[1][2], 0, 0, 0);
  acc[1][3] = __builtin_amdgcn_mfma_f32_16x16x32_bf16(afr[1][1], sI.bf7, acc[1][3], 0, 0, 0);
  accd[1]   = __builtin_amdgcn_mfma_f32_16x16x32_bf16(afr[1][1], ones,   accd[1],   0, 0, 0);
}

template<int NSTEPS>
__device__ __forceinline__ void gat_part32(
    const unsigned* __restrict__ bits, int MT,
    const float* lds_t1, const float* lds_t2,   // LDS, wave-local offset applied
    const unsigned short* __restrict__ htT_h,
    int n0, int m_begin, int r16, int qo,
    float e1n0, float e2n0, float e1n1, float e2n1, s16x8 ones,
    f32x4 acc[2][4], f32x4 accd[2])
{
#pragma unroll
  for (int nt = 0; nt < 2; ++nt) {
    accd[nt] = (f32x4){0.f, 0.f, 0.f, 0.f};
#pragma unroll
    for (int dt = 0; dt < 4; ++dt) acc[nt][dt] = (f32x4){0.f, 0.f, 0.f, 0.f};
  }
  int mb0 = m_begin >> 5;
  const unsigned* br0 = &bits[(size_t)(n0 + r16) * MT + mb0];
  const unsigned* br1 = &bits[(size_t)(n0 + 16 + r16) * MT + mb0];
  const float* t1 = lds_t1 + qo;
  const float* t2 = lds_t2 + qo;
  const unsigned short* hb0 = &htT_h[(size_t)mb0 * 2048 + r16 * 32 + qo];
  const unsigned short* hb1 = hb0 + 4096;

  StepIn sA = load_step<0>(br0, br1, t1, t2, hb0, hb1);
#pragma unroll
  for (int st = 0; st < NSTEPS - 2; st += 2) {
    StepIn sB = load_step<1>(br0, br1, t1, t2, hb0, hb1);
    br0 += 4; br1 += 4; t1 += 128; t2 += 128; hb0 += 8192; hb1 += 8192;
    compute_step(sA, qo, e1n0, e2n0, e1n1, e2n1, ones, acc, accd);
    sA = load_step<0>(br0, br1, t1, t2, hb0, hb1);
    compute_step(sB, qo, e1n0, e2n0, e1n1, e2n1, ones, acc, accd);
  }
  StepIn sB = load_step<1>(br0, br1, t1, t2, hb0, hb1);
  compute_step(sA, qo, e1n0, e2n0, e1n1, e2n1, ones, acc, accd);
  compute_step(sB, qo, e1n0, e2n0, e1n1, e2n1, ones, acc, accd);
}

// two-pass (d-half) combine + global store
__device__ __forceinline__ void combine_store(
    f32x4 acc[2][4], f32x4 accd[2],
    float lnum[4][32][36], float lden[4][32],
    int w, int q, int r16, int tid,
    float* __restrict__ NUM, float* __restrict__ DEN, int sh, int n0)
{
  const int crow = tid >> 3, cd4 = (tid & 7) * 4;
#pragma unroll
  for (int pass = 0; pass < 2; ++pass) {
    __syncthreads();
#pragma unroll
    for (int nt = 0; nt < 2; ++nt)
#pragma unroll
      for (int dtl = 0; dtl < 2; ++dtl)
#pragma unroll
        for (int qi = 0; qi < 4; ++qi)
          lnum[w][nt * 16 + q * 4 + qi][dtl * 16 + r16] =
              acc[nt][pass * 2 + dtl][qi];
    if (pass == 0 && r16 == 0) {
#pragma unroll
      for (int nt = 0; nt < 2; ++nt)
#pragma unroll
        for (int qi = 0; qi < 4; ++qi)
          lden[w][nt * 16 + q * 4 + qi] = accd[nt][qi];
    }
    __syncthreads();
    f32x4 s = (f32x4){0.f, 0.f, 0.f, 0.f};
#pragma unroll
    for (int ww = 0; ww < 4; ++ww) s += *(const f32x4*)&lnum[ww][crow][cd4];
    *(f32x4*)&NUM[((size_t)sh * N_NODES + n0 + crow) * 64 + pass * 32 + cd4] = s;
    if (pass == 0 && (tid & 7) == 0) {
      float dsum = lden[0][crow] + lden[1][crow] + lden[2][crow] + lden[3][crow];
      DEN[(size_t)sh * N_NODES + n0 + crow] = dsum;
    }
  }
}

__global__ __launch_bounds__(256, 2) void gat_main(
    const unsigned short* __restrict__ htT_n, const unsigned short* __restrict__ htT_e,
    const float* __restrict__ srcN1, const float* __restrict__ srcN2,
    const float* __restrict__ tgtN1, const float* __restrict__ tgtN2,
    const float* __restrict__ srcE1, const float* __restrict__ srcE2,
    const float* __restrict__ tgtE1, const float* __restrict__ tgtE2,
    const unsigned* __restrict__ bitsN, const unsigned* __restrict__ bitsE,
    float* __restrict__ NUM_N, float* __restrict__ DEN_N,
    float* __restrict__ NUM_E, float* __restrict__ DEN_E)
{
  const int i = blockIdx.x;                     // 1024 blocks
  const int h = i & 7;
  const int tile = (i >> 3) & 63;
  const int ms = i >> 9;                        // m-split 0/1
  const int n0 = tile * 32;
  const int tid = threadIdx.x, w = tid >> 6, lane = tid & 63;
  const int r16 = lane & 15, q = lane >> 4, qo = q * 8;
  const int sh = ms * 8 + h;

  __shared__ __align__(16) float lnum[4][32][36];   // 18.4 KiB
  __shared__ float lden[4][32];
  __shared__ __align__(16) float lt1[2048];          // 8 KiB (tgt E1 window)
  __shared__ __align__(16) float lt2[2048];          // 8 KiB (tgt E2 window)

  s16x8 ones;
#pragma unroll
  for (int j = 0; j < 8; ++j) ones[j] = (short)0x3F80;    // bf16 1.0

  f32x4 acc[2][4], accd[2];

  // ---------------- nodes part: 4 steps, m window = 1024 ----------------
  {
    // stage tgt E window [ms*1024, ms*1024+1024) into LDS
    {
      int base = h * N_NODES + ms * 1024 + tid * 4;
      *(float4*)&lt1[tid * 4] = *(const float4*)&tgtN1[base];
      *(float4*)&lt2[tid * 4] = *(const float4*)&tgtN2[base];
    }
    __syncthreads();
    float e1n0 = srcN1[h * N_NODES + n0 + r16];
    float e2n0 = srcN2[h * N_NODES + n0 + r16];
    float e1n1 = srcN1[h * N_NODES + n0 + 16 + r16];
    float e2n1 = srcN2[h * N_NODES + n0 + 16 + r16];
    gat_part32<4>(bitsN, N_NODES / 32,
                  lt1 + w * 256, lt2 + w * 256,
                  htT_n + (size_t)h * (N_NODES / 32) * 2048,
                  n0, ms * 1024 + w * 256, r16, qo,
                  e1n0, e2n0, e1n1, e2n1, ones, acc, accd);
    combine_store(acc, accd, lnum, lden, w, q, r16, tid, NUM_N, DEN_N, sh, n0);
  }

  // ---------------- edges part: 8 steps, m window = 2048 ----------------
  {
    __syncthreads();   // part-1 LDS reads complete before overwrite
    {
      int base = h * N_EDGES + ms * 2048 + tid * 8;
      *(float4*)&lt1[tid * 8]     = *(const float4*)&tgtE1[base];
      *(float4*)&lt1[tid * 8 + 4] = *(const float4*)&tgtE1[base + 4];
      *(float4*)&lt2[tid * 8]     = *(const float4*)&tgtE2[base];
      *(float4*)&lt2[tid * 8 + 4] = *(const float4*)&tgtE2[base + 4];
    }
    __syncthreads();
    float e1n0 = srcE1[h * N_NODES + n0 + r16];
    float e2n0 = srcE2[h * N_NODES + n0 + r16];
    float e1n1 = srcE1[h * N_NODES + n0 + 16 + r16];
    float e2n1 = srcE2[h * N_NODES + n0 + 16 + r16];
    gat_part32<8>(bitsE, N_EDGES / 32,
                  lt1 + w * 512, lt2 + w * 512,
                  htT_e + (size_t)h * (N_EDGES / 32) * 2048,
                  n0, ms * 2048 + w * 512, r16, qo,
                  e1n0, e2n0, e1n1, e2n1, ones, acc, accd);
    combine_store(acc, accd, lnum, lden, w, q, r16, tid, NUM_E, DEN_E, sh, n0);
  }
}

// ---------------------------------------------------------------------------
// Kernel D: combine 2 msplit partials, normalize, mean over heads.
// ---------------------------------------------------------------------------
__global__ __launch_bounds__(128) void reduce_out(
    const float* __restrict__ NUM_N, const float* __restrict__ DEN_N,
    const float* __restrict__ NUM_E, const float* __restrict__ DEN_E,
    float* __restrict__ out)
{
  int idx = blockIdx.x * 128 + threadIdx.x;   // 32768 threads (256 blocks)
  int n = idx >> 4, d4 = (idx & 15) * 4;
  f32x4 r = (f32x4){0.f, 0.f, 0.f, 0.f};
#pragma unroll
  for (int h = 0; h < H_HEADS; ++h) {
    f32x4 nn = *(const f32x4*)&NUM_N[((size_t)h * N_NODES + n) * 64 + d4]
             + *(const f32x4*)&NUM_N[((size_t)(8 + h) * N_NODES + n) * 64 + d4];
    float dn = DEN_N[(size_t)h * N_NODES + n] + DEN_N[(size_t)(8 + h) * N_NODES + n];
    f32x4 ne = *(const f32x4*)&NUM_E[((size_t)h * N_NODES + n) * 64 + d4]
             + *(const f32x4*)&NUM_E[((size_t)(8 + h) * N_NODES + n) * 64 + d4];
    float de = DEN_E[(size_t)h * N_NODES + n] + DEN_E[(size_t)(8 + h) * N_NODES + n];
    float idn = 1.0f / dn, ide = 1.0f / de;
    r.x += nn.x * idn + ne.x * ide;
    r.y += nn.y * idn + ne.y * ide;
    r.z += nn.z * idn + ne.z * ide;
    r.w += nn.w * idn + ne.w * ide;
  }
  f32x4 o = (f32x4){r.x * 0.125f, r.y * 0.125f, r.z * 0.125f, r.w * 0.125f};
  *(f32x4*)&out[(size_t)n * 64 + d4] = o;
}

// ---------------------------------------------------------------------------
extern "C" void kernel_launch(void* const* d_in, const int* in_sizes, int n_in,
                              void* d_out, int out_size, void* d_ws, size_t ws_size,
                              hipStream_t stream)
{
  const float* nodes = (const float*)d_in[0];
  const float* edges = (const float*)d_in[1];
  const float* WN    = (const float*)d_in[2];
  const float* WE    = (const float*)d_in[3];
  const float* aN    = (const float*)d_in[4];
  const float* aE    = (const float*)d_in[5];
  const int*   matN  = (const int*)d_in[6];
  const int*   matE  = (const int*)d_in[7];
  float* out = (float*)d_out;

  float* ws = (float*)d_ws;
  size_t o = 0;
  unsigned short* htT_n = (unsigned short*)(ws + o); o += (size_t)H_HEADS * 64 * N_NODES / 2;  // 2MB
  unsigned short* htT_e = (unsigned short*)(ws + o); o += (size_t)H_HEADS * 64 * N_EDGES / 2;  // 4MB
  unsigned* bitsN = (unsigned*)(ws + o); o += (size_t)N_NODES * (N_NODES / 32);                // 512KB
  unsigned* bitsE = (unsigned*)(ws + o); o += (size_t)N_NODES * (N_EDGES / 32);                // 1MB
  float* srcN  = ws + o;  o += (size_t)H_HEADS * N_NODES;
  float* tgtN  = ws + o;  o += (size_t)H_HEADS * N_NODES;
  float* srcE  = ws + o;  o += (size_t)H_HEADS * N_NODES;
  float* tgtE  = ws + o;  o += (size_t)H_HEADS * N_EDGES;
  float* srcN1 = ws + o;  o += (size_t)H_HEADS * N_NODES;
  float* srcN2 = ws + o;  o += (size_t)H_HEADS * N_NODES;
  float* tgtN1 = ws + o;  o += (size_t)H_HEADS * N_NODES;
  float* tgtN2 = ws + o;  o += (size_t)H_HEADS * N_NODES;
  float* srcE1 = ws + o;  o += (size_t)H_HEADS * N_NODES;
  float* srcE2 = ws + o;  o += (size_t)H_HEADS * N_NODES;
  float* tgtE1 = ws + o;  o += (size_t)H_HEADS * N_EDGES;
  float* tgtE2 = ws + o;  o += (size_t)H_HEADS * N_EDGES;
  float* NUM_N = ws + o;  o += (size_t)2 * H_HEADS * N_NODES * 64;   // 8MB
  float* DEN_N = ws + o;  o += (size_t)2 * H_HEADS * N_NODES;
  float* NUM_E = ws + o;  o += (size_t)2 * H_HEADS * N_NODES * 64;   // 8MB
  float* DEN_E = ws + o;  o += (size_t)2 * H_HEADS * N_NODES;

  hipLaunchKernelGGL(front, dim3(2304), dim3(256), 0, stream,
                     nodes, edges, WN, WE, aN, aE, matN, matE, bitsN, bitsE,
                     htT_n, htT_e, srcN, tgtN, srcE, tgtE);
  hipLaunchKernelGGL(expify, dim3(320), dim3(256), 0, stream,
                     srcN, tgtN, srcE, tgtE,
                     srcN1, srcN2, tgtN1, tgtN2, srcE1, srcE2, tgtE1, tgtE2);
  hipLaunchKernelGGL(gat_main, dim3(1024), dim3(256), 0, stream,
                     htT_n, htT_e, srcN1, srcN2, tgtN1, tgtN2,
                     srcE1, srcE2, tgtE1, tgtE2, bitsN, bitsE,
                     NUM_N, DEN_N, NUM_E, DEN_E);
  hipLaunchKernelGGL(reduce_out, dim3(256), dim3(128), 0, stream,
                     NUM_N, DEN_N, NUM_E, DEN_E, out);
}

// Round 21
// 77.427 us; speedup vs baseline: 1.3540x; 1.0707x over previous
//
#include <hip/hip_runtime.h>
#include <hip/hip_bf16.h>

#define N_NODES 2048
#define N_EDGES 4096
#define F_IN    256
#define H_HEADS 8
#define HD      512
#define LOG2E   1.44269504088896f

typedef __attribute__((ext_vector_type(4))) float f32x4;
typedef __attribute__((ext_vector_type(8))) short s16x8;
typedef __attribute__((ext_vector_type(4))) unsigned u32x4;

static __device__ __forceinline__ unsigned short f2bf(float x) {
  union { float f; unsigned u; } v; v.f = x;
  unsigned r = v.u + 0x7fff + ((v.u >> 16) & 1);   // RNE
  return (unsigned short)(r >> 16);
}
static __device__ __forceinline__ float bf2f(unsigned short h) {
  union { unsigned u; float f; } v; v.u = ((unsigned)h) << 16;
  return v.f;
}
static __device__ __forceinline__ unsigned cvtpk(float lo, float hi) {
  unsigned r;
  asm("v_cvt_pk_bf16_f32 %0, %1, %2" : "=v"(r) : "v"(lo), "v"(hi));
  return r;
}

// ---------------------------------------------------------------------------
// Kernel A: bit-pack masks (standalone).
// ---------------------------------------------------------------------------
__global__ __launch_bounds__(256) void pack_masks(
    const int* __restrict__ matN, const int* __restrict__ matE,
    unsigned* __restrict__ bitsN, unsigned* __restrict__ bitsE)
{
  int t = blockIdx.x * 256 + threadIdx.x;      // 393216 threads
  const int* src; unsigned* dst;
  if (t < N_NODES * (N_NODES / 32)) {
    int row = t >> 6, w = t & 63;
    src = &matN[(size_t)row * N_NODES + w * 32]; dst = &bitsN[t];
  } else {
    int tt = t - N_NODES * (N_NODES / 32);
    int row = tt >> 7, w = tt & 127;
    src = &matE[(size_t)row * N_EDGES + w * 32]; dst = &bitsE[tt];
  }
  unsigned b = 0;
#pragma unroll
  for (int k = 7; k >= 0; --k) {
    int4 v = *(const int4*)&src[k * 4];
    b = (b << 1) | ((unsigned)v.w & 1u);
    b = (b << 1) | ((unsigned)v.z & 1u);
    b = (b << 1) | ((unsigned)v.y & 1u);
    b = (b << 1) | ((unsigned)v.x & 1u);
  }
  *dst = b;
}

// ---------------------------------------------------------------------------
// Kernel A2: prep2 — split into hi/lo bf16, MFMA-fragment-swizzled layouts:
//   X2[rblk][kb][lane][8]:  row = rblk*16+(lane&15), k = kb*32+(lane>>4)*8+j
//   W2[mat][h][dt][kb][lane][8]: col = h*64+dt*16+(lane&15), same k mapping
// X: 196608 threads. W: 32768 threads (2*8*4*8*64).  Grid = 896 blocks.
// ---------------------------------------------------------------------------
__global__ __launch_bounds__(256) void prep2(
    const float* __restrict__ nodes, const float* __restrict__ edges,
    const float* __restrict__ WN, const float* __restrict__ WE,
    unsigned short* __restrict__ X2hi, unsigned short* __restrict__ X2lo,
    unsigned short* __restrict__ W2hi, unsigned short* __restrict__ W2lo)
{
  int t = blockIdx.x * 256 + threadIdx.x;
  if (t < 196608) {                            // X: 384 rblk x 8 kb x 64 lane
    int lane = t & 63, kb = (t >> 6) & 7, rblk = t >> 9;
    int row = rblk * 16 + (lane & 15);
    int k0  = kb * 32 + (lane >> 4) * 8;
    const float* src = (row < N_NODES)
                     ? &nodes[(size_t)row * F_IN + k0]
                     : &edges[(size_t)(row - N_NODES) * F_IN + k0];
    float4 a = *(const float4*)src;
    float4 c = *(const float4*)(src + 4);
    float v[8] = {a.x, a.y, a.z, a.w, c.x, c.y, c.z, c.w};
    s16x8 hi, lo;
#pragma unroll
    for (int j = 0; j < 8; ++j) {
      unsigned short h = f2bf(v[j]);
      hi[j] = (short)h;
      lo[j] = (short)f2bf(v[j] - bf2f(h));
    }
    *(s16x8*)&X2hi[(size_t)t * 8] = hi;
    *(s16x8*)&X2lo[(size_t)t * 8] = lo;
  } else if (t < 229376) {                     // W: 32768 threads
    int wt = t - 196608;
    int lane = wt & 63, kb = (wt >> 6) & 7, dt = (wt >> 9) & 3;
    int hh = (wt >> 11) & 7, mat = wt >> 14;
    const float* W = mat ? WE : WN;
    int k0  = kb * 32 + (lane >> 4) * 8;
    int col = hh * 64 + dt * 16 + (lane & 15);
    s16x8 hi, lo;
#pragma unroll
    for (int j = 0; j < 8; ++j) {
      float v = W[(size_t)(k0 + j) * HD + col];
      unsigned short h = f2bf(v);
      hi[j] = (short)h;
      lo[j] = (short)f2bf(v - bf2f(h));
    }
    *(s16x8*)&W2hi[(size_t)wt * 8] = hi;
    *(s16x8*)&W2lo[(size_t)wt * 8] = lo;
  }
}

// ---------------------------------------------------------------------------
// Kernel B: MFMA ht-GEMM (split-bf16 x3, pure-register, coalesced swizzled
// operands) + bf16 tiled transpose-out + score vectors (xLOG2E).
// ---------------------------------------------------------------------------
__global__ __launch_bounds__(256) void gemm_fused(
    const unsigned short* __restrict__ X2hi, const unsigned short* __restrict__ X2lo,
    const unsigned short* __restrict__ W2hi, const unsigned short* __restrict__ W2lo,
    const float* __restrict__ aN, const float* __restrict__ aE,
    unsigned short* __restrict__ htT_n, unsigned short* __restrict__ htT_e,
    float* __restrict__ srcN, float* __restrict__ tgtN,
    float* __restrict__ srcE, float* __restrict__ tgtE)
{
  const int rt = blockIdx.x;   // 0..31 nodes, 32..95 edges
  const int h  = blockIdx.y;   // head
  const bool isNode = (rt < 32);
  const int r0 = (isNode ? rt : rt - 32) * 64;
  const int rowg = (isNode ? 0 : N_NODES) + r0;
  const int MT = (isNode ? N_NODES : N_EDGES) / 32;

  __shared__ __align__(16) float T[64][68];    // T[d][m_local]

  const int tid = threadIdx.x;
  const int w = tid >> 6, l = tid & 63;
  const int r16 = l & 15;

  const size_t abase = ((size_t)((rowg >> 4) + w)) * 4096 + l * 8;
  const unsigned short* Ah = &X2hi[abase];
  const unsigned short* Al = &X2lo[abase];
  const size_t wbase = ((size_t)((isNode ? 0 : 1) * 8 + h)) * 16384 + l * 8;
  const unsigned short* WH = &W2hi[wbase];
  const unsigned short* WL = &W2lo[wbase];

  f32x4 acc[4];
#pragma unroll
  for (int dt = 0; dt < 4; ++dt) acc[dt] = (f32x4){0.f, 0.f, 0.f, 0.f};

#pragma unroll
  for (int kb = 0; kb < 8; ++kb) {
    s16x8 ahi = *(const s16x8*)&Ah[kb * 512];
    s16x8 alo = *(const s16x8*)&Al[kb * 512];
#pragma unroll
    for (int dt = 0; dt < 4; ++dt) {
      s16x8 bhi = *(const s16x8*)&WH[(dt * 8 + kb) * 512];
      s16x8 blo = *(const s16x8*)&WL[(dt * 8 + kb) * 512];
      acc[dt] = __builtin_amdgcn_mfma_f32_16x16x32_bf16(ahi, bhi, acc[dt], 0, 0, 0);
      acc[dt] = __builtin_amdgcn_mfma_f32_16x16x32_bf16(ahi, blo, acc[dt], 0, 0, 0);
      acc[dt] = __builtin_amdgcn_mfma_f32_16x16x32_bf16(alo, bhi, acc[dt], 0, 0, 0);
    }
  }

  // C[m_local = 16w + (l>>4)*4 + reg][d = dt*16 + r16] -> T[d][m_local]
#pragma unroll
  for (int dt = 0; dt < 4; ++dt)
#pragma unroll
    for (int reg = 0; reg < 4; ++reg)
      T[dt * 16 + r16][16 * w + (l >> 4) * 4 + reg] = acc[dt][reg];
  __syncthreads();

  // bf16 tiled transposed write: htT2[h][mblk][d][m%32]
  {
    int d = tid >> 2, mq = tid & 3;
    s16x8 o0, o1;
#pragma unroll
    for (int k = 0; k < 8; ++k) o0[k] = (short)f2bf(T[d][mq * 16 + k]);
#pragma unroll
    for (int k = 0; k < 8; ++k) o1[k] = (short)f2bf(T[d][mq * 16 + 8 + k]);
    unsigned short* dst = isNode ? htT_n : htT_e;
    int mb0 = r0 >> 5;
    size_t base = (size_t)h * MT * 2048 + (size_t)(mb0 + (mq >> 1)) * 2048
                + d * 32 + (mq & 1) * 16;
    *(s16x8*)&dst[base] = o0;
    *(s16x8*)&dst[base + 8] = o1;
  }

  // score vectors, pre-scaled by LOG2E
  {
    int r = tid >> 2, q4 = tid & 3;
    float tr[16];
#pragma unroll
    for (int k = 0; k < 16; ++k) tr[k] = T[q4 * 16 + k][r];
    if (isNode) {
      float s1 = 0.f, s2 = 0.f, s3 = 0.f;
#pragma unroll
      for (int k = 0; k < 16; ++k) {
        s1 = fmaf(tr[k], aN[h * 128 + q4 * 16 + k], s1);
        s2 = fmaf(tr[k], aN[h * 128 + 64 + q4 * 16 + k], s2);
        s3 = fmaf(tr[k], aE[h * 128 + q4 * 16 + k], s3);
      }
      s1 += __shfl_xor(s1, 1); s1 += __shfl_xor(s1, 2);
      s2 += __shfl_xor(s2, 1); s2 += __shfl_xor(s2, 2);
      s3 += __shfl_xor(s3, 1); s3 += __shfl_xor(s3, 2);
      if (q4 == 0) {
        srcN[h * N_NODES + r0 + r] = s1 * LOG2E;
        tgtN[h * N_NODES + r0 + r] = s2 * LOG2E;
        srcE[h * N_NODES + r0 + r] = s3 * LOG2E;
      }
    } else {
      float s4 = 0.f;
#pragma unroll
      for (int k = 0; k < 16; ++k)
        s4 = fmaf(tr[k], aE[h * 128 + 64 + q4 * 16 + k], s4);
      s4 += __shfl_xor(s4, 1); s4 += __shfl_xor(s4, 2);
      if (q4 == 0) tgtE[h * N_EDGES + r0 + r] = s4 * LOG2E;
    }
  }
}

// ---------------------------------------------------------------------------
// Kernel B2: expify — scores -> factorized exp pairs.
// ---------------------------------------------------------------------------
__global__ __launch_bounds__(256) void expify(
    const float* __restrict__ srcN, const float* __restrict__ tgtN,
    const float* __restrict__ srcE, const float* __restrict__ tgtE,
    float* __restrict__ srcN1, float* __restrict__ srcN2,
    float* __restrict__ tgtN1, float* __restrict__ tgtN2,
    float* __restrict__ srcE1, float* __restrict__ srcE2,
    float* __restrict__ tgtE1, float* __restrict__ tgtE2)
{
  int t = blockIdx.x * 256 + threadIdx.x;   // 81920 threads
  const float* in; float* o1; float* o2; int idx;
  if (t < 16384)      { in = srcN; o1 = srcN1; o2 = srcN2; idx = t; }
  else if (t < 32768) { in = tgtN; o1 = tgtN1; o2 = tgtN2; idx = t - 16384; }
  else if (t < 49152) { in = srcE; o1 = srcE1; o2 = srcE2; idx = t - 32768; }
  else                { in = tgtE; o1 = tgtE1; o2 = tgtE2; idx = t - 49152; }
  float s = in[idx];
  o1[idx] = __builtin_amdgcn_exp2f(s);
  o2[idx] = __builtin_amdgcn_exp2f(0.2f * s);
}

// ---------------------------------------------------------------------------
// Kernel C: main GAT (R19-exact: tgt E-pairs staged in LDS).
// ---------------------------------------------------------------------------
struct StepIn {
  unsigned wd00, wd01, wd10, wd11;
  float4 ta1, tb1, tc1, td1;
  float4 ta2, tb2, tc2, td2;
  s16x8 bf0, bf1, bf2, bf3;
  s16x8 bf4, bf5, bf6, bf7;
};

template<int REL>
__device__ __forceinline__ StepIn load_step(
    const unsigned* __restrict__ br0, const unsigned* __restrict__ br1,
    const float* t1, const float* t2,
    const unsigned short* __restrict__ hb0,
    const unsigned short* __restrict__ hb1)
{
  StepIn s;
  s.wd00 = br0[REL * 2]; s.wd01 = br0[REL * 2 + 1];
  s.wd10 = br1[REL * 2]; s.wd11 = br1[REL * 2 + 1];
  s.ta1 = *(const float4*)&t1[REL * 64];
  s.tb1 = *(const float4*)&t1[REL * 64 + 4];
  s.tc1 = *(const float4*)&t1[REL * 64 + 32];
  s.td1 = *(const float4*)&t1[REL * 64 + 36];
  s.ta2 = *(const float4*)&t2[REL * 64];
  s.tb2 = *(const float4*)&t2[REL * 64 + 4];
  s.tc2 = *(const float4*)&t2[REL * 64 + 32];
  s.td2 = *(const float4*)&t2[REL * 64 + 36];
  const unsigned short* hb = REL ? hb1 : hb0;
  s.bf0 = *(const s16x8*)&hb[0 * 512];
  s.bf1 = *(const s16x8*)&hb[1 * 512];
  s.bf2 = *(const s16x8*)&hb[2 * 512];
  s.bf3 = *(const s16x8*)&hb[3 * 512];
  s.bf4 = *(const s16x8*)&hb[2048 + 0 * 512];
  s.bf5 = *(const s16x8*)&hb[2048 + 1 * 512];
  s.bf6 = *(const s16x8*)&hb[2048 + 2 * 512];
  s.bf7 = *(const s16x8*)&hb[2048 + 3 * 512];
  return s;
}

__device__ __forceinline__ void compute_step(
    const StepIn& sI, int qo,
    float e1n0, float e2n0, float e1n1, float e2n1, s16x8 ones,
    f32x4 acc[2][4], f32x4 accd[2])
{
  s16x8 afr[2][2];
#pragma unroll
  for (int nt = 0; nt < 2; ++nt) {
    float e1n = nt ? e1n1 : e1n0;
    float e2n = nt ? e2n1 : e2n0;
#pragma unroll
    for (int ks = 0; ks < 2; ++ks) {
      unsigned wdw = nt ? (ks ? sI.wd11 : sI.wd10) : (ks ? sI.wd01 : sI.wd00);
      unsigned wq = wdw >> qo;
      float4 u1 = ks ? sI.tc1 : sI.ta1;
      float4 v1 = ks ? sI.td1 : sI.tb1;
      float4 u2 = ks ? sI.tc2 : sI.ta2;
      float4 v2 = ks ? sI.td2 : sI.tb2;
      float m1[8] = {u1.x, u1.y, u1.z, u1.w, v1.x, v1.y, v1.z, v1.w};
      float m2[8] = {u2.x, u2.y, u2.z, u2.w, v2.x, v2.y, v2.z, v2.w};
      float wv[8];
#pragma unroll
      for (int j = 0; j < 8; ++j) {
        float p1 = e1n * m1[j];
        float p2 = e2n * m2[j];
        float mx = fmaxf(p1, p2);               // = exp(lrelu(e)) by monotonicity
        int msk = -(int)((wq >> j) & 1u);       // 0 or 0xFFFFFFFF (portable)
        wv[j] = __int_as_float(msk & __float_as_int(mx));
      }
      u32x4 p;
      p[0] = cvtpk(wv[0], wv[1]);
      p[1] = cvtpk(wv[2], wv[3]);
      p[2] = cvtpk(wv[4], wv[5]);
      p[3] = cvtpk(wv[6], wv[7]);
      afr[nt][ks] = __builtin_bit_cast(s16x8, p);
    }
  }
  acc[0][0] = __builtin_amdgcn_mfma_f32_16x16x32_bf16(afr[0][0], sI.bf0, acc[0][0], 0, 0, 0);
  acc[0][1] = __builtin_amdgcn_mfma_f32_16x16x32_bf16(afr[0][0], sI.bf1, acc[0][1], 0, 0, 0);
  acc[0][2] = __builtin_amdgcn_mfma_f32_16x16x32_bf16(afr[0][0], sI.bf2, acc[0][2], 0, 0, 0);
  acc[0][3] = __builtin_amdgcn_mfma_f32_16x16x32_bf16(afr[0][0], sI.bf3, acc[0][3], 0, 0, 0);
  accd[0]   = __builtin_amdgcn_mfma_f32_16x16x32_bf16(afr[0][0], ones,   accd[0],   0, 0, 0);
  acc[1][0] = __builtin_amdgcn_mfma_f32_16x16x32_bf16(afr[1][0], sI.bf0, acc[1][0], 0, 0, 0);
  acc[1][1] = __builtin_amdgcn_mfma_f32_16x16x32_bf16(afr[1][0], sI.bf1, acc[1][1], 0, 0, 0);
  acc[1][2] = __builtin_amdgcn_mfma_f32_16x16x32_bf16(afr[1][0], sI.bf2, acc[1][2], 0, 0, 0);
  acc[1][3] = __builtin_amdgcn_mfma_f32_16x16x32_bf16(afr[1][0], sI.bf3, acc[1][3], 0, 0, 0);
  accd[1]   = __builtin_amdgcn_mfma_f32_16x16x32_bf16(afr[1][0], ones,   accd[1],   0, 0, 0);
  acc[0][0] = __builtin_amdgcn_mfma_f32_16x16x32_bf16(afr[0][1], sI.bf4, acc[0][0], 0, 0, 0);
  acc[0][1] = __builtin_amdgcn_mfma_f32_16x16x32_bf16(afr[0][1], sI.bf5, acc[0][1], 0, 0, 0);
  acc[0][2] = __builtin_amdgcn_mfma_f32_16x16x32_bf16(afr[0][1], sI.bf6, acc[0][2], 0, 0, 0);
  acc[0][3] = __builtin_amdgcn_mfma_f32_16x16x32_bf16(afr[0][1], sI.bf7, acc[0][3], 0, 0, 0);
  accd[0]   = __builtin_amdgcn_mfma_f32_16x16x32_bf16(afr[0][1], ones,   accd[0],   0, 0, 0);
  acc[1][0] = __builtin_amdgcn_mfma_f32_16x16x32_bf16(afr[1][1], sI.bf4, acc[1][0], 0, 0, 0);
  acc[1][1] = __builtin_amdgcn_mfma_f32_16x16x32_bf16(afr[1][1], sI.bf5, acc[1][1], 0, 0, 0);
  acc[1][2] = __builtin_amdgcn_mfma_f32_16x16x32_bf16(afr[1][1], sI.bf6, acc[1][2], 0, 0, 0);
  acc[1][3] = __builtin_amdgcn_mfma_f32_16x16x32_bf16(afr[1][1], sI.bf7, acc[1][3], 0, 0, 0);
  accd[1]   = __builtin_amdgcn_mfma_f32_16x16x32_bf16(afr[1][1], ones,   accd[1],   0, 0, 0);
}

template<int NSTEPS>
__device__ __forceinline__ void gat_part32(
    const unsigned* __restrict__ bits, int MT,
    const float* lds_t1, const float* lds_t2,
    const unsigned short* __restrict__ htT_h,
    int n0, int m_begin, int r16, int qo,
    float e1n0, float e2n0, float e1n1, float e2n1, s16x8 ones,
    f32x4 acc[2][4], f32x4 accd[2])
{
#pragma unroll
  for (int nt = 0; nt < 2; ++nt) {
    accd[nt] = (f32x4){0.f, 0.f, 0.f, 0.f};
#pragma unroll
    for (int dt = 0; dt < 4; ++dt) acc[nt][dt] = (f32x4){0.f, 0.f, 0.f, 0.f};
  }
  int mb0 = m_begin >> 5;
  const unsigned* br0 = &bits[(size_t)(n0 + r16) * MT + mb0];
  const unsigned* br1 = &bits[(size_t)(n0 + 16 + r16) * MT + mb0];
  const float* t1 = lds_t1 + qo;
  const float* t2 = lds_t2 + qo;
  const unsigned short* hb0 = &htT_h[(size_t)mb0 * 2048 + r16 * 32 + qo];
  const unsigned short* hb1 = hb0 + 4096;

  StepIn sA = load_step<0>(br0, br1, t1, t2, hb0, hb1);
#pragma unroll
  for (int st = 0; st < NSTEPS - 2; st += 2) {
    StepIn sB = load_step<1>(br0, br1, t1, t2, hb0, hb1);
    br0 += 4; br1 += 4; t1 += 128; t2 += 128; hb0 += 8192; hb1 += 8192;
    compute_step(sA, qo, e1n0, e2n0, e1n1, e2n1, ones, acc, accd);
    sA = load_step<0>(br0, br1, t1, t2, hb0, hb1);
    compute_step(sB, qo, e1n0, e2n0, e1n1, e2n1, ones, acc, accd);
  }
  StepIn sB = load_step<1>(br0, br1, t1, t2, hb0, hb1);
  compute_step(sA, qo, e1n0, e2n0, e1n1, e2n1, ones, acc, accd);
  compute_step(sB, qo, e1n0, e2n0, e1n1, e2n1, ones, acc, accd);
}

// two-pass (d-half) combine + global store
__device__ __forceinline__ void combine_store(
    f32x4 acc[2][4], f32x4 accd[2],
    float lnum[4][32][36], float lden[4][32],
    int w, int q, int r16, int tid,
    float* __restrict__ NUM, float* __restrict__ DEN, int sh, int n0)
{
  const int crow = tid >> 3, cd4 = (tid & 7) * 4;
#pragma unroll
  for (int pass = 0; pass < 2; ++pass) {
    __syncthreads();
#pragma unroll
    for (int nt = 0; nt < 2; ++nt)
#pragma unroll
      for (int dtl = 0; dtl < 2; ++dtl)
#pragma unroll
        for (int qi = 0; qi < 4; ++qi)
          lnum[w][nt * 16 + q * 4 + qi][dtl * 16 + r16] =
              acc[nt][pass * 2 + dtl][qi];
    if (pass == 0 && r16 == 0) {
#pragma unroll
      for (int nt = 0; nt < 2; ++nt)
#pragma unroll
        for (int qi = 0; qi < 4; ++qi)
          lden[w][nt * 16 + q * 4 + qi] = accd[nt][qi];
    }
    __syncthreads();
    f32x4 s = (f32x4){0.f, 0.f, 0.f, 0.f};
#pragma unroll
    for (int ww = 0; ww < 4; ++ww) s += *(const f32x4*)&lnum[ww][crow][cd4];
    *(f32x4*)&NUM[((size_t)sh * N_NODES + n0 + crow) * 64 + pass * 32 + cd4] = s;
    if (pass == 0 && (tid & 7) == 0) {
      float dsum = lden[0][crow] + lden[1][crow] + lden[2][crow] + lden[3][crow];
      DEN[(size_t)sh * N_NODES + n0 + crow] = dsum;
    }
  }
}

__global__ __launch_bounds__(256, 2) void gat_main(
    const unsigned short* __restrict__ htT_n, const unsigned short* __restrict__ htT_e,
    const float* __restrict__ srcN1, const float* __restrict__ srcN2,
    const float* __restrict__ tgtN1, const float* __restrict__ tgtN2,
    const float* __restrict__ srcE1, const float* __restrict__ srcE2,
    const float* __restrict__ tgtE1, const float* __restrict__ tgtE2,
    const unsigned* __restrict__ bitsN, const unsigned* __restrict__ bitsE,
    float* __restrict__ NUM_N, float* __restrict__ DEN_N,
    float* __restrict__ NUM_E, float* __restrict__ DEN_E)
{
  const int i = blockIdx.x;                     // 1024 blocks
  const int h = i & 7;
  const int tile = (i >> 3) & 63;
  const int ms = i >> 9;                        // m-split 0/1
  const int n0 = tile * 32;
  const int tid = threadIdx.x, w = tid >> 6, lane = tid & 63;
  const int r16 = lane & 15, q = lane >> 4, qo = q * 8;
  const int sh = ms * 8 + h;

  __shared__ __align__(16) float lnum[4][32][36];   // 18.4 KiB
  __shared__ float lden[4][32];
  __shared__ __align__(16) float lt1[2048];          // 8 KiB
  __shared__ __align__(16) float lt2[2048];          // 8 KiB

  s16x8 ones;
#pragma unroll
  for (int j = 0; j < 8; ++j) ones[j] = (short)0x3F80;    // bf16 1.0

  f32x4 acc[2][4], accd[2];

  // ---------------- nodes part: 4 steps, m window = 1024 ----------------
  {
    {
      int base = h * N_NODES + ms * 1024 + tid * 4;
      *(float4*)&lt1[tid * 4] = *(const float4*)&tgtN1[base];
      *(float4*)&lt2[tid * 4] = *(const float4*)&tgtN2[base];
    }
    __syncthreads();
    float e1n0 = srcN1[h * N_NODES + n0 + r16];
    float e2n0 = srcN2[h * N_NODES + n0 + r16];
    float e1n1 = srcN1[h * N_NODES + n0 + 16 + r16];
    float e2n1 = srcN2[h * N_NODES + n0 + 16 + r16];
    gat_part32<4>(bitsN, N_NODES / 32,
                  lt1 + w * 256, lt2 + w * 256,
                  htT_n + (size_t)h * (N_NODES / 32) * 2048,
                  n0, ms * 1024 + w * 256, r16, qo,
                  e1n0, e2n0, e1n1, e2n1, ones, acc, accd);
    combine_store(acc, accd, lnum, lden, w, q, r16, tid, NUM_N, DEN_N, sh, n0);
  }

  // ---------------- edges part: 8 steps, m window = 2048 ----------------
  {
    __syncthreads();
    {
      int base = h * N_EDGES + ms * 2048 + tid * 8;
      *(float4*)&lt1[tid * 8]     = *(const float4*)&tgtE1[base];
      *(float4*)&lt1[tid * 8 + 4] = *(const float4*)&tgtE1[base + 4];
      *(float4*)&lt2[tid * 8]     = *(const float4*)&tgtE2[base];
      *(float4*)&lt2[tid * 8 + 4] = *(const float4*)&tgtE2[base + 4];
    }
    __syncthreads();
    float e1n0 = srcE1[h * N_NODES + n0 + r16];
    float e2n0 = srcE2[h * N_NODES + n0 + r16];
    float e1n1 = srcE1[h * N_NODES + n0 + 16 + r16];
    float e2n1 = srcE2[h * N_NODES + n0 + 16 + r16];
    gat_part32<8>(bitsE, N_EDGES / 32,
                  lt1 + w * 512, lt2 + w * 512,
                  htT_e + (size_t)h * (N_EDGES / 32) * 2048,
                  n0, ms * 2048 + w * 512, r16, qo,
                  e1n0, e2n0, e1n1, e2n1, ones, acc, accd);
    combine_store(acc, accd, lnum, lden, w, q, r16, tid, NUM_E, DEN_E, sh, n0);
  }
}

// ---------------------------------------------------------------------------
// Kernel D: combine 2 msplit partials, normalize, mean over heads.
// ---------------------------------------------------------------------------
__global__ __launch_bounds__(128) void reduce_out(
    const float* __restrict__ NUM_N, const float* __restrict__ DEN_N,
    const float* __restrict__ NUM_E, const float* __restrict__ DEN_E,
    float* __restrict__ out)
{
  int idx = blockIdx.x * 128 + threadIdx.x;   // 32768 threads (256 blocks)
  int n = idx >> 4, d4 = (idx & 15) * 4;
  f32x4 r = (f32x4){0.f, 0.f, 0.f, 0.f};
#pragma unroll
  for (int h = 0; h < H_HEADS; ++h) {
    f32x4 nn = *(const f32x4*)&NUM_N[((size_t)h * N_NODES + n) * 64 + d4]
             + *(const f32x4*)&NUM_N[((size_t)(8 + h) * N_NODES + n) * 64 + d4];
    float dn = DEN_N[(size_t)h * N_NODES + n] + DEN_N[(size_t)(8 + h) * N_NODES + n];
    f32x4 ne = *(const f32x4*)&NUM_E[((size_t)h * N_NODES + n) * 64 + d4]
             + *(const f32x4*)&NUM_E[((size_t)(8 + h) * N_NODES + n) * 64 + d4];
    float de = DEN_E[(size_t)h * N_NODES + n] + DEN_E[(size_t)(8 + h) * N_NODES + n];
    float idn = 1.0f / dn, ide = 1.0f / de;
    r.x += nn.x * idn + ne.x * ide;
    r.y += nn.y * idn + ne.y * ide;
    r.z += nn.z * idn + ne.z * ide;
    r.w += nn.w * idn + ne.w * ide;
  }
  f32x4 o = (f32x4){r.x * 0.125f, r.y * 0.125f, r.z * 0.125f, r.w * 0.125f};
  *(f32x4*)&out[(size_t)n * 64 + d4] = o;
}

// ---------------------------------------------------------------------------
extern "C" void kernel_launch(void* const* d_in, const int* in_sizes, int n_in,
                              void* d_out, int out_size, void* d_ws, size_t ws_size,
                              hipStream_t stream)
{
  const float* nodes = (const float*)d_in[0];
  const float* edges = (const float*)d_in[1];
  const float* WN    = (const float*)d_in[2];
  const float* WE    = (const float*)d_in[3];
  const float* aN    = (const float*)d_in[4];
  const float* aE    = (const float*)d_in[5];
  const int*   matN  = (const int*)d_in[6];
  const int*   matE  = (const int*)d_in[7];
  float* out = (float*)d_out;

  float* ws = (float*)d_ws;
  size_t o = 0;
  unsigned short* htT_n = (unsigned short*)(ws + o); o += (size_t)H_HEADS * 64 * N_NODES / 2;  // 2MB
  unsigned short* htT_e = (unsigned short*)(ws + o); o += (size_t)H_HEADS * 64 * N_EDGES / 2;  // 4MB
  unsigned* bitsN = (unsigned*)(ws + o); o += (size_t)N_NODES * (N_NODES / 32);                // 512KB
  unsigned* bitsE = (unsigned*)(ws + o); o += (size_t)N_NODES * (N_EDGES / 32);                // 1MB
  unsigned short* X2hi = (unsigned short*)(ws + o); o += (size_t)6144 * 256 / 2;               // 3MB
  unsigned short* X2lo = (unsigned short*)(ws + o); o += (size_t)6144 * 256 / 2;               // 3MB
  unsigned short* W2hi = (unsigned short*)(ws + o); o += (size_t)2 * 512 * 256 / 2;            // 512KB
  unsigned short* W2lo = (unsigned short*)(ws + o); o += (size_t)2 * 512 * 256 / 2;            // 512KB
  float* srcN  = ws + o;  o += (size_t)H_HEADS * N_NODES;
  float* tgtN  = ws + o;  o += (size_t)H_HEADS * N_NODES;
  float* srcE  = ws + o;  o += (size_t)H_HEADS * N_NODES;
  float* tgtE  = ws + o;  o += (size_t)H_HEADS * N_EDGES;
  float* srcN1 = ws + o;  o += (size_t)H_HEADS * N_NODES;
  float* srcN2 = ws + o;  o += (size_t)H_HEADS * N_NODES;
  float* tgtN1 = ws + o;  o += (size_t)H_HEADS * N_NODES;
  float* tgtN2 = ws + o;  o += (size_t)H_HEADS * N_NODES;
  float* srcE1 = ws + o;  o += (size_t)H_HEADS * N_NODES;
  float* srcE2 = ws + o;  o += (size_t)H_HEADS * N_NODES;
  float* tgtE1 = ws + o;  o += (size_t)H_HEADS * N_EDGES;
  float* tgtE2 = ws + o;  o += (size_t)H_HEADS * N_EDGES;
  float* NUM_N = ws + o;  o += (size_t)2 * H_HEADS * N_NODES * 64;   // 8MB
  float* DEN_N = ws + o;  o += (size_t)2 * H_HEADS * N_NODES;
  float* NUM_E = ws + o;  o += (size_t)2 * H_HEADS * N_NODES * 64;   // 8MB
  float* DEN_E = ws + o;  o += (size_t)2 * H_HEADS * N_NODES;

  hipLaunchKernelGGL(prep2, dim3(896), dim3(256), 0, stream,
                     nodes, edges, WN, WE, X2hi, X2lo, W2hi, W2lo);
  hipLaunchKernelGGL(gemm_fused, dim3(96, 8), dim3(256), 0, stream,
                     X2hi, X2lo, W2hi, W2lo, aN, aE,
                     htT_n, htT_e, srcN, tgtN, srcE, tgtE);
  hipLaunchKernelGGL(pack_masks, dim3(1536), dim3(256), 0, stream,
                     matN, matE, bitsN, bitsE);
  hipLaunchKernelGGL(expify, dim3(320), dim3(256), 0, stream,
                     srcN, tgtN, srcE, tgtE,
                     srcN1, srcN2, tgtN1, tgtN2, srcE1, srcE2, tgtE1, tgtE2);
  hipLaunchKernelGGL(gat_main, dim3(1024), dim3(256), 0, stream,
                     htT_n, htT_e, srcN1, srcN2, tgtN1, tgtN2,
                     srcE1, srcE2, tgtE1, tgtE2, bitsN, bitsE,
                     NUM_N, DEN_N, NUM_E, DEN_E);
  hipLaunchKernelGGL(reduce_out, dim3(256), dim3(128), 0, stream,
                     NUM_N, DEN_N, NUM_E, DEN_E, out);
}

// Round 22
// 73.833 us; speedup vs baseline: 1.4199x; 1.0487x over previous
//
#include <hip/hip_runtime.h>
#include <hip/hip_bf16.h>

#define N_NODES 2048
#define N_EDGES 4096
#define F_IN    256
#define H_HEADS 8
#define HD      512
#define LOG2E   1.44269504088896f

typedef __attribute__((ext_vector_type(4))) float f32x4;
typedef __attribute__((ext_vector_type(8))) short s16x8;
typedef __attribute__((ext_vector_type(4))) unsigned u32x4;

static __device__ __forceinline__ unsigned short f2bf(float x) {
  union { float f; unsigned u; } v; v.f = x;
  unsigned r = v.u + 0x7fff + ((v.u >> 16) & 1);   // RNE
  return (unsigned short)(r >> 16);
}
static __device__ __forceinline__ float bf2f(unsigned short h) {
  union { unsigned u; float f; } v; v.u = ((unsigned)h) << 16;
  return v.f;
}
static __device__ __forceinline__ unsigned cvtpk(float lo, float hi) {
  unsigned r;
  asm("v_cvt_pk_bf16_f32 %0, %1, %2" : "=v"(r) : "v"(lo), "v"(hi));
  return r;
}

// ---------------------------------------------------------------------------
// Kernel A: prep_pack — fused prep2 (blocks 0..895) + pack_masks (896..2431).
// Both LDS-free, memory-bound; streams overlap.
//   X2[rblk][kb][lane][8]:  row = rblk*16+(lane&15), k = kb*32+(lane>>4)*8+j
//   W2[mat][h][dt][kb][lane][8]: col = h*64+dt*16+(lane&15), same k mapping
// ---------------------------------------------------------------------------
__global__ __launch_bounds__(256) void prep_pack(
    const float* __restrict__ nodes, const float* __restrict__ edges,
    const float* __restrict__ WN, const float* __restrict__ WE,
    const int* __restrict__ matN, const int* __restrict__ matE,
    unsigned short* __restrict__ X2hi, unsigned short* __restrict__ X2lo,
    unsigned short* __restrict__ W2hi, unsigned short* __restrict__ W2lo,
    unsigned* __restrict__ bitsN, unsigned* __restrict__ bitsE)
{
  int t = blockIdx.x * 256 + threadIdx.x;
  if (t < 196608) {                            // X: 384 rblk x 8 kb x 64 lane
    int lane = t & 63, kb = (t >> 6) & 7, rblk = t >> 9;
    int row = rblk * 16 + (lane & 15);
    int k0  = kb * 32 + (lane >> 4) * 8;
    const float* src = (row < N_NODES)
                     ? &nodes[(size_t)row * F_IN + k0]
                     : &edges[(size_t)(row - N_NODES) * F_IN + k0];
    float4 a = *(const float4*)src;
    float4 c = *(const float4*)(src + 4);
    float v[8] = {a.x, a.y, a.z, a.w, c.x, c.y, c.z, c.w};
    s16x8 hi, lo;
#pragma unroll
    for (int j = 0; j < 8; ++j) {
      unsigned short h = f2bf(v[j]);
      hi[j] = (short)h;
      lo[j] = (short)f2bf(v[j] - bf2f(h));
    }
    *(s16x8*)&X2hi[(size_t)t * 8] = hi;
    *(s16x8*)&X2lo[(size_t)t * 8] = lo;
  } else if (t < 229376) {                     // W: 32768 threads
    int wt = t - 196608;
    int lane = wt & 63, kb = (wt >> 6) & 7, dt = (wt >> 9) & 3;
    int hh = (wt >> 11) & 7, mat = wt >> 14;
    const float* W = mat ? WE : WN;
    int k0  = kb * 32 + (lane >> 4) * 8;
    int col = hh * 64 + dt * 16 + (lane & 15);
    s16x8 hi, lo;
#pragma unroll
    for (int j = 0; j < 8; ++j) {
      float v = W[(size_t)(k0 + j) * HD + col];
      unsigned short h = f2bf(v);
      hi[j] = (short)h;
      lo[j] = (short)f2bf(v - bf2f(h));
    }
    *(s16x8*)&W2hi[(size_t)wt * 8] = hi;
    *(s16x8*)&W2lo[(size_t)wt * 8] = lo;
  } else {                                     // pack: 393216 threads
    int p = t - 229376;
    const int* src; unsigned* dst;
    if (p < N_NODES * (N_NODES / 32)) {
      int row = p >> 6, w = p & 63;
      src = &matN[(size_t)row * N_NODES + w * 32]; dst = &bitsN[p];
    } else {
      int pp = p - N_NODES * (N_NODES / 32);
      int row = pp >> 7, w = pp & 127;
      src = &matE[(size_t)row * N_EDGES + w * 32]; dst = &bitsE[pp];
    }
    unsigned b = 0;
#pragma unroll
    for (int k = 7; k >= 0; --k) {
      int4 v = *(const int4*)&src[k * 4];
      b = (b << 1) | ((unsigned)v.w & 1u);
      b = (b << 1) | ((unsigned)v.z & 1u);
      b = (b << 1) | ((unsigned)v.y & 1u);
      b = (b << 1) | ((unsigned)v.x & 1u);
    }
    *dst = b;
  }
}

// ---------------------------------------------------------------------------
// Kernel B: MFMA ht-GEMM (split-bf16 x3, pure-register, coalesced swizzled
// operands) + bf16 tiled transpose-out + score vectors (xLOG2E).  (R21-exact)
// ---------------------------------------------------------------------------
__global__ __launch_bounds__(256) void gemm_fused(
    const unsigned short* __restrict__ X2hi, const unsigned short* __restrict__ X2lo,
    const unsigned short* __restrict__ W2hi, const unsigned short* __restrict__ W2lo,
    const float* __restrict__ aN, const float* __restrict__ aE,
    unsigned short* __restrict__ htT_n, unsigned short* __restrict__ htT_e,
    float* __restrict__ srcN, float* __restrict__ tgtN,
    float* __restrict__ srcE, float* __restrict__ tgtE)
{
  const int rt = blockIdx.x;   // 0..31 nodes, 32..95 edges
  const int h  = blockIdx.y;   // head
  const bool isNode = (rt < 32);
  const int r0 = (isNode ? rt : rt - 32) * 64;
  const int rowg = (isNode ? 0 : N_NODES) + r0;
  const int MT = (isNode ? N_NODES : N_EDGES) / 32;

  __shared__ __align__(16) float T[64][68];    // T[d][m_local]

  const int tid = threadIdx.x;
  const int w = tid >> 6, l = tid & 63;
  const int r16 = l & 15;

  const size_t abase = ((size_t)((rowg >> 4) + w)) * 4096 + l * 8;
  const unsigned short* Ah = &X2hi[abase];
  const unsigned short* Al = &X2lo[abase];
  const size_t wbase = ((size_t)((isNode ? 0 : 1) * 8 + h)) * 16384 + l * 8;
  const unsigned short* WH = &W2hi[wbase];
  const unsigned short* WL = &W2lo[wbase];

  f32x4 acc[4];
#pragma unroll
  for (int dt = 0; dt < 4; ++dt) acc[dt] = (f32x4){0.f, 0.f, 0.f, 0.f};

#pragma unroll
  for (int kb = 0; kb < 8; ++kb) {
    s16x8 ahi = *(const s16x8*)&Ah[kb * 512];
    s16x8 alo = *(const s16x8*)&Al[kb * 512];
#pragma unroll
    for (int dt = 0; dt < 4; ++dt) {
      s16x8 bhi = *(const s16x8*)&WH[(dt * 8 + kb) * 512];
      s16x8 blo = *(const s16x8*)&WL[(dt * 8 + kb) * 512];
      acc[dt] = __builtin_amdgcn_mfma_f32_16x16x32_bf16(ahi, bhi, acc[dt], 0, 0, 0);
      acc[dt] = __builtin_amdgcn_mfma_f32_16x16x32_bf16(ahi, blo, acc[dt], 0, 0, 0);
      acc[dt] = __builtin_amdgcn_mfma_f32_16x16x32_bf16(alo, bhi, acc[dt], 0, 0, 0);
    }
  }

  // C[m_local = 16w + (l>>4)*4 + reg][d = dt*16 + r16] -> T[d][m_local]
#pragma unroll
  for (int dt = 0; dt < 4; ++dt)
#pragma unroll
    for (int reg = 0; reg < 4; ++reg)
      T[dt * 16 + r16][16 * w + (l >> 4) * 4 + reg] = acc[dt][reg];
  __syncthreads();

  // bf16 tiled transposed write: htT2[h][mblk][d][m%32]
  {
    int d = tid >> 2, mq = tid & 3;
    s16x8 o0, o1;
#pragma unroll
    for (int k = 0; k < 8; ++k) o0[k] = (short)f2bf(T[d][mq * 16 + k]);
#pragma unroll
    for (int k = 0; k < 8; ++k) o1[k] = (short)f2bf(T[d][mq * 16 + 8 + k]);
    unsigned short* dst = isNode ? htT_n : htT_e;
    int mb0 = r0 >> 5;
    size_t base = (size_t)h * MT * 2048 + (size_t)(mb0 + (mq >> 1)) * 2048
                + d * 32 + (mq & 1) * 16;
    *(s16x8*)&dst[base] = o0;
    *(s16x8*)&dst[base + 8] = o1;
  }

  // score vectors, pre-scaled by LOG2E
  {
    int r = tid >> 2, q4 = tid & 3;
    float tr[16];
#pragma unroll
    for (int k = 0; k < 16; ++k) tr[k] = T[q4 * 16 + k][r];
    if (isNode) {
      float s1 = 0.f, s2 = 0.f, s3 = 0.f;
#pragma unroll
      for (int k = 0; k < 16; ++k) {
        s1 = fmaf(tr[k], aN[h * 128 + q4 * 16 + k], s1);
        s2 = fmaf(tr[k], aN[h * 128 + 64 + q4 * 16 + k], s2);
        s3 = fmaf(tr[k], aE[h * 128 + q4 * 16 + k], s3);
      }
      s1 += __shfl_xor(s1, 1); s1 += __shfl_xor(s1, 2);
      s2 += __shfl_xor(s2, 1); s2 += __shfl_xor(s2, 2);
      s3 += __shfl_xor(s3, 1); s3 += __shfl_xor(s3, 2);
      if (q4 == 0) {
        srcN[h * N_NODES + r0 + r] = s1 * LOG2E;
        tgtN[h * N_NODES + r0 + r] = s2 * LOG2E;
        srcE[h * N_NODES + r0 + r] = s3 * LOG2E;
      }
    } else {
      float s4 = 0.f;
#pragma unroll
      for (int k = 0; k < 16; ++k)
        s4 = fmaf(tr[k], aE[h * 128 + 64 + q4 * 16 + k], s4);
      s4 += __shfl_xor(s4, 1); s4 += __shfl_xor(s4, 2);
      if (q4 == 0) tgtE[h * N_EDGES + r0 + r] = s4 * LOG2E;
    }
  }
}

// ---------------------------------------------------------------------------
// Kernel C: main GAT. tgt E-pairs computed by exp2 DURING LDS staging
// (expify kernel absorbed); src pairs inline.  Core loop R21-exact.
// ---------------------------------------------------------------------------
struct StepIn {
  unsigned wd00, wd01, wd10, wd11;
  float4 ta1, tb1, tc1, td1;
  float4 ta2, tb2, tc2, td2;
  s16x8 bf0, bf1, bf2, bf3;
  s16x8 bf4, bf5, bf6, bf7;
};

template<int REL>
__device__ __forceinline__ StepIn load_step(
    const unsigned* __restrict__ br0, const unsigned* __restrict__ br1,
    const float* t1, const float* t2,
    const unsigned short* __restrict__ hb0,
    const unsigned short* __restrict__ hb1)
{
  StepIn s;
  s.wd00 = br0[REL * 2]; s.wd01 = br0[REL * 2 + 1];
  s.wd10 = br1[REL * 2]; s.wd11 = br1[REL * 2 + 1];
  s.ta1 = *(const float4*)&t1[REL * 64];
  s.tb1 = *(const float4*)&t1[REL * 64 + 4];
  s.tc1 = *(const float4*)&t1[REL * 64 + 32];
  s.td1 = *(const float4*)&t1[REL * 64 + 36];
  s.ta2 = *(const float4*)&t2[REL * 64];
  s.tb2 = *(const float4*)&t2[REL * 64 + 4];
  s.tc2 = *(const float4*)&t2[REL * 64 + 32];
  s.td2 = *(const float4*)&t2[REL * 64 + 36];
  const unsigned short* hb = REL ? hb1 : hb0;
  s.bf0 = *(const s16x8*)&hb[0 * 512];
  s.bf1 = *(const s16x8*)&hb[1 * 512];
  s.bf2 = *(const s16x8*)&hb[2 * 512];
  s.bf3 = *(const s16x8*)&hb[3 * 512];
  s.bf4 = *(const s16x8*)&hb[2048 + 0 * 512];
  s.bf5 = *(const s16x8*)&hb[2048 + 1 * 512];
  s.bf6 = *(const s16x8*)&hb[2048 + 2 * 512];
  s.bf7 = *(const s16x8*)&hb[2048 + 3 * 512];
  return s;
}

__device__ __forceinline__ void compute_step(
    const StepIn& sI, int qo,
    float e1n0, float e2n0, float e1n1, float e2n1, s16x8 ones,
    f32x4 acc[2][4], f32x4 accd[2])
{
  s16x8 afr[2][2];
#pragma unroll
  for (int nt = 0; nt < 2; ++nt) {
    float e1n = nt ? e1n1 : e1n0;
    float e2n = nt ? e2n1 : e2n0;
#pragma unroll
    for (int ks = 0; ks < 2; ++ks) {
      unsigned wdw = nt ? (ks ? sI.wd11 : sI.wd10) : (ks ? sI.wd01 : sI.wd00);
      unsigned wq = wdw >> qo;
      float4 u1 = ks ? sI.tc1 : sI.ta1;
      float4 v1 = ks ? sI.td1 : sI.tb1;
      float4 u2 = ks ? sI.tc2 : sI.ta2;
      float4 v2 = ks ? sI.td2 : sI.tb2;
      float m1[8] = {u1.x, u1.y, u1.z, u1.w, v1.x, v1.y, v1.z, v1.w};
      float m2[8] = {u2.x, u2.y, u2.z, u2.w, v2.x, v2.y, v2.z, v2.w};
      float wv[8];
#pragma unroll
      for (int j = 0; j < 8; ++j) {
        float p1 = e1n * m1[j];
        float p2 = e2n * m2[j];
        float mx = fmaxf(p1, p2);               // = exp(lrelu(e)) by monotonicity
        int msk = -(int)((wq >> j) & 1u);       // 0 or 0xFFFFFFFF (portable)
        wv[j] = __int_as_float(msk & __float_as_int(mx));
      }
      u32x4 p;
      p[0] = cvtpk(wv[0], wv[1]);
      p[1] = cvtpk(wv[2], wv[3]);
      p[2] = cvtpk(wv[4], wv[5]);
      p[3] = cvtpk(wv[6], wv[7]);
      afr[nt][ks] = __builtin_bit_cast(s16x8, p);
    }
  }
  acc[0][0] = __builtin_amdgcn_mfma_f32_16x16x32_bf16(afr[0][0], sI.bf0, acc[0][0], 0, 0, 0);
  acc[0][1] = __builtin_amdgcn_mfma_f32_16x16x32_bf16(afr[0][0], sI.bf1, acc[0][1], 0, 0, 0);
  acc[0][2] = __builtin_amdgcn_mfma_f32_16x16x32_bf16(afr[0][0], sI.bf2, acc[0][2], 0, 0, 0);
  acc[0][3] = __builtin_amdgcn_mfma_f32_16x16x32_bf16(afr[0][0], sI.bf3, acc[0][3], 0, 0, 0);
  accd[0]   = __builtin_amdgcn_mfma_f32_16x16x32_bf16(afr[0][0], ones,   accd[0],   0, 0, 0);
  acc[1][0] = __builtin_amdgcn_mfma_f32_16x16x32_bf16(afr[1][0], sI.bf0, acc[1][0], 0, 0, 0);
  acc[1][1] = __builtin_amdgcn_mfma_f32_16x16x32_bf16(afr[1][0], sI.bf1, acc[1][1], 0, 0, 0);
  acc[1][2] = __builtin_amdgcn_mfma_f32_16x16x32_bf16(afr[1][0], sI.bf2, acc[1][2], 0, 0, 0);
  acc[1][3] = __builtin_amdgcn_mfma_f32_16x16x32_bf16(afr[1][0], sI.bf3, acc[1][3], 0, 0, 0);
  accd[1]   = __builtin_amdgcn_mfma_f32_16x16x32_bf16(afr[1][0], ones,   accd[1],   0, 0, 0);
  acc[0][0] = __builtin_amdgcn_mfma_f32_16x16x32_bf16(afr[0][1], sI.bf4, acc[0][0], 0, 0, 0);
  acc[0][1] = __builtin_amdgcn_mfma_f32_16x16x32_bf16(afr[0][1], sI.bf5, acc[0][1], 0, 0, 0);
  acc[0][2] = __builtin_amdgcn_mfma_f32_16x16x32_bf16(afr[0][1], sI.bf6, acc[0][2], 0, 0, 0);
  acc[0][3] = __builtin_amdgcn_mfma_f32_16x16x32_bf16(afr[0][1], sI.bf7, acc[0][3], 0, 0, 0);
  accd[0]   = __builtin_amdgcn_mfma_f32_16x16x32_bf16(afr[0][1], ones,   accd[0],   0, 0, 0);
  acc[1][0] = __builtin_amdgcn_mfma_f32_16x16x32_bf16(afr[1][1], sI.bf4, acc[1][0], 0, 0, 0);
  acc[1][1] = __builtin_amdgcn_mfma_f32_16x16x32_bf16(afr[1][1], sI.bf5, acc[1][1], 0, 0, 0);
  acc[1][2] = __builtin_amdgcn_mfma_f32_16x16x32_bf16(afr[1][1], sI.bf6, acc[1][2], 0, 0, 0);
  acc[1][3] = __builtin_amdgcn_mfma_f32_16x16x32_bf16(afr[1][1], sI.bf7, acc[1][3], 0, 0, 0);
  accd[1]   = __builtin_amdgcn_mfma_f32_16x16x32_bf16(afr[1][1], ones,   accd[1],   0, 0, 0);
}

template<int NSTEPS>
__device__ __forceinline__ void gat_part32(
    const unsigned* __restrict__ bits, int MT,
    const float* lds_t1, const float* lds_t2,
    const unsigned short* __restrict__ htT_h,
    int n0, int m_begin, int r16, int qo,
    float e1n0, float e2n0, float e1n1, float e2n1, s16x8 ones,
    f32x4 acc[2][4], f32x4 accd[2])
{
#pragma unroll
  for (int nt = 0; nt < 2; ++nt) {
    accd[nt] = (f32x4){0.f, 0.f, 0.f, 0.f};
#pragma unroll
    for (int dt = 0; dt < 4; ++dt) acc[nt][dt] = (f32x4){0.f, 0.f, 0.f, 0.f};
  }
  int mb0 = m_begin >> 5;
  const unsigned* br0 = &bits[(size_t)(n0 + r16) * MT + mb0];
  const unsigned* br1 = &bits[(size_t)(n0 + 16 + r16) * MT + mb0];
  const float* t1 = lds_t1 + qo;
  const float* t2 = lds_t2 + qo;
  const unsigned short* hb0 = &htT_h[(size_t)mb0 * 2048 + r16 * 32 + qo];
  const unsigned short* hb1 = hb0 + 4096;

  StepIn sA = load_step<0>(br0, br1, t1, t2, hb0, hb1);
#pragma unroll
  for (int st = 0; st < NSTEPS - 2; st += 2) {
    StepIn sB = load_step<1>(br0, br1, t1, t2, hb0, hb1);
    br0 += 4; br1 += 4; t1 += 128; t2 += 128; hb0 += 8192; hb1 += 8192;
    compute_step(sA, qo, e1n0, e2n0, e1n1, e2n1, ones, acc, accd);
    sA = load_step<0>(br0, br1, t1, t2, hb0, hb1);
    compute_step(sB, qo, e1n0, e2n0, e1n1, e2n1, ones, acc, accd);
  }
  StepIn sB = load_step<1>(br0, br1, t1, t2, hb0, hb1);
  compute_step(sA, qo, e1n0, e2n0, e1n1, e2n1, ones, acc, accd);
  compute_step(sB, qo, e1n0, e2n0, e1n1, e2n1, ones, acc, accd);
}

// two-pass (d-half) combine + global store
__device__ __forceinline__ void combine_store(
    f32x4 acc[2][4], f32x4 accd[2],
    float lnum[4][32][36], float lden[4][32],
    int w, int q, int r16, int tid,
    float* __restrict__ NUM, float* __restrict__ DEN, int sh, int n0)
{
  const int crow = tid >> 3, cd4 = (tid & 7) * 4;
#pragma unroll
  for (int pass = 0; pass < 2; ++pass) {
    __syncthreads();
#pragma unroll
    for (int nt = 0; nt < 2; ++nt)
#pragma unroll
      for (int dtl = 0; dtl < 2; ++dtl)
#pragma unroll
        for (int qi = 0; qi < 4; ++qi)
          lnum[w][nt * 16 + q * 4 + qi][dtl * 16 + r16] =
              acc[nt][pass * 2 + dtl][qi];
    if (pass == 0 && r16 == 0) {
#pragma unroll
      for (int nt = 0; nt < 2; ++nt)
#pragma unroll
        for (int qi = 0; qi < 4; ++qi)
          lden[w][nt * 16 + q * 4 + qi] = accd[nt][qi];
    }
    __syncthreads();
    f32x4 s = (f32x4){0.f, 0.f, 0.f, 0.f};
#pragma unroll
    for (int ww = 0; ww < 4; ++ww) s += *(const f32x4*)&lnum[ww][crow][cd4];
    *(f32x4*)&NUM[((size_t)sh * N_NODES + n0 + crow) * 64 + pass * 32 + cd4] = s;
    if (pass == 0 && (tid & 7) == 0) {
      float dsum = lden[0][crow] + lden[1][crow] + lden[2][crow] + lden[3][crow];
      DEN[(size_t)sh * N_NODES + n0 + crow] = dsum;
    }
  }
}

__global__ __launch_bounds__(256, 2) void gat_main(
    const unsigned short* __restrict__ htT_n, const unsigned short* __restrict__ htT_e,
    const float* __restrict__ srcN, const float* __restrict__ tgtN,
    const float* __restrict__ srcE, const float* __restrict__ tgtE,
    const unsigned* __restrict__ bitsN, const unsigned* __restrict__ bitsE,
    float* __restrict__ NUM_N, float* __restrict__ DEN_N,
    float* __restrict__ NUM_E, float* __restrict__ DEN_E)
{
  const int i = blockIdx.x;                     // 1024 blocks
  const int h = i & 7;
  const int tile = (i >> 3) & 63;
  const int ms = i >> 9;                        // m-split 0/1
  const int n0 = tile * 32;
  const int tid = threadIdx.x, w = tid >> 6, lane = tid & 63;
  const int r16 = lane & 15, q = lane >> 4, qo = q * 8;
  const int sh = ms * 8 + h;

  __shared__ __align__(16) float lnum[4][32][36];   // 18.4 KiB
  __shared__ float lden[4][32];
  __shared__ __align__(16) float lt1[2048];          // 8 KiB (E1 window)
  __shared__ __align__(16) float lt2[2048];          // 8 KiB (E2 window)

  s16x8 ones;
#pragma unroll
  for (int j = 0; j < 8; ++j) ones[j] = (short)0x3F80;    // bf16 1.0

  f32x4 acc[2][4], accd[2];

  // ---------------- nodes part: 4 steps, m window = 1024 ----------------
  {
    {
      int base = h * N_NODES + ms * 1024 + tid * 4;
      float4 s = *(const float4*)&tgtN[base];
      lt1[tid * 4 + 0] = __builtin_amdgcn_exp2f(s.x);
      lt1[tid * 4 + 1] = __builtin_amdgcn_exp2f(s.y);
      lt1[tid * 4 + 2] = __builtin_amdgcn_exp2f(s.z);
      lt1[tid * 4 + 3] = __builtin_amdgcn_exp2f(s.w);
      lt2[tid * 4 + 0] = __builtin_amdgcn_exp2f(0.2f * s.x);
      lt2[tid * 4 + 1] = __builtin_amdgcn_exp2f(0.2f * s.y);
      lt2[tid * 4 + 2] = __builtin_amdgcn_exp2f(0.2f * s.z);
      lt2[tid * 4 + 3] = __builtin_amdgcn_exp2f(0.2f * s.w);
    }
    __syncthreads();
    float sv0 = srcN[h * N_NODES + n0 + r16];
    float sv1 = srcN[h * N_NODES + n0 + 16 + r16];
    float e1n0 = __builtin_amdgcn_exp2f(sv0);
    float e2n0 = __builtin_amdgcn_exp2f(0.2f * sv0);
    float e1n1 = __builtin_amdgcn_exp2f(sv1);
    float e2n1 = __builtin_amdgcn_exp2f(0.2f * sv1);
    gat_part32<4>(bitsN, N_NODES / 32,
                  lt1 + w * 256, lt2 + w * 256,
                  htT_n + (size_t)h * (N_NODES / 32) * 2048,
                  n0, ms * 1024 + w * 256, r16, qo,
                  e1n0, e2n0, e1n1, e2n1, ones, acc, accd);
    combine_store(acc, accd, lnum, lden, w, q, r16, tid, NUM_N, DEN_N, sh, n0);
  }

  // ---------------- edges part: 8 steps, m window = 2048 ----------------
  {
    __syncthreads();
    {
      int base = h * N_EDGES + ms * 2048 + tid * 8;
      float4 s0 = *(const float4*)&tgtE[base];
      float4 s1 = *(const float4*)&tgtE[base + 4];
      lt1[tid * 8 + 0] = __builtin_amdgcn_exp2f(s0.x);
      lt1[tid * 8 + 1] = __builtin_amdgcn_exp2f(s0.y);
      lt1[tid * 8 + 2] = __builtin_amdgcn_exp2f(s0.z);
      lt1[tid * 8 + 3] = __builtin_amdgcn_exp2f(s0.w);
      lt1[tid * 8 + 4] = __builtin_amdgcn_exp2f(s1.x);
      lt1[tid * 8 + 5] = __builtin_amdgcn_exp2f(s1.y);
      lt1[tid * 8 + 6] = __builtin_amdgcn_exp2f(s1.z);
      lt1[tid * 8 + 7] = __builtin_amdgcn_exp2f(s1.w);
      lt2[tid * 8 + 0] = __builtin_amdgcn_exp2f(0.2f * s0.x);
      lt2[tid * 8 + 1] = __builtin_amdgcn_exp2f(0.2f * s0.y);
      lt2[tid * 8 + 2] = __builtin_amdgcn_exp2f(0.2f * s0.z);
      lt2[tid * 8 + 3] = __builtin_amdgcn_exp2f(0.2f * s0.w);
      lt2[tid * 8 + 4] = __builtin_amdgcn_exp2f(0.2f * s1.x);
      lt2[tid * 8 + 5] = __builtin_amdgcn_exp2f(0.2f * s1.y);
      lt2[tid * 8 + 6] = __builtin_amdgcn_exp2f(0.2f * s1.z);
      lt2[tid * 8 + 7] = __builtin_amdgcn_exp2f(0.2f * s1.w);
    }
    __syncthreads();
    float sv0 = srcE[h * N_NODES + n0 + r16];
    float sv1 = srcE[h * N_NODES + n0 + 16 + r16];
    float e1n0 = __builtin_amdgcn_exp2f(sv0);
    float e2n0 = __builtin_amdgcn_exp2f(0.2f * sv0);
    float e1n1 = __builtin_amdgcn_exp2f(sv1);
    float e2n1 = __builtin_amdgcn_exp2f(0.2f * sv1);
    gat_part32<8>(bitsE, N_EDGES / 32,
                  lt1 + w * 512, lt2 + w * 512,
                  htT_e + (size_t)h * (N_EDGES / 32) * 2048,
                  n0, ms * 2048 + w * 512, r16, qo,
                  e1n0, e2n0, e1n1, e2n1, ones, acc, accd);
    combine_store(acc, accd, lnum, lden, w, q, r16, tid, NUM_E, DEN_E, sh, n0);
  }
}

// ---------------------------------------------------------------------------
// Kernel D: combine 2 msplit partials, normalize, mean over heads.
// ---------------------------------------------------------------------------
__global__ __launch_bounds__(128) void reduce_out(
    const float* __restrict__ NUM_N, const float* __restrict__ DEN_N,
    const float* __restrict__ NUM_E, const float* __restrict__ DEN_E,
    float* __restrict__ out)
{
  int idx = blockIdx.x * 128 + threadIdx.x;   // 32768 threads (256 blocks)
  int n = idx >> 4, d4 = (idx & 15) * 4;
  f32x4 r = (f32x4){0.f, 0.f, 0.f, 0.f};
#pragma unroll
  for (int h = 0; h < H_HEADS; ++h) {
    f32x4 nn = *(const f32x4*)&NUM_N[((size_t)h * N_NODES + n) * 64 + d4]
             + *(const f32x4*)&NUM_N[((size_t)(8 + h) * N_NODES + n) * 64 + d4];
    float dn = DEN_N[(size_t)h * N_NODES + n] + DEN_N[(size_t)(8 + h) * N_NODES + n];
    f32x4 ne = *(const f32x4*)&NUM_E[((size_t)h * N_NODES + n) * 64 + d4]
             + *(const f32x4*)&NUM_E[((size_t)(8 + h) * N_NODES + n) * 64 + d4];
    float de = DEN_E[(size_t)h * N_NODES + n] + DEN_E[(size_t)(8 + h) * N_NODES + n];
    float idn = 1.0f / dn, ide = 1.0f / de;
    r.x += nn.x * idn + ne.x * ide;
    r.y += nn.y * idn + ne.y * ide;
    r.z += nn.z * idn + ne.z * ide;
    r.w += nn.w * idn + ne.w * ide;
  }
  f32x4 o = (f32x4){r.x * 0.125f, r.y * 0.125f, r.z * 0.125f, r.w * 0.125f};
  *(f32x4*)&out[(size_t)n * 64 + d4] = o;
}

// ---------------------------------------------------------------------------
extern "C" void kernel_launch(void* const* d_in, const int* in_sizes, int n_in,
                              void* d_out, int out_size, void* d_ws, size_t ws_size,
                              hipStream_t stream)
{
  const float* nodes = (const float*)d_in[0];
  const float* edges = (const float*)d_in[1];
  const float* WN    = (const float*)d_in[2];
  const float* WE    = (const float*)d_in[3];
  const float* aN    = (const float*)d_in[4];
  const float* aE    = (const float*)d_in[5];
  const int*   matN  = (const int*)d_in[6];
  const int*   matE  = (const int*)d_in[7];
  float* out = (float*)d_out;

  float* ws = (float*)d_ws;
  size_t o = 0;
  unsigned short* htT_n = (unsigned short*)(ws + o); o += (size_t)H_HEADS * 64 * N_NODES / 2;  // 2MB
  unsigned short* htT_e = (unsigned short*)(ws + o); o += (size_t)H_HEADS * 64 * N_EDGES / 2;  // 4MB
  unsigned* bitsN = (unsigned*)(ws + o); o += (size_t)N_NODES * (N_NODES / 32);                // 512KB
  unsigned* bitsE = (unsigned*)(ws + o); o += (size_t)N_NODES * (N_EDGES / 32);                // 1MB
  unsigned short* X2hi = (unsigned short*)(ws + o); o += (size_t)6144 * 256 / 2;               // 3MB
  unsigned short* X2lo = (unsigned short*)(ws + o); o += (size_t)6144 * 256 / 2;               // 3MB
  unsigned short* W2hi = (unsigned short*)(ws + o); o += (size_t)2 * 512 * 256 / 2;            // 512KB
  unsigned short* W2lo = (unsigned short*)(ws + o); o += (size_t)2 * 512 * 256 / 2;            // 512KB
  float* srcN  = ws + o;  o += (size_t)H_HEADS * N_NODES;
  float* tgtN  = ws + o;  o += (size_t)H_HEADS * N_NODES;
  float* srcE  = ws + o;  o += (size_t)H_HEADS * N_NODES;
  float* tgtE  = ws + o;  o += (size_t)H_HEADS * N_EDGES;
  float* NUM_N = ws + o;  o += (size_t)2 * H_HEADS * N_NODES * 64;   // 8MB
  float* DEN_N = ws + o;  o += (size_t)2 * H_HEADS * N_NODES;
  float* NUM_E = ws + o;  o += (size_t)2 * H_HEADS * N_NODES * 64;   // 8MB
  float* DEN_E = ws + o;  o += (size_t)2 * H_HEADS * N_NODES;

  hipLaunchKernelGGL(prep_pack, dim3(2432), dim3(256), 0, stream,
                     nodes, edges, WN, WE, matN, matE,
                     X2hi, X2lo, W2hi, W2lo, bitsN, bitsE);
  hipLaunchKernelGGL(gemm_fused, dim3(96, 8), dim3(256), 0, stream,
                     X2hi, X2lo, W2hi, W2lo, aN, aE,
                     htT_n, htT_e, srcN, tgtN, srcE, tgtE);
  hipLaunchKernelGGL(gat_main, dim3(1024), dim3(256), 0, stream,
                     htT_n, htT_e, srcN, tgtN, srcE, tgtE, bitsN, bitsE,
                     NUM_N, DEN_N, NUM_E, DEN_E);
  hipLaunchKernelGGL(reduce_out, dim3(256), dim3(128), 0, stream,
                     NUM_N, DEN_N, NUM_E, DEN_E, out);
}

// Round 23
// 72.593 us; speedup vs baseline: 1.4442x; 1.0171x over previous
//
#include <hip/hip_runtime.h>
#include <hip/hip_bf16.h>

#define N_NODES 2048
#define N_EDGES 4096
#define F_IN    256
#define H_HEADS 8
#define HD      512
#define LOG2E   1.44269504088896f

typedef __attribute__((ext_vector_type(4))) float f32x4;
typedef __attribute__((ext_vector_type(8))) short s16x8;
typedef __attribute__((ext_vector_type(4))) unsigned u32x4;

static __device__ __forceinline__ unsigned short f2bf(float x) {
  union { float f; unsigned u; } v; v.f = x;
  unsigned r = v.u + 0x7fff + ((v.u >> 16) & 1);   // RNE
  return (unsigned short)(r >> 16);
}
static __device__ __forceinline__ float bf2f(unsigned short h) {
  union { unsigned u; float f; } v; v.u = ((unsigned)h) << 16;
  return v.f;
}
static __device__ __forceinline__ unsigned cvtpk(float lo, float hi) {
  unsigned r;
  asm("v_cvt_pk_bf16_f32 %0, %1, %2" : "=v"(r) : "v"(lo), "v"(hi));
  return r;
}

// ---------------------------------------------------------------------------
// Kernel A: front2 — fused W2-prep (blocks 0..127) + mask bit-pack (128..1663).
//   W2[mat][h][dt][kb][lane][8]: col = h*64+dt*16+(lane&15), k = kb*32+(lane>>4)*8+j
// ---------------------------------------------------------------------------
__global__ __launch_bounds__(256) void front2(
    const float* __restrict__ WN, const float* __restrict__ WE,
    const int* __restrict__ matN, const int* __restrict__ matE,
    unsigned short* __restrict__ W2hi, unsigned short* __restrict__ W2lo,
    unsigned* __restrict__ bitsN, unsigned* __restrict__ bitsE)
{
  int t = blockIdx.x * 256 + threadIdx.x;
  if (t < 32768) {                             // W: 2 x 8 x 4 x 8 x 64 threads
    int wt = t;
    int lane = wt & 63, kb = (wt >> 6) & 7, dt = (wt >> 9) & 3;
    int hh = (wt >> 11) & 7, mat = wt >> 14;
    const float* W = mat ? WE : WN;
    int k0  = kb * 32 + (lane >> 4) * 8;
    int col = hh * 64 + dt * 16 + (lane & 15);
    s16x8 hi, lo;
#pragma unroll
    for (int j = 0; j < 8; ++j) {
      float v = W[(size_t)(k0 + j) * HD + col];
      unsigned short h = f2bf(v);
      hi[j] = (short)h;
      lo[j] = (short)f2bf(v - bf2f(h));
    }
    *(s16x8*)&W2hi[(size_t)wt * 8] = hi;
    *(s16x8*)&W2lo[(size_t)wt * 8] = lo;
  } else {                                     // pack: 393216 threads
    int p = t - 32768;
    const int* src; unsigned* dst;
    if (p < N_NODES * (N_NODES / 32)) {
      int row = p >> 6, w = p & 63;
      src = &matN[(size_t)row * N_NODES + w * 32]; dst = &bitsN[p];
    } else {
      int pp = p - N_NODES * (N_NODES / 32);
      int row = pp >> 7, w = pp & 127;
      src = &matE[(size_t)row * N_EDGES + w * 32]; dst = &bitsE[pp];
    }
    unsigned b = 0;
#pragma unroll
    for (int k = 7; k >= 0; --k) {
      int4 v = *(const int4*)&src[k * 4];
      b = (b << 1) | ((unsigned)v.w & 1u);
      b = (b << 1) | ((unsigned)v.z & 1u);
      b = (b << 1) | ((unsigned)v.y & 1u);
      b = (b << 1) | ((unsigned)v.x & 1u);
    }
    *dst = b;
  }
}

// ---------------------------------------------------------------------------
// Kernel B: MFMA ht-GEMM — A operands read directly from fp32 X and split
// hi/lo inline (bit-identical to prep-based split); B from swizzled W2.
// + bf16 tiled transpose-out + score vectors (xLOG2E).
// ---------------------------------------------------------------------------
__global__ __launch_bounds__(256) void gemm_fused(
    const float* __restrict__ nodes, const float* __restrict__ edges,
    const unsigned short* __restrict__ W2hi, const unsigned short* __restrict__ W2lo,
    const float* __restrict__ aN, const float* __restrict__ aE,
    unsigned short* __restrict__ htT_n, unsigned short* __restrict__ htT_e,
    float* __restrict__ srcN, float* __restrict__ tgtN,
    float* __restrict__ srcE, float* __restrict__ tgtE)
{
  const int rt = blockIdx.x;   // 0..31 nodes, 32..95 edges
  const int h  = blockIdx.y;   // head
  const bool isNode = (rt < 32);
  const int r0 = (isNode ? rt : rt - 32) * 64;
  const int MT = (isNode ? N_NODES : N_EDGES) / 32;

  __shared__ __align__(16) float T[64][68];    // T[d][m_local]

  const int tid = threadIdx.x;
  const int w = tid >> 6, l = tid & 63;
  const int r16 = l & 15;

  const float* Xf = isNode ? nodes : edges;
  const float* Aptr = &Xf[(size_t)(r0 + 16 * w + r16) * F_IN + (l >> 4) * 8];
  const size_t wbase = ((size_t)((isNode ? 0 : 1) * 8 + h)) * 16384 + l * 8;
  const unsigned short* WH = &W2hi[wbase];
  const unsigned short* WL = &W2lo[wbase];

  f32x4 acc[4];
#pragma unroll
  for (int dt = 0; dt < 4; ++dt) acc[dt] = (f32x4){0.f, 0.f, 0.f, 0.f};

#pragma unroll
  for (int kb = 0; kb < 8; ++kb) {
    float4 a = *(const float4*)&Aptr[kb * 32];
    float4 c = *(const float4*)&Aptr[kb * 32 + 4];
    float v[8] = {a.x, a.y, a.z, a.w, c.x, c.y, c.z, c.w};
    s16x8 ahi, alo;
#pragma unroll
    for (int j = 0; j < 8; ++j) {
      unsigned short hj = f2bf(v[j]);
      ahi[j] = (short)hj;
      alo[j] = (short)f2bf(v[j] - bf2f(hj));
    }
#pragma unroll
    for (int dt = 0; dt < 4; ++dt) {
      s16x8 bhi = *(const s16x8*)&WH[(dt * 8 + kb) * 512];
      s16x8 blo = *(const s16x8*)&WL[(dt * 8 + kb) * 512];
      acc[dt] = __builtin_amdgcn_mfma_f32_16x16x32_bf16(ahi, bhi, acc[dt], 0, 0, 0);
      acc[dt] = __builtin_amdgcn_mfma_f32_16x16x32_bf16(ahi, blo, acc[dt], 0, 0, 0);
      acc[dt] = __builtin_amdgcn_mfma_f32_16x16x32_bf16(alo, bhi, acc[dt], 0, 0, 0);
    }
  }

  // C[m_local = 16w + (l>>4)*4 + reg][d = dt*16 + r16] -> T[d][m_local]
#pragma unroll
  for (int dt = 0; dt < 4; ++dt)
#pragma unroll
    for (int reg = 0; reg < 4; ++reg)
      T[dt * 16 + r16][16 * w + (l >> 4) * 4 + reg] = acc[dt][reg];
  __syncthreads();

  // bf16 tiled transposed write: htT2[h][mblk][d][m%32]
  {
    int d = tid >> 2, mq = tid & 3;
    s16x8 o0, o1;
#pragma unroll
    for (int k = 0; k < 8; ++k) o0[k] = (short)f2bf(T[d][mq * 16 + k]);
#pragma unroll
    for (int k = 0; k < 8; ++k) o1[k] = (short)f2bf(T[d][mq * 16 + 8 + k]);
    unsigned short* dst = isNode ? htT_n : htT_e;
    int mb0 = r0 >> 5;
    size_t base = (size_t)h * MT * 2048 + (size_t)(mb0 + (mq >> 1)) * 2048
                + d * 32 + (mq & 1) * 16;
    *(s16x8*)&dst[base] = o0;
    *(s16x8*)&dst[base + 8] = o1;
  }

  // score vectors, pre-scaled by LOG2E
  {
    int r = tid >> 2, q4 = tid & 3;
    float tr[16];
#pragma unroll
    for (int k = 0; k < 16; ++k) tr[k] = T[q4 * 16 + k][r];
    if (isNode) {
      float s1 = 0.f, s2 = 0.f, s3 = 0.f;
#pragma unroll
      for (int k = 0; k < 16; ++k) {
        s1 = fmaf(tr[k], aN[h * 128 + q4 * 16 + k], s1);
        s2 = fmaf(tr[k], aN[h * 128 + 64 + q4 * 16 + k], s2);
        s3 = fmaf(tr[k], aE[h * 128 + q4 * 16 + k], s3);
      }
      s1 += __shfl_xor(s1, 1); s1 += __shfl_xor(s1, 2);
      s2 += __shfl_xor(s2, 1); s2 += __shfl_xor(s2, 2);
      s3 += __shfl_xor(s3, 1); s3 += __shfl_xor(s3, 2);
      if (q4 == 0) {
        srcN[h * N_NODES + r0 + r] = s1 * LOG2E;
        tgtN[h * N_NODES + r0 + r] = s2 * LOG2E;
        srcE[h * N_NODES + r0 + r] = s3 * LOG2E;
      }
    } else {
      float s4 = 0.f;
#pragma unroll
      for (int k = 0; k < 16; ++k)
        s4 = fmaf(tr[k], aE[h * 128 + 64 + q4 * 16 + k], s4);
      s4 += __shfl_xor(s4, 1); s4 += __shfl_xor(s4, 2);
      if (q4 == 0) tgtE[h * N_EDGES + r0 + r] = s4 * LOG2E;
    }
  }
}

// ---------------------------------------------------------------------------
// Kernel C: main GAT (R22-exact). exp2 during LDS staging; factorized w.
// ---------------------------------------------------------------------------
struct StepIn {
  unsigned wd00, wd01, wd10, wd11;
  float4 ta1, tb1, tc1, td1;
  float4 ta2, tb2, tc2, td2;
  s16x8 bf0, bf1, bf2, bf3;
  s16x8 bf4, bf5, bf6, bf7;
};

template<int REL>
__device__ __forceinline__ StepIn load_step(
    const unsigned* __restrict__ br0, const unsigned* __restrict__ br1,
    const float* t1, const float* t2,
    const unsigned short* __restrict__ hb0,
    const unsigned short* __restrict__ hb1)
{
  StepIn s;
  s.wd00 = br0[REL * 2]; s.wd01 = br0[REL * 2 + 1];
  s.wd10 = br1[REL * 2]; s.wd11 = br1[REL * 2 + 1];
  s.ta1 = *(const float4*)&t1[REL * 64];
  s.tb1 = *(const float4*)&t1[REL * 64 + 4];
  s.tc1 = *(const float4*)&t1[REL * 64 + 32];
  s.td1 = *(const float4*)&t1[REL * 64 + 36];
  s.ta2 = *(const float4*)&t2[REL * 64];
  s.tb2 = *(const float4*)&t2[REL * 64 + 4];
  s.tc2 = *(const float4*)&t2[REL * 64 + 32];
  s.td2 = *(const float4*)&t2[REL * 64 + 36];
  const unsigned short* hb = REL ? hb1 : hb0;
  s.bf0 = *(const s16x8*)&hb[0 * 512];
  s.bf1 = *(const s16x8*)&hb[1 * 512];
  s.bf2 = *(const s16x8*)&hb[2 * 512];
  s.bf3 = *(const s16x8*)&hb[3 * 512];
  s.bf4 = *(const s16x8*)&hb[2048 + 0 * 512];
  s.bf5 = *(const s16x8*)&hb[2048 + 1 * 512];
  s.bf6 = *(const s16x8*)&hb[2048 + 2 * 512];
  s.bf7 = *(const s16x8*)&hb[2048 + 3 * 512];
  return s;
}

__device__ __forceinline__ void compute_step(
    const StepIn& sI, int qo,
    float e1n0, float e2n0, float e1n1, float e2n1, s16x8 ones,
    f32x4 acc[2][4], f32x4 accd[2])
{
  s16x8 afr[2][2];
#pragma unroll
  for (int nt = 0; nt < 2; ++nt) {
    float e1n = nt ? e1n1 : e1n0;
    float e2n = nt ? e2n1 : e2n0;
#pragma unroll
    for (int ks = 0; ks < 2; ++ks) {
      unsigned wdw = nt ? (ks ? sI.wd11 : sI.wd10) : (ks ? sI.wd01 : sI.wd00);
      unsigned wq = wdw >> qo;
      float4 u1 = ks ? sI.tc1 : sI.ta1;
      float4 v1 = ks ? sI.td1 : sI.tb1;
      float4 u2 = ks ? sI.tc2 : sI.ta2;
      float4 v2 = ks ? sI.td2 : sI.tb2;
      float m1[8] = {u1.x, u1.y, u1.z, u1.w, v1.x, v1.y, v1.z, v1.w};
      float m2[8] = {u2.x, u2.y, u2.z, u2.w, v2.x, v2.y, v2.z, v2.w};
      float wv[8];
#pragma unroll
      for (int j = 0; j < 8; ++j) {
        float p1 = e1n * m1[j];
        float p2 = e2n * m2[j];
        float mx = fmaxf(p1, p2);               // = exp(lrelu(e)) by monotonicity
        int msk = -(int)((wq >> j) & 1u);       // 0 or 0xFFFFFFFF (portable)
        wv[j] = __int_as_float(msk & __float_as_int(mx));
      }
      u32x4 p;
      p[0] = cvtpk(wv[0], wv[1]);
      p[1] = cvtpk(wv[2], wv[3]);
      p[2] = cvtpk(wv[4], wv[5]);
      p[3] = cvtpk(wv[6], wv[7]);
      afr[nt][ks] = __builtin_bit_cast(s16x8, p);
    }
  }
  acc[0][0] = __builtin_amdgcn_mfma_f32_16x16x32_bf16(afr[0][0], sI.bf0, acc[0][0], 0, 0, 0);
  acc[0][1] = __builtin_amdgcn_mfma_f32_16x16x32_bf16(afr[0][0], sI.bf1, acc[0][1], 0, 0, 0);
  acc[0][2] = __builtin_amdgcn_mfma_f32_16x16x32_bf16(afr[0][0], sI.bf2, acc[0][2], 0, 0, 0);
  acc[0][3] = __builtin_amdgcn_mfma_f32_16x16x32_bf16(afr[0][0], sI.bf3, acc[0][3], 0, 0, 0);
  accd[0]   = __builtin_amdgcn_mfma_f32_16x16x32_bf16(afr[0][0], ones,   accd[0],   0, 0, 0);
  acc[1][0] = __builtin_amdgcn_mfma_f32_16x16x32_bf16(afr[1][0], sI.bf0, acc[1][0], 0, 0, 0);
  acc[1][1] = __builtin_amdgcn_mfma_f32_16x16x32_bf16(afr[1][0], sI.bf1, acc[1][1], 0, 0, 0);
  acc[1][2] = __builtin_amdgcn_mfma_f32_16x16x32_bf16(afr[1][0], sI.bf2, acc[1][2], 0, 0, 0);
  acc[1][3] = __builtin_amdgcn_mfma_f32_16x16x32_bf16(afr[1][0], sI.bf3, acc[1][3], 0, 0, 0);
  accd[1]   = __builtin_amdgcn_mfma_f32_16x16x32_bf16(afr[1][0], ones,   accd[1],   0, 0, 0);
  acc[0][0] = __builtin_amdgcn_mfma_f32_16x16x32_bf16(afr[0][1], sI.bf4, acc[0][0], 0, 0, 0);
  acc[0][1] = __builtin_amdgcn_mfma_f32_16x16x32_bf16(afr[0][1], sI.bf5, acc[0][1], 0, 0, 0);
  acc[0][2] = __builtin_amdgcn_mfma_f32_16x16x32_bf16(afr[0][1], sI.bf6, acc[0][2], 0, 0, 0);
  acc[0][3] = __builtin_amdgcn_mfma_f32_16x16x32_bf16(afr[0][1], sI.bf7, acc[0][3], 0, 0, 0);
  accd[0]   = __builtin_amdgcn_mfma_f32_16x16x32_bf16(afr[0][1], ones,   accd[0],   0, 0, 0);
  acc[1][0] = __builtin_amdgcn_mfma_f32_16x16x32_bf16(afr[1][1], sI.bf4, acc[1][0], 0, 0, 0);
  acc[1][1] = __builtin_amdgcn_mfma_f32_16x16x32_bf16(afr[1][1], sI.bf5, acc[1][1], 0, 0, 0);
  acc[1][2] = __builtin_amdgcn_mfma_f32_16x16x32_bf16(afr[1][1], sI.bf6, acc[1][2], 0, 0, 0);
  acc[1][3] = __builtin_amdgcn_mfma_f32_16x16x32_bf16(afr[1][1], sI.bf7, acc[1][3], 0, 0, 0);
  accd[1]   = __builtin_amdgcn_mfma_f32_16x16x32_bf16(afr[1][1], ones,   accd[1],   0, 0, 0);
}

template<int NSTEPS>
__device__ __forceinline__ void gat_part32(
    const unsigned* __restrict__ bits, int MT,
    const float* lds_t1, const float* lds_t2,
    const unsigned short* __restrict__ htT_h,
    int n0, int m_begin, int r16, int qo,
    float e1n0, float e2n0, float e1n1, float e2n1, s16x8 ones,
    f32x4 acc[2][4], f32x4 accd[2])
{
#pragma unroll
  for (int nt = 0; nt < 2; ++nt) {
    accd[nt] = (f32x4){0.f, 0.f, 0.f, 0.f};
#pragma unroll
    for (int dt = 0; dt < 4; ++dt) acc[nt][dt] = (f32x4){0.f, 0.f, 0.f, 0.f};
  }
  int mb0 = m_begin >> 5;
  const unsigned* br0 = &bits[(size_t)(n0 + r16) * MT + mb0];
  const unsigned* br1 = &bits[(size_t)(n0 + 16 + r16) * MT + mb0];
  const float* t1 = lds_t1 + qo;
  const float* t2 = lds_t2 + qo;
  const unsigned short* hb0 = &htT_h[(size_t)mb0 * 2048 + r16 * 32 + qo];
  const unsigned short* hb1 = hb0 + 4096;

  StepIn sA = load_step<0>(br0, br1, t1, t2, hb0, hb1);
#pragma unroll
  for (int st = 0; st < NSTEPS - 2; st += 2) {
    StepIn sB = load_step<1>(br0, br1, t1, t2, hb0, hb1);
    br0 += 4; br1 += 4; t1 += 128; t2 += 128; hb0 += 8192; hb1 += 8192;
    compute_step(sA, qo, e1n0, e2n0, e1n1, e2n1, ones, acc, accd);
    sA = load_step<0>(br0, br1, t1, t2, hb0, hb1);
    compute_step(sB, qo, e1n0, e2n0, e1n1, e2n1, ones, acc, accd);
  }
  StepIn sB = load_step<1>(br0, br1, t1, t2, hb0, hb1);
  compute_step(sA, qo, e1n0, e2n0, e1n1, e2n1, ones, acc, accd);
  compute_step(sB, qo, e1n0, e2n0, e1n1, e2n1, ones, acc, accd);
}

// two-pass (d-half) combine + global store
__device__ __forceinline__ void combine_store(
    f32x4 acc[2][4], f32x4 accd[2],
    float lnum[4][32][36], float lden[4][32],
    int w, int q, int r16, int tid,
    float* __restrict__ NUM, float* __restrict__ DEN, int sh, int n0)
{
  const int crow = tid >> 3, cd4 = (tid & 7) * 4;
#pragma unroll
  for (int pass = 0; pass < 2; ++pass) {
    __syncthreads();
#pragma unroll
    for (int nt = 0; nt < 2; ++nt)
#pragma unroll
      for (int dtl = 0; dtl < 2; ++dtl)
#pragma unroll
        for (int qi = 0; qi < 4; ++qi)
          lnum[w][nt * 16 + q * 4 + qi][dtl * 16 + r16] =
              acc[nt][pass * 2 + dtl][qi];
    if (pass == 0 && r16 == 0) {
#pragma unroll
      for (int nt = 0; nt < 2; ++nt)
#pragma unroll
        for (int qi = 0; qi < 4; ++qi)
          lden[w][nt * 16 + q * 4 + qi] = accd[nt][qi];
    }
    __syncthreads();
    f32x4 s = (f32x4){0.f, 0.f, 0.f, 0.f};
#pragma unroll
    for (int ww = 0; ww < 4; ++ww) s += *(const f32x4*)&lnum[ww][crow][cd4];
    *(f32x4*)&NUM[((size_t)sh * N_NODES + n0 + crow) * 64 + pass * 32 + cd4] = s;
    if (pass == 0 && (tid & 7) == 0) {
      float dsum = lden[0][crow] + lden[1][crow] + lden[2][crow] + lden[3][crow];
      DEN[(size_t)sh * N_NODES + n0 + crow] = dsum;
    }
  }
}

__global__ __launch_bounds__(256, 2) void gat_main(
    const unsigned short* __restrict__ htT_n, const unsigned short* __restrict__ htT_e,
    const float* __restrict__ srcN, const float* __restrict__ tgtN,
    const float* __restrict__ srcE, const float* __restrict__ tgtE,
    const unsigned* __restrict__ bitsN, const unsigned* __restrict__ bitsE,
    float* __restrict__ NUM_N, float* __restrict__ DEN_N,
    float* __restrict__ NUM_E, float* __restrict__ DEN_E)
{
  const int i = blockIdx.x;                     // 1024 blocks
  const int h = i & 7;
  const int tile = (i >> 3) & 63;
  const int ms = i >> 9;                        // m-split 0/1
  const int n0 = tile * 32;
  const int tid = threadIdx.x, w = tid >> 6, lane = tid & 63;
  const int r16 = lane & 15, q = lane >> 4, qo = q * 8;
  const int sh = ms * 8 + h;

  __shared__ __align__(16) float lnum[4][32][36];   // 18.4 KiB
  __shared__ float lden[4][32];
  __shared__ __align__(16) float lt1[2048];          // 8 KiB (E1 window)
  __shared__ __align__(16) float lt2[2048];          // 8 KiB (E2 window)

  s16x8 ones;
#pragma unroll
  for (int j = 0; j < 8; ++j) ones[j] = (short)0x3F80;    // bf16 1.0

  f32x4 acc[2][4], accd[2];

  // ---------------- nodes part: 4 steps, m window = 1024 ----------------
  {
    {
      int base = h * N_NODES + ms * 1024 + tid * 4;
      float4 s = *(const float4*)&tgtN[base];
      lt1[tid * 4 + 0] = __builtin_amdgcn_exp2f(s.x);
      lt1[tid * 4 + 1] = __builtin_amdgcn_exp2f(s.y);
      lt1[tid * 4 + 2] = __builtin_amdgcn_exp2f(s.z);
      lt1[tid * 4 + 3] = __builtin_amdgcn_exp2f(s.w);
      lt2[tid * 4 + 0] = __builtin_amdgcn_exp2f(0.2f * s.x);
      lt2[tid * 4 + 1] = __builtin_amdgcn_exp2f(0.2f * s.y);
      lt2[tid * 4 + 2] = __builtin_amdgcn_exp2f(0.2f * s.z);
      lt2[tid * 4 + 3] = __builtin_amdgcn_exp2f(0.2f * s.w);
    }
    __syncthreads();
    float sv0 = srcN[h * N_NODES + n0 + r16];
    float sv1 = srcN[h * N_NODES + n0 + 16 + r16];
    float e1n0 = __builtin_amdgcn_exp2f(sv0);
    float e2n0 = __builtin_amdgcn_exp2f(0.2f * sv0);
    float e1n1 = __builtin_amdgcn_exp2f(sv1);
    float e2n1 = __builtin_amdgcn_exp2f(0.2f * sv1);
    gat_part32<4>(bitsN, N_NODES / 32,
                  lt1 + w * 256, lt2 + w * 256,
                  htT_n + (size_t)h * (N_NODES / 32) * 2048,
                  n0, ms * 1024 + w * 256, r16, qo,
                  e1n0, e2n0, e1n1, e2n1, ones, acc, accd);
    combine_store(acc, accd, lnum, lden, w, q, r16, tid, NUM_N, DEN_N, sh, n0);
  }

  // ---------------- edges part: 8 steps, m window = 2048 ----------------
  {
    __syncthreads();
    {
      int base = h * N_EDGES + ms * 2048 + tid * 8;
      float4 s0 = *(const float4*)&tgtE[base];
      float4 s1 = *(const float4*)&tgtE[base + 4];
      lt1[tid * 8 + 0] = __builtin_amdgcn_exp2f(s0.x);
      lt1[tid * 8 + 1] = __builtin_amdgcn_exp2f(s0.y);
      lt1[tid * 8 + 2] = __builtin_amdgcn_exp2f(s0.z);
      lt1[tid * 8 + 3] = __builtin_amdgcn_exp2f(s0.w);
      lt1[tid * 8 + 4] = __builtin_amdgcn_exp2f(s1.x);
      lt1[tid * 8 + 5] = __builtin_amdgcn_exp2f(s1.y);
      lt1[tid * 8 + 6] = __builtin_amdgcn_exp2f(s1.z);
      lt1[tid * 8 + 7] = __builtin_amdgcn_exp2f(s1.w);
      lt2[tid * 8 + 0] = __builtin_amdgcn_exp2f(0.2f * s0.x);
      lt2[tid * 8 + 1] = __builtin_amdgcn_exp2f(0.2f * s0.y);
      lt2[tid * 8 + 2] = __builtin_amdgcn_exp2f(0.2f * s0.z);
      lt2[tid * 8 + 3] = __builtin_amdgcn_exp2f(0.2f * s0.w);
      lt2[tid * 8 + 4] = __builtin_amdgcn_exp2f(0.2f * s1.x);
      lt2[tid * 8 + 5] = __builtin_amdgcn_exp2f(0.2f * s1.y);
      lt2[tid * 8 + 6] = __builtin_amdgcn_exp2f(0.2f * s1.z);
      lt2[tid * 8 + 7] = __builtin_amdgcn_exp2f(0.2f * s1.w);
    }
    __syncthreads();
    float sv0 = srcE[h * N_NODES + n0 + r16];
    float sv1 = srcE[h * N_NODES + n0 + 16 + r16];
    float e1n0 = __builtin_amdgcn_exp2f(sv0);
    float e2n0 = __builtin_amdgcn_exp2f(0.2f * sv0);
    float e1n1 = __builtin_amdgcn_exp2f(sv1);
    float e2n1 = __builtin_amdgcn_exp2f(0.2f * sv1);
    gat_part32<8>(bitsE, N_EDGES / 32,
                  lt1 + w * 512, lt2 + w * 512,
                  htT_e + (size_t)h * (N_EDGES / 32) * 2048,
                  n0, ms * 2048 + w * 512, r16, qo,
                  e1n0, e2n0, e1n1, e2n1, ones, acc, accd);
    combine_store(acc, accd, lnum, lden, w, q, r16, tid, NUM_E, DEN_E, sh, n0);
  }
}

// ---------------------------------------------------------------------------
// Kernel D: combine 2 msplit partials, normalize, mean over heads.
// ---------------------------------------------------------------------------
__global__ __launch_bounds__(128) void reduce_out(
    const float* __restrict__ NUM_N, const float* __restrict__ DEN_N,
    const float* __restrict__ NUM_E, const float* __restrict__ DEN_E,
    float* __restrict__ out)
{
  int idx = blockIdx.x * 128 + threadIdx.x;   // 32768 threads (256 blocks)
  int n = idx >> 4, d4 = (idx & 15) * 4;
  f32x4 r = (f32x4){0.f, 0.f, 0.f, 0.f};
#pragma unroll
  for (int h = 0; h < H_HEADS; ++h) {
    f32x4 nn = *(const f32x4*)&NUM_N[((size_t)h * N_NODES + n) * 64 + d4]
             + *(const f32x4*)&NUM_N[((size_t)(8 + h) * N_NODES + n) * 64 + d4];
    float dn = DEN_N[(size_t)h * N_NODES + n] + DEN_N[(size_t)(8 + h) * N_NODES + n];
    f32x4 ne = *(const f32x4*)&NUM_E[((size_t)h * N_NODES + n) * 64 + d4]
             + *(const f32x4*)&NUM_E[((size_t)(8 + h) * N_NODES + n) * 64 + d4];
    float de = DEN_E[(size_t)h * N_NODES + n] + DEN_E[(size_t)(8 + h) * N_NODES + n];
    float idn = 1.0f / dn, ide = 1.0f / de;
    r.x += nn.x * idn + ne.x * ide;
    r.y += nn.y * idn + ne.y * ide;
    r.z += nn.z * idn + ne.z * ide;
    r.w += nn.w * idn + ne.w * ide;
  }
  f32x4 o = (f32x4){r.x * 0.125f, r.y * 0.125f, r.z * 0.125f, r.w * 0.125f};
  *(f32x4*)&out[(size_t)n * 64 + d4] = o;
}

// ---------------------------------------------------------------------------
extern "C" void kernel_launch(void* const* d_in, const int* in_sizes, int n_in,
                              void* d_out, int out_size, void* d_ws, size_t ws_size,
                              hipStream_t stream)
{
  const float* nodes = (const float*)d_in[0];
  const float* edges = (const float*)d_in[1];
  const float* WN    = (const float*)d_in[2];
  const float* WE    = (const float*)d_in[3];
  const float* aN    = (const float*)d_in[4];
  const float* aE    = (const float*)d_in[5];
  const int*   matN  = (const int*)d_in[6];
  const int*   matE  = (const int*)d_in[7];
  float* out = (float*)d_out;

  float* ws = (float*)d_ws;
  size_t o = 0;
  unsigned short* htT_n = (unsigned short*)(ws + o); o += (size_t)H_HEADS * 64 * N_NODES / 2;  // 2MB
  unsigned short* htT_e = (unsigned short*)(ws + o); o += (size_t)H_HEADS * 64 * N_EDGES / 2;  // 4MB
  unsigned* bitsN = (unsigned*)(ws + o); o += (size_t)N_NODES * (N_NODES / 32);                // 512KB
  unsigned* bitsE = (unsigned*)(ws + o); o += (size_t)N_NODES * (N_EDGES / 32);                // 1MB
  unsigned short* W2hi = (unsigned short*)(ws + o); o += (size_t)2 * 512 * 256 / 2;            // 512KB
  unsigned short* W2lo = (unsigned short*)(ws + o); o += (size_t)2 * 512 * 256 / 2;            // 512KB
  float* srcN  = ws + o;  o += (size_t)H_HEADS * N_NODES;
  float* tgtN  = ws + o;  o += (size_t)H_HEADS * N_NODES;
  float* srcE  = ws + o;  o += (size_t)H_HEADS * N_NODES;
  float* tgtE  = ws + o;  o += (size_t)H_HEADS * N_EDGES;
  float* NUM_N = ws + o;  o += (size_t)2 * H_HEADS * N_NODES * 64;   // 8MB
  float* DEN_N = ws + o;  o += (size_t)2 * H_HEADS * N_NODES;
  float* NUM_E = ws + o;  o += (size_t)2 * H_HEADS * N_NODES * 64;   // 8MB
  float* DEN_E = ws + o;  o += (size_t)2 * H_HEADS * N_NODES;

  hipLaunchKernelGGL(front2, dim3(1664), dim3(256), 0, stream,
                     WN, WE, matN, matE, W2hi, W2lo, bitsN, bitsE);
  hipLaunchKernelGGL(gemm_fused, dim3(96, 8), dim3(256), 0, stream,
                     nodes, edges, W2hi, W2lo, aN, aE,
                     htT_n, htT_e, srcN, tgtN, srcE, tgtE);
  hipLaunchKernelGGL(gat_main, dim3(1024), dim3(256), 0, stream,
                     htT_n, htT_e, srcN, tgtN, srcE, tgtE, bitsN, bitsE,
                     NUM_N, DEN_N, NUM_E, DEN_E);
  hipLaunchKernelGGL(reduce_out, dim3(256), dim3(128), 0, stream,
                     NUM_N, DEN_N, NUM_E, DEN_E, out);
}